// Round 5
// baseline (794.097 us; speedup 1.0000x reference)
//
#include <hip/hip_runtime.h>
#include <math.h>
#include <stdint.h>

#define N_NODES 20000
#define N_EDGES 320000
#define H 256
#define GH 512
#define G3 768
#define NT 3
#define R_ROUNDS 2

typedef __attribute__((ext_vector_type(8))) short short8;
typedef __attribute__((ext_vector_type(8))) unsigned short ushort8;
typedef __attribute__((ext_vector_type(4))) float floatx4;

static __device__ __forceinline__ unsigned short f2bf(float x) {
  unsigned u = __float_as_uint(x);
  u += 0x7fffu + ((u >> 16) & 1u);
  return (unsigned short)(u >> 16);
}

// ---------------------------------------------------------------- CSR build
__global__ __launch_bounds__(256) void hist_kernel(
    const int* __restrict__ dst, const float* __restrict__ he,
    int* __restrict__ cnt, float* __restrict__ hesum) {
  int e = blockIdx.x * 256 + threadIdx.x;
  if (e >= N_EDGES) return;
  int d = dst[e];
  atomicAdd(&cnt[d], 1);
  unsafeAtomicAdd(&hesum[d], he[e]);
}

__global__ __launch_bounds__(1024) void scan_kernel(
    const int* __restrict__ cnt, int* __restrict__ rowptr, int* __restrict__ cursor) {
  __shared__ int part[1024];
  const int CH = (N_NODES + 1023) / 1024;  // 20
  int t = threadIdx.x;
  int base = t * CH;
  int s = 0;
  for (int j = 0; j < CH; j++) {
    int idx = base + j;
    if (idx < N_NODES) s += cnt[idx];
  }
  part[t] = s;
  __syncthreads();
  int v = part[t];
  for (int off = 1; off < 1024; off <<= 1) {
    int o = (t >= off) ? part[t - off] : 0;
    __syncthreads();
    part[t] += o;
    __syncthreads();
  }
  int excl = part[t] - v;
  int run = excl;
  for (int j = 0; j < CH; j++) {
    int idx = base + j;
    if (idx < N_NODES) {
      rowptr[idx] = run;
      cursor[idx] = run;
      run += cnt[idx];
    }
  }
  if (t == 1023) rowptr[N_NODES] = run;
}

__global__ __launch_bounds__(256) void fill_kernel(
    const int* __restrict__ dst, const int* __restrict__ src,
    int* __restrict__ cursor, int* __restrict__ nbr) {
  int e = blockIdx.x * 256 + threadIdx.x;
  if (e >= N_EDGES) return;
  int p = atomicAdd(&cursor[dst[e]], 1);
  nbr[p] = src[e];
}

// ---------------------------------------------------------------- weight prep
__global__ __launch_bounds__(256) void cast_bf16(const float* __restrict__ in,
                                                 unsigned short* __restrict__ out, int n) {
  int i = blockIdx.x * 256 + threadIdx.x;
  if (i < n) out[i] = f2bf(in[i]);
}

// in: 512x512 (k rows, n cols) -> out[n*512+k] = in[k*512+n]
__global__ __launch_bounds__(256) void transpose_cast(const float* __restrict__ in,
                                                      unsigned short* __restrict__ out) {
  int idx = blockIdx.x * 256 + threadIdx.x;
  int n = idx >> 9, k = idx & 511;
  out[idx] = f2bf(in[k * 512 + n]);
}

// ---------------------------------------------------------------- gather
// A_msg[i] = bf16([deg[i]*hv[i] | sum_nbr hv]); HVb[i] = bf16(hv[i]); deg out.
__global__ __launch_bounds__(256) void gather_kernel(
    const float* __restrict__ hv, const int* __restrict__ rowptr,
    const int* __restrict__ nbr, unsigned short* __restrict__ A_msg,
    unsigned short* __restrict__ HVb, float* __restrict__ deg) {
  int w = (blockIdx.x * blockDim.x + threadIdx.x) >> 6;
  int lane = threadIdx.x & 63;
  if (w >= N_NODES) return;
  int start = rowptr[w], end = rowptr[w + 1];
  float4 acc = make_float4(0.f, 0.f, 0.f, 0.f);
  for (int b = start; b < end; b += 64) {
    int nb = min(64, end - b);
    int sidx = (lane < nb) ? nbr[b + lane] : 0;
    for (int j = 0; j < nb; j++) {
      int s = __shfl(sidx, j);
      const float4 v = *reinterpret_cast<const float4*>(hv + (size_t)s * H + lane * 4);
      acc.x += v.x; acc.y += v.y; acc.z += v.z; acc.w += v.w;
    }
  }
  float dg = (float)(end - start);
  const float4 own = *reinterpret_cast<const float4*>(hv + (size_t)w * H + lane * 4);
  ushort4 o;
  o.x = f2bf(own.x * dg); o.y = f2bf(own.y * dg);
  o.z = f2bf(own.z * dg); o.w = f2bf(own.w * dg);
  *reinterpret_cast<ushort4*>(A_msg + (size_t)w * GH + lane * 4) = o;
  o.x = f2bf(acc.x); o.y = f2bf(acc.y); o.z = f2bf(acc.z); o.w = f2bf(acc.w);
  *reinterpret_cast<ushort4*>(A_msg + (size_t)w * GH + H + lane * 4) = o;
  o.x = f2bf(own.x); o.y = f2bf(own.y); o.z = f2bf(own.z); o.w = f2bf(own.w);
  *reinterpret_cast<ushort4*>(HVb + (size_t)w * H + lane * 4) = o;
  if (lane == 0) deg[w] = dg;
}

// ---------------------------------------------------------------- MFMA GEMM
// C[M x Nc] = A[M x K](bf16) @ W[Nc x K](bf16)^T, 128x128 tile, BK=64.
// mode 0: Cf = acc + bias[col] (fp32); mode 1: Cb = bf16(acc + hesum*we + deg*bias)
__global__ __launch_bounds__(256) void mfma_gemm(
    int M, int K,
    const unsigned short* __restrict__ A, const unsigned short* __restrict__ W,
    const float* __restrict__ bias, const float* __restrict__ we,
    const float* __restrict__ deg, const float* __restrict__ hesum,
    float* __restrict__ Cf, unsigned short* __restrict__ Cb, int ldc, int mode) {
  __shared__ unsigned short As[128 * 88];
  __shared__ unsigned short Bs[128 * 88];
  int t = threadIdx.x;
  size_t i0 = (size_t)blockIdx.y * 128;
  size_t j0 = (size_t)blockIdx.x * 128;
  int wv = t >> 6, lane = t & 63;
  int m0 = (wv >> 1) * 64, n0 = (wv & 1) * 64;
  int lr = lane & 15, lq = lane >> 4;
  int r0 = t >> 3, kc = t & 7;
  floatx4 acc[4][4];
#pragma unroll
  for (int a = 0; a < 4; a++)
#pragma unroll
    for (int b = 0; b < 4; b++) acc[a][b] = (floatx4){0.f, 0.f, 0.f, 0.f};

  for (int k0 = 0; k0 < K; k0 += 64) {
    ushort8 va[4], vb[4];
#pragma unroll
    for (int p = 0; p < 4; p++) {
      va[p] = *(const ushort8*)(A + (i0 + r0 + p * 32) * K + k0 + kc * 8);
      vb[p] = *(const ushort8*)(W + (j0 + r0 + p * 32) * K + k0 + kc * 8);
    }
    __syncthreads();
#pragma unroll
    for (int p = 0; p < 4; p++) {
      *(ushort8*)(As + (r0 + p * 32) * 88 + kc * 8) = va[p];
      *(ushort8*)(Bs + (r0 + p * 32) * 88 + kc * 8) = vb[p];
    }
    __syncthreads();
#pragma unroll
    for (int kk = 0; kk < 2; kk++) {
      short8 af[4], bf[4];
#pragma unroll
      for (int mi = 0; mi < 4; mi++)
        af[mi] = *(const short8*)(As + (m0 + mi * 16 + lr) * 88 + kk * 32 + lq * 8);
#pragma unroll
      for (int ni = 0; ni < 4; ni++)
        bf[ni] = *(const short8*)(Bs + (n0 + ni * 16 + lr) * 88 + kk * 32 + lq * 8);
#pragma unroll
      for (int mi = 0; mi < 4; mi++)
#pragma unroll
        for (int ni = 0; ni < 4; ni++)
          acc[mi][ni] = __builtin_amdgcn_mfma_f32_16x16x32_bf16(af[mi], bf[ni],
                                                                acc[mi][ni], 0, 0, 0);
    }
  }

  if (mode == 0) {
#pragma unroll
    for (int mi = 0; mi < 4; mi++) {
#pragma unroll
      for (int ni = 0; ni < 4; ni++) {
        int col = (int)j0 + n0 + ni * 16 + lr;
        float bv = bias[col];
#pragma unroll
        for (int i = 0; i < 4; i++) {
          size_t row = i0 + m0 + mi * 16 + lq * 4 + i;
          if (row < (size_t)M) Cf[row * ldc + col] = acc[mi][ni][i] + bv;
        }
      }
    }
  } else {
#pragma unroll
    for (int mi = 0; mi < 4; mi++) {
#pragma unroll
      for (int ni = 0; ni < 4; ni++) {
        int col = (int)j0 + n0 + ni * 16 + lr;
        float wv_ = we[col], bv = bias[col];
#pragma unroll
        for (int i = 0; i < 4; i++) {
          size_t row = i0 + m0 + mi * 16 + lq * 4 + i;
          if (row < (size_t)M)
            Cb[row * ldc + col] = f2bf(acc[mi][ni][i] + hesum[row] * wv_ + deg[row] * bv);
        }
      }
    }
  }
}

// ---------------------------------------------------------------- GRU elementwise
__global__ void gru_update(const float* __restrict__ gi, const float* __restrict__ gh,
                           float* __restrict__ hv) {
  int idx = blockIdx.x * blockDim.x + threadIdx.x;
  if (idx >= N_NODES * H) return;
  int row = idx >> 8, col = idx & 255;
  const float* gir = gi + (size_t)row * G3;
  const float* ghr = gh + (size_t)row * G3;
  float ir = gir[col], iz = gir[H + col], inn = gir[2 * H + col];
  float hr = ghr[col], hz = ghr[H + col], hn = ghr[2 * H + col];
  float r = 1.f / (1.f + expf(-(ir + hr)));
  float z = 1.f / (1.f + expf(-(iz + hz)));
  float n = tanhf(inn + r * hn);
  hv[idx] = (1.f - z) * n + z * hv[idx];
}

// ---------------------------------------------------------------- graph embed phase 1
__global__ __launch_bounds__(256) void embed_phase1(
    const float* __restrict__ hv, const int* __restrict__ ntype,
    const float* __restrict__ gate_w, const float* __restrict__ gate_b,
    float* __restrict__ U, float* __restrict__ G) {
  __shared__ float Ul[NT * H];
  __shared__ float Gl[NT];
  for (int j = threadIdx.x; j < NT * H; j += 256) Ul[j] = 0.f;
  if (threadIdx.x < NT) Gl[threadIdx.x] = 0.f;
  __syncthreads();
  int lane = threadIdx.x & 63;
  int wave = blockIdx.x * 4 + (threadIdx.x >> 6);
  int nwaves = gridDim.x * 4;
  for (int i = wave; i < N_NODES; i += nwaves) {
    int t = ntype[i];
    float4 h = *reinterpret_cast<const float4*>(hv + (size_t)i * H + lane * 4);
    float4 w = *reinterpret_cast<const float4*>(gate_w + t * H + lane * 4);
    float s = h.x * w.x + h.y * w.y + h.z * w.z + h.w * w.w;
    for (int off = 32; off; off >>= 1) s += __shfl_xor(s, off);
    float g = 1.f / (1.f + expf(-(s + gate_b[t])));
    float* up = Ul + t * H + lane * 4;
    atomicAdd(up + 0, g * h.x);
    atomicAdd(up + 1, g * h.y);
    atomicAdd(up + 2, g * h.z);
    atomicAdd(up + 3, g * h.w);
    if (lane == 0) atomicAdd(&Gl[t], g);
  }
  __syncthreads();
  for (int j = threadIdx.x; j < NT * H; j += 256) unsafeAtomicAdd(&U[j], Ul[j]);
  if (threadIdx.x < NT) unsafeAtomicAdd(&G[threadIdx.x], Gl[threadIdx.x]);
}

// ---------------------------------------------------------------- gembed (parallel)
// grid 6: t = b>>1, half = b&1. gembed[col] += sum_k U[t][k]*W[t][k][col] + G[t]*b[t][col]
__global__ __launch_bounds__(256) void gembed_partial(
    const float* __restrict__ U, const float* __restrict__ G,
    const float* __restrict__ tograph_w, const float* __restrict__ tograph_b,
    float* __restrict__ gembed_out) {
  int t = blockIdx.x >> 1;
  int col = (blockIdx.x & 1) * 256 + threadIdx.x;
  const float* Wt = tograph_w + (size_t)t * H * GH;
  float acc = G[t] * tograph_b[t * GH + col];
  for (int k = 0; k < H; k++) acc += U[t * H + k] * Wt[(size_t)k * GH + col];
  unsafeAtomicAdd(&gembed_out[col], acc);
}

// ---------------------------------------------------------------- heads (parallel)
// grid 6: blocks 0..3 = hv_init k-chunks; 4 = node logits; 5 = edge_logit + c2.
__global__ __launch_bounds__(256) void heads_kernel(
    const float* __restrict__ ge, const float* __restrict__ addnode_w,
    const float* __restrict__ addnode_b, const float* __restrict__ ntype_embed,
    const float* __restrict__ inithv_w, const float* __restrict__ inithv_b,
    const float* __restrict__ addedge_w, const float* __restrict__ addedge_b,
    const float* __restrict__ hv, const float* __restrict__ dest_w,
    const float* __restrict__ dest_b, float* __restrict__ nodelogp_out,
    float* __restrict__ hvinit_out, float* __restrict__ edgelogit_out,
    float* __restrict__ misc) {
  int b = blockIdx.x;
  int tid = threadIdx.x;
  if (b < 4) {  // hv_init: k in [b*192, b*192+192), col = tid
    float acc = (b == 0) ? inithv_b[tid] : 0.f;
    int k0 = b * 192, k1 = k0 + 192;
    for (int k = k0; k < k1; k++) {
      float x = (k < H) ? ntype_embed[k] : ge[k - H];
      acc += x * inithv_w[(size_t)k * H + tid];
    }
    unsafeAtomicAdd(&hvinit_out[tid], acc);
  } else if (b == 4) {  // node logits + log_softmax (4 waves, one per logit)
    __shared__ float lg[4];
    int w = tid >> 6, lane = tid & 63;
    float s = 0.f;
    for (int k = lane; k < GH; k += 64) s += ge[k] * addnode_w[k * 4 + w];
    for (int off = 32; off; off >>= 1) s += __shfl_xor(s, off);
    if (lane == 0) lg[w] = s + addnode_b[w];
    __syncthreads();
    if (tid == 0) {
      float m = fmaxf(fmaxf(lg[0], lg[1]), fmaxf(lg[2], lg[3]));
      float sum = 0.f;
      for (int c = 0; c < 4; c++) sum += expf(lg[c] - m);
      float lse = m + logf(sum);
      for (int c = 0; c < 4; c++) nodelogp_out[c] = lg[c] - lse;
    }
  } else {  // edge_logit (wave 0), c2 -> misc (wave 1)
    int w = tid >> 6, lane = tid & 63;
    const float* se = hv + (size_t)(N_NODES - 1) * H;
    if (w == 0) {
      float s = 0.f;
      for (int k = lane; k < G3; k += 64) {
        float x = (k < GH) ? ge[k] : se[k - GH];
        s += x * addedge_w[k];
      }
      for (int off = 32; off; off >>= 1) s += __shfl_xor(s, off);
      if (lane == 0) edgelogit_out[0] = s + addedge_b[0];
    } else if (w == 1) {
      float s = 0.f;
      for (int k = lane; k < H; k += 64) s += se[k] * dest_w[H + k];
      for (int off = 32; off; off >>= 1) s += __shfl_xor(s, off);
      if (lane == 0) misc[0] = s + dest_b[0];
    }
  }
}

// ---------------------------------------------------------------- dest scores
__global__ __launch_bounds__(256) void dest_scores_kernel(
    const float* __restrict__ hv, const float* __restrict__ dest_w,
    const float* __restrict__ misc, float* __restrict__ scores) {
  int w = (blockIdx.x * blockDim.x + threadIdx.x) >> 6;
  int lane = threadIdx.x & 63;
  if (w >= N_NODES - 1) return;
  float4 h = *reinterpret_cast<const float4*>(hv + (size_t)w * H + lane * 4);
  float4 d = *reinterpret_cast<const float4*>(dest_w + lane * 4);
  float s = h.x * d.x + h.y * d.y + h.z * d.z + h.w * d.w;
  for (int off = 32; off; off >>= 1) s += __shfl_xor(s, off);
  if (lane == 0) scores[w] = s + misc[0];
}

__global__ __launch_bounds__(1024) void dest_softmax(const float* __restrict__ scores,
                                                     float* __restrict__ out) {
  const int n = N_NODES - 1;
  __shared__ float red[16];
  __shared__ float bc[2];
  int tid = threadIdx.x;
  float m = -1e30f;
  for (int i = tid; i < n; i += 1024) m = fmaxf(m, scores[i]);
  for (int off = 32; off; off >>= 1) m = fmaxf(m, __shfl_xor(m, off));
  if ((tid & 63) == 0) red[tid >> 6] = m;
  __syncthreads();
  if (tid == 0) {
    float v = red[0];
    for (int i = 1; i < 16; i++) v = fmaxf(v, red[i]);
    bc[0] = v;
  }
  __syncthreads();
  float mx = bc[0];
  float s = 0.f;
  for (int i = tid; i < n; i += 1024) s += expf(scores[i] - mx);
  for (int off = 32; off; off >>= 1) s += __shfl_xor(s, off);
  if ((tid & 63) == 0) red[tid >> 6] = s;
  __syncthreads();
  if (tid == 0) {
    float v = 0.f;
    for (int i = 0; i < 16; i++) v += red[i];
    bc[1] = v;
  }
  __syncthreads();
  float lse = mx + logf(bc[1]);
  for (int i = tid; i < n; i += 1024) out[i] = scores[i] - lse;
}

// ---------------------------------------------------------------- launch
extern "C" void kernel_launch(void* const* d_in, const int* in_sizes, int n_in,
                              void* d_out, int out_size, void* d_ws, size_t ws_size,
                              hipStream_t stream) {
  const float* hv0 = (const float*)d_in[0];
  const float* he = (const float*)d_in[1];
  const int* ntype = (const int*)d_in[2];
  const int* src = (const int*)d_in[3];
  const int* dst = (const int*)d_in[4];
  const float* msg_w = (const float*)d_in[5];
  const float* msg_b = (const float*)d_in[6];
  const float* w_ih = (const float*)d_in[7];
  const float* b_ih = (const float*)d_in[8];
  const float* w_hh = (const float*)d_in[9];
  const float* b_hh = (const float*)d_in[10];
  const float* gate_w = (const float*)d_in[11];
  const float* gate_b = (const float*)d_in[12];
  const float* tograph_w = (const float*)d_in[13];
  const float* tograph_b = (const float*)d_in[14];
  const float* addnode_w = (const float*)d_in[15];
  const float* addnode_b = (const float*)d_in[16];
  const float* ntype_embed = (const float*)d_in[17];
  const float* inithv_w = (const float*)d_in[18];
  const float* inithv_b = (const float*)d_in[19];
  const float* addedge_w = (const float*)d_in[20];
  const float* addedge_b = (const float*)d_in[21];
  const float* dest_w = (const float*)d_in[22];
  const float* dest_b = (const float*)d_in[23];

  float* out = (float*)d_out;
  float* HV = out;
  float* gembed_out = out + (size_t)N_NODES * H;
  float* nodelogp_out = gembed_out + GH;
  float* hvinit_out = nodelogp_out + 4;
  float* edgelogit_out = hvinit_out + H;
  float* destlogp_out = edgelogit_out + 1;

  float* ws = (float*)d_ws;
  float* deg = ws;                                    // N
  float* hesum = deg + N_NODES;                       // N
  float* gi = hesum + N_NODES;                        // N*G3
  float* gh = gi + (size_t)N_NODES * G3;              // N*G3
  float* U = gh + (size_t)N_NODES * G3;               // NT*H
  float* G = U + NT * H;                              // NT
  float* misc = G + NT;                               // 16
  float* scores = misc + 16;                          // N
  int* cnt = (int*)(scores + N_NODES);                // N
  int* rowptr = cnt + N_NODES;                        // N+1
  int* cursor = rowptr + N_NODES + 1;                 // N
  int* nbr = cursor + N_NODES;                        // E
  unsigned short* A_msg =
      (unsigned short*)(((uintptr_t)(nbr + N_EDGES) + 15) & ~(uintptr_t)15);
  unsigned short* HVb = A_msg + (size_t)(N_NODES + 128) * GH;
  unsigned short* a_b = HVb + (size_t)(N_NODES + 128) * H;
  unsigned short* wihb = a_b + (size_t)(N_NODES + 128) * GH;
  unsigned short* whhb = wihb + (size_t)2 * G3 * GH;
  unsigned short* Wmt = whhb + (size_t)2 * G3 * H;

  hipMemcpyAsync(HV, hv0, sizeof(float) * (size_t)N_NODES * H,
                 hipMemcpyDeviceToDevice, stream);

  // ---- weight prep (bf16; msg_w transposed to N x K)
  cast_bf16<<<(2 * G3 * GH + 255) / 256, 256, 0, stream>>>(w_ih, wihb, 2 * G3 * GH);
  cast_bf16<<<(2 * G3 * H + 255) / 256, 256, 0, stream>>>(w_hh, whhb, 2 * G3 * H);
  transpose_cast<<<(512 * 512) / 256, 256, 0, stream>>>(msg_w, Wmt);
  transpose_cast<<<(512 * 512) / 256, 256, 0, stream>>>(msg_w + 513 * 512,
                                                        Wmt + 512 * 512);

  // ---- CSR build
  hipMemsetAsync(hesum, 0, sizeof(float) * N_NODES, stream);
  hipMemsetAsync(cnt, 0, sizeof(int) * N_NODES, stream);
  hist_kernel<<<(N_EDGES + 255) / 256, 256, 0, stream>>>(dst, he, cnt, hesum);
  scan_kernel<<<1, 1024, 0, stream>>>(cnt, rowptr, cursor);
  fill_kernel<<<(N_EDGES + 255) / 256, 256, 0, stream>>>(dst, src, cursor, nbr);

  const int MB = (N_NODES + 127) / 128;  // 157
  for (int t = 0; t < R_ROUNDS; t++) {
    gather_kernel<<<N_NODES / 4, 256, 0, stream>>>(HV, rowptr, nbr, A_msg, HVb, deg);
    mfma_gemm<<<dim3(GH / 128, MB), 256, 0, stream>>>(
        N_NODES, GH, A_msg, Wmt + (size_t)t * GH * GH, msg_b + (size_t)t * GH,
        msg_w + (size_t)t * (2 * H + 1) * GH + (size_t)GH * GH, deg, hesum,
        nullptr, a_b, GH, 1);
    mfma_gemm<<<dim3(G3 / 128, MB), 256, 0, stream>>>(
        N_NODES, GH, a_b, wihb + (size_t)t * G3 * GH, b_ih + (size_t)t * G3,
        nullptr, nullptr, nullptr, gi, nullptr, G3, 0);
    mfma_gemm<<<dim3(G3 / 128, MB), 256, 0, stream>>>(
        N_NODES, H, HVb, whhb + (size_t)t * G3 * H, b_hh + (size_t)t * G3,
        nullptr, nullptr, nullptr, gh, nullptr, G3, 0);
    gru_update<<<(N_NODES * H + 255) / 256, 256, 0, stream>>>(gi, gh, HV);
  }

  hipMemsetAsync(U, 0, sizeof(float) * (NT * H + NT), stream);
  embed_phase1<<<128, 256, 0, stream>>>(HV, ntype, gate_w, gate_b, U, G);
  hipMemsetAsync(gembed_out, 0, sizeof(float) * GH, stream);
  hipMemsetAsync(hvinit_out, 0, sizeof(float) * H, stream);
  gembed_partial<<<6, 256, 0, stream>>>(U, G, tograph_w, tograph_b, gembed_out);
  heads_kernel<<<6, 256, 0, stream>>>(gembed_out, addnode_w, addnode_b, ntype_embed,
                                      inithv_w, inithv_b, addedge_w, addedge_b, HV,
                                      dest_w, dest_b, nodelogp_out, hvinit_out,
                                      edgelogit_out, misc);
  dest_scores_kernel<<<((N_NODES - 1) * 64 + 255) / 256, 256, 0, stream>>>(
      HV, dest_w, misc, scores);
  dest_softmax<<<1, 1024, 0, stream>>>(scores, destlogp_out);
}

// Round 6
// 709.788 us; speedup vs baseline: 1.1188x; 1.1188x over previous
//
#include <hip/hip_runtime.h>
#include <math.h>
#include <stdint.h>

#define N_NODES 20000
#define N_EDGES 320000
#define H 256
#define GH 512
#define G3 768
#define NT 3
#define R_ROUNDS 2

typedef __attribute__((ext_vector_type(8))) short short8;
typedef __attribute__((ext_vector_type(8))) unsigned short ushort8;
typedef __attribute__((ext_vector_type(4))) float floatx4;

static __device__ __forceinline__ unsigned short f2bf(float x) {
  unsigned u = __float_as_uint(x);
  u += 0x7fffu + ((u >> 16) & 1u);
  return (unsigned short)(u >> 16);
}

// ---------------------------------------------------------------- CSR build
__global__ __launch_bounds__(256) void hist_kernel(
    const int* __restrict__ dst, const float* __restrict__ he,
    int* __restrict__ cnt, float* __restrict__ hesum) {
  int e = blockIdx.x * 256 + threadIdx.x;
  if (e >= N_EDGES) return;
  int d = dst[e];
  atomicAdd(&cnt[d], 1);
  unsafeAtomicAdd(&hesum[d], he[e]);
}

__global__ __launch_bounds__(1024) void scan_kernel(
    const int* __restrict__ cnt, int* __restrict__ rowptr, int* __restrict__ cursor) {
  __shared__ int part[1024];
  const int CH = (N_NODES + 1023) / 1024;  // 20
  int t = threadIdx.x;
  int base = t * CH;
  int s = 0;
  for (int j = 0; j < CH; j++) {
    int idx = base + j;
    if (idx < N_NODES) s += cnt[idx];
  }
  part[t] = s;
  __syncthreads();
  int v = part[t];
  for (int off = 1; off < 1024; off <<= 1) {
    int o = (t >= off) ? part[t - off] : 0;
    __syncthreads();
    part[t] += o;
    __syncthreads();
  }
  int excl = part[t] - v;
  int run = excl;
  for (int j = 0; j < CH; j++) {
    int idx = base + j;
    if (idx < N_NODES) {
      rowptr[idx] = run;
      cursor[idx] = run;
      run += cnt[idx];
    }
  }
  if (t == 1023) rowptr[N_NODES] = run;
}

__global__ __launch_bounds__(256) void fill_kernel(
    const int* __restrict__ dst, const int* __restrict__ src,
    int* __restrict__ cursor, int* __restrict__ nbr) {
  int e = blockIdx.x * 256 + threadIdx.x;
  if (e >= N_EDGES) return;
  int p = atomicAdd(&cursor[dst[e]], 1);
  nbr[p] = src[e];
}

// ---------------------------------------------------------------- weight prep
__global__ __launch_bounds__(256) void cast_bf16(const float* __restrict__ in,
                                                 unsigned short* __restrict__ out, int n) {
  int i = blockIdx.x * 256 + threadIdx.x;
  if (i < n) out[i] = f2bf(in[i]);
}

// in: 512x512 (k rows, n cols) -> out[n*512+k] = in[k*512+n]
__global__ __launch_bounds__(256) void transpose_cast(const float* __restrict__ in,
                                                      unsigned short* __restrict__ out) {
  int idx = blockIdx.x * 256 + threadIdx.x;
  int n = idx >> 9, k = idx & 511;
  out[idx] = f2bf(in[k * 512 + n]);
}

// ---------------------------------------------------------------- gather
// A_msg[i] = bf16([deg[i]*hv[i] | sum_nbr hv]); HVb[i] = bf16(hv[i]); deg out.
__global__ __launch_bounds__(256) void gather_kernel(
    const float* __restrict__ hv, const int* __restrict__ rowptr,
    const int* __restrict__ nbr, unsigned short* __restrict__ A_msg,
    unsigned short* __restrict__ HVb, float* __restrict__ deg) {
  int w = (blockIdx.x * blockDim.x + threadIdx.x) >> 6;
  int lane = threadIdx.x & 63;
  if (w >= N_NODES) return;
  int start = rowptr[w], end = rowptr[w + 1];
  float4 acc = make_float4(0.f, 0.f, 0.f, 0.f);
  for (int b = start; b < end; b += 64) {
    int nb = min(64, end - b);
    int sidx = (lane < nb) ? nbr[b + lane] : 0;
    for (int j = 0; j < nb; j++) {
      int s = __shfl(sidx, j);
      const float4 v = *reinterpret_cast<const float4*>(hv + (size_t)s * H + lane * 4);
      acc.x += v.x; acc.y += v.y; acc.z += v.z; acc.w += v.w;
    }
  }
  float dg = (float)(end - start);
  const float4 own = *reinterpret_cast<const float4*>(hv + (size_t)w * H + lane * 4);
  ushort4 o;
  o.x = f2bf(own.x * dg); o.y = f2bf(own.y * dg);
  o.z = f2bf(own.z * dg); o.w = f2bf(own.w * dg);
  *reinterpret_cast<ushort4*>(A_msg + (size_t)w * GH + lane * 4) = o;
  o.x = f2bf(acc.x); o.y = f2bf(acc.y); o.z = f2bf(acc.z); o.w = f2bf(acc.w);
  *reinterpret_cast<ushort4*>(A_msg + (size_t)w * GH + H + lane * 4) = o;
  o.x = f2bf(own.x); o.y = f2bf(own.y); o.z = f2bf(own.z); o.w = f2bf(own.w);
  *reinterpret_cast<ushort4*>(HVb + (size_t)w * H + lane * 4) = o;
  if (lane == 0) deg[w] = dg;
}

// ---------------------------------------------------------------- MFMA GEMM
// C[M x Nc] = A[M x K](bf16) @ W[Nc x K](bf16)^T, 128x128 tile, BK=64.
// mode 0: Cf = acc + bias[col] (fp32); mode 1: Cb = bf16(acc + hesum*we + deg*bias)
__global__ __launch_bounds__(256) void mfma_gemm(
    int M, int K,
    const unsigned short* __restrict__ A, const unsigned short* __restrict__ W,
    const float* __restrict__ bias, const float* __restrict__ we,
    const float* __restrict__ deg, const float* __restrict__ hesum,
    float* __restrict__ Cf, unsigned short* __restrict__ Cb, int ldc, int mode) {
  __shared__ unsigned short As[128 * 88];
  __shared__ unsigned short Bs[128 * 88];
  int t = threadIdx.x;
  size_t i0 = (size_t)blockIdx.y * 128;
  size_t j0 = (size_t)blockIdx.x * 128;
  int wv = t >> 6, lane = t & 63;
  int m0 = (wv >> 1) * 64, n0 = (wv & 1) * 64;
  int lr = lane & 15, lq = lane >> 4;
  int r0 = t >> 3, kc = t & 7;
  floatx4 acc[4][4];
#pragma unroll
  for (int a = 0; a < 4; a++)
#pragma unroll
    for (int b = 0; b < 4; b++) acc[a][b] = (floatx4){0.f, 0.f, 0.f, 0.f};

  for (int k0 = 0; k0 < K; k0 += 64) {
    ushort8 va[4], vb[4];
#pragma unroll
    for (int p = 0; p < 4; p++) {
      va[p] = *(const ushort8*)(A + (i0 + r0 + p * 32) * K + k0 + kc * 8);
      vb[p] = *(const ushort8*)(W + (j0 + r0 + p * 32) * K + k0 + kc * 8);
    }
    __syncthreads();
#pragma unroll
    for (int p = 0; p < 4; p++) {
      *(ushort8*)(As + (r0 + p * 32) * 88 + kc * 8) = va[p];
      *(ushort8*)(Bs + (r0 + p * 32) * 88 + kc * 8) = vb[p];
    }
    __syncthreads();
#pragma unroll
    for (int kk = 0; kk < 2; kk++) {
      short8 af[4], bf[4];
#pragma unroll
      for (int mi = 0; mi < 4; mi++)
        af[mi] = *(const short8*)(As + (m0 + mi * 16 + lr) * 88 + kk * 32 + lq * 8);
#pragma unroll
      for (int ni = 0; ni < 4; ni++)
        bf[ni] = *(const short8*)(Bs + (n0 + ni * 16 + lr) * 88 + kk * 32 + lq * 8);
#pragma unroll
      for (int mi = 0; mi < 4; mi++)
#pragma unroll
        for (int ni = 0; ni < 4; ni++)
          acc[mi][ni] = __builtin_amdgcn_mfma_f32_16x16x32_bf16(af[mi], bf[ni],
                                                                acc[mi][ni], 0, 0, 0);
    }
  }

  if (mode == 0) {
#pragma unroll
    for (int mi = 0; mi < 4; mi++) {
#pragma unroll
      for (int ni = 0; ni < 4; ni++) {
        int col = (int)j0 + n0 + ni * 16 + lr;
        float bv = bias[col];
#pragma unroll
        for (int i = 0; i < 4; i++) {
          size_t row = i0 + m0 + mi * 16 + lq * 4 + i;
          if (row < (size_t)M) Cf[row * ldc + col] = acc[mi][ni][i] + bv;
        }
      }
    }
  } else {
#pragma unroll
    for (int mi = 0; mi < 4; mi++) {
#pragma unroll
      for (int ni = 0; ni < 4; ni++) {
        int col = (int)j0 + n0 + ni * 16 + lr;
        float wv_ = we[col], bv = bias[col];
#pragma unroll
        for (int i = 0; i < 4; i++) {
          size_t row = i0 + m0 + mi * 16 + lq * 4 + i;
          if (row < (size_t)M)
            Cb[row * ldc + col] = f2bf(acc[mi][ni][i] + hesum[row] * wv_ + deg[row] * bv);
        }
      }
    }
  }
}

// ---------------------------------------------------------------- GRU elementwise
__global__ void gru_update(const float* __restrict__ gi, const float* __restrict__ gh,
                           float* __restrict__ hv) {
  int idx = blockIdx.x * blockDim.x + threadIdx.x;
  if (idx >= N_NODES * H) return;
  int row = idx >> 8, col = idx & 255;
  const float* gir = gi + (size_t)row * G3;
  const float* ghr = gh + (size_t)row * G3;
  float ir = gir[col], iz = gir[H + col], inn = gir[2 * H + col];
  float hr = ghr[col], hz = ghr[H + col], hn = ghr[2 * H + col];
  float r = 1.f / (1.f + expf(-(ir + hr)));
  float z = 1.f / (1.f + expf(-(iz + hz)));
  float n = tanhf(inn + r * hn);
  hv[idx] = (1.f - z) * n + z * hv[idx];
}

// ---------------------------------------------------------------- graph embed phase 1
__global__ __launch_bounds__(256) void embed_phase1(
    const float* __restrict__ hv, const int* __restrict__ ntype,
    const float* __restrict__ gate_w, const float* __restrict__ gate_b,
    float* __restrict__ U, float* __restrict__ G) {
  __shared__ float Ul[NT * H];
  __shared__ float Gl[NT];
  for (int j = threadIdx.x; j < NT * H; j += 256) Ul[j] = 0.f;
  if (threadIdx.x < NT) Gl[threadIdx.x] = 0.f;
  __syncthreads();
  int lane = threadIdx.x & 63;
  int wave = blockIdx.x * 4 + (threadIdx.x >> 6);
  int nwaves = gridDim.x * 4;
  for (int i = wave; i < N_NODES; i += nwaves) {
    int t = ntype[i];
    float4 h = *reinterpret_cast<const float4*>(hv + (size_t)i * H + lane * 4);
    float4 w = *reinterpret_cast<const float4*>(gate_w + t * H + lane * 4);
    float s = h.x * w.x + h.y * w.y + h.z * w.z + h.w * w.w;
    for (int off = 32; off; off >>= 1) s += __shfl_xor(s, off);
    float g = 1.f / (1.f + expf(-(s + gate_b[t])));
    float* up = Ul + t * H + lane * 4;
    atomicAdd(up + 0, g * h.x);
    atomicAdd(up + 1, g * h.y);
    atomicAdd(up + 2, g * h.z);
    atomicAdd(up + 3, g * h.w);
    if (lane == 0) atomicAdd(&Gl[t], g);
  }
  __syncthreads();
  for (int j = threadIdx.x; j < NT * H; j += 256) unsafeAtomicAdd(&U[j], Ul[j]);
  if (threadIdx.x < NT) unsafeAtomicAdd(&G[threadIdx.x], Gl[threadIdx.x]);
}

// ---------------------------------------------------------------- gembed (k-split, MLP)
// grid 48: t = b>>4, half = (b>>3)&1, kc = b&7 (32 k each). 32 independent loads.
__global__ __launch_bounds__(256) void gembed_partial(
    const float* __restrict__ U, const float* __restrict__ G,
    const float* __restrict__ tograph_w, const float* __restrict__ tograph_b,
    float* __restrict__ gembed_out) {
  int b = blockIdx.x;
  int t = b >> 4, half = (b >> 3) & 1, kc = b & 7;
  int col = half * 256 + threadIdx.x;
  int k0 = kc * 32;
  const float* Wt = tograph_w + (size_t)t * H * GH;
  float w[32], u[32];
#pragma unroll
  for (int j = 0; j < 32; j++) w[j] = Wt[(size_t)(k0 + j) * GH + col];
#pragma unroll
  for (int j = 0; j < 32; j++) u[j] = U[t * H + k0 + j];
  float acc = (kc == 0) ? G[t] * tograph_b[t * GH + col] : 0.f;
#pragma unroll
  for (int j = 0; j < 32; j++) acc += u[j] * w[j];
  unsafeAtomicAdd(&gembed_out[col], acc);
}

// ---------------------------------------------------------------- heads (k-split, MLP)
// grid 26: blocks 0..23 = hv_init k-chunks (32 k each); 24 = node logits; 25 = edge_logit.
// NOTE: dest c2 constant cancels in log_softmax -> not computed at all.
__global__ __launch_bounds__(256) void heads_kernel(
    const float* __restrict__ ge, const float* __restrict__ addnode_w,
    const float* __restrict__ addnode_b, const float* __restrict__ ntype_embed,
    const float* __restrict__ inithv_w, const float* __restrict__ inithv_b,
    const float* __restrict__ addedge_w, const float* __restrict__ addedge_b,
    const float* __restrict__ hv, float* __restrict__ nodelogp_out,
    float* __restrict__ hvinit_out, float* __restrict__ edgelogit_out) {
  int b = blockIdx.x;
  int tid = threadIdx.x;
  if (b < 24) {  // hv_init: k in [b*32, b*32+32), col = tid
    int k0 = b * 32;
    float w[32], x[32];
#pragma unroll
    for (int j = 0; j < 32; j++) w[j] = inithv_w[(size_t)(k0 + j) * H + tid];
#pragma unroll
    for (int j = 0; j < 32; j++) {
      int k = k0 + j;
      x[j] = (k < H) ? ntype_embed[k] : ge[k - H];
    }
    float acc = (b == 0) ? inithv_b[tid] : 0.f;
#pragma unroll
    for (int j = 0; j < 32; j++) acc += x[j] * w[j];
    unsafeAtomicAdd(&hvinit_out[tid], acc);
  } else if (b == 24) {  // node logits + log_softmax (4 waves, one per logit)
    __shared__ float lg[4];
    int w = tid >> 6, lane = tid & 63;
    float s = 0.f;
    for (int k = lane; k < GH; k += 64) s += ge[k] * addnode_w[k * 4 + w];
    for (int off = 32; off; off >>= 1) s += __shfl_xor(s, off);
    if (lane == 0) lg[w] = s + addnode_b[w];
    __syncthreads();
    if (tid == 0) {
      float m = fmaxf(fmaxf(lg[0], lg[1]), fmaxf(lg[2], lg[3]));
      float sum = 0.f;
      for (int c = 0; c < 4; c++) sum += expf(lg[c] - m);
      float lse = m + logf(sum);
      for (int c = 0; c < 4; c++) nodelogp_out[c] = lg[c] - lse;
    }
  } else {  // edge_logit (wave 0)
    int w = tid >> 6, lane = tid & 63;
    if (w == 0) {
      const float* se = hv + (size_t)(N_NODES - 1) * H;
      float s = 0.f;
      for (int k = lane; k < G3; k += 64) {
        float x = (k < GH) ? ge[k] : se[k - GH];
        s += x * addedge_w[k];
      }
      for (int off = 32; off; off >>= 1) s += __shfl_xor(s, off);
      if (lane == 0) edgelogit_out[0] = s + addedge_b[0];
    }
  }
}

// ---------------------------------------------------------------- dest scores
// c2 (+dest_b + se.dest_w[256:]) is constant over i and cancels in log_softmax.
__global__ __launch_bounds__(256) void dest_scores_kernel(
    const float* __restrict__ hv, const float* __restrict__ dest_w,
    float* __restrict__ scores) {
  int w = (blockIdx.x * blockDim.x + threadIdx.x) >> 6;
  int lane = threadIdx.x & 63;
  if (w >= N_NODES - 1) return;
  float4 h = *reinterpret_cast<const float4*>(hv + (size_t)w * H + lane * 4);
  float4 d = *reinterpret_cast<const float4*>(dest_w + lane * 4);
  float s = h.x * d.x + h.y * d.y + h.z * d.z + h.w * d.w;
  for (int off = 32; off; off >>= 1) s += __shfl_xor(s, off);
  if (lane == 0) scores[w] = s;
}

__global__ __launch_bounds__(1024) void dest_softmax(const float* __restrict__ scores,
                                                     float* __restrict__ out) {
  const int n = N_NODES - 1;
  __shared__ float red[16];
  __shared__ float bc[2];
  int tid = threadIdx.x;
  float m = -1e30f;
  for (int i = tid; i < n; i += 1024) m = fmaxf(m, scores[i]);
  for (int off = 32; off; off >>= 1) m = fmaxf(m, __shfl_xor(m, off));
  if ((tid & 63) == 0) red[tid >> 6] = m;
  __syncthreads();
  if (tid == 0) {
    float v = red[0];
    for (int i = 1; i < 16; i++) v = fmaxf(v, red[i]);
    bc[0] = v;
  }
  __syncthreads();
  float mx = bc[0];
  float s = 0.f;
  for (int i = tid; i < n; i += 1024) s += expf(scores[i] - mx);
  for (int off = 32; off; off >>= 1) s += __shfl_xor(s, off);
  if ((tid & 63) == 0) red[tid >> 6] = s;
  __syncthreads();
  if (tid == 0) {
    float v = 0.f;
    for (int i = 0; i < 16; i++) v += red[i];
    bc[1] = v;
  }
  __syncthreads();
  float lse = mx + logf(bc[1]);
  for (int i = tid; i < n; i += 1024) out[i] = scores[i] - lse;
}

// ---------------------------------------------------------------- launch
extern "C" void kernel_launch(void* const* d_in, const int* in_sizes, int n_in,
                              void* d_out, int out_size, void* d_ws, size_t ws_size,
                              hipStream_t stream) {
  const float* hv0 = (const float*)d_in[0];
  const float* he = (const float*)d_in[1];
  const int* ntype = (const int*)d_in[2];
  const int* src = (const int*)d_in[3];
  const int* dst = (const int*)d_in[4];
  const float* msg_w = (const float*)d_in[5];
  const float* msg_b = (const float*)d_in[6];
  const float* w_ih = (const float*)d_in[7];
  const float* b_ih = (const float*)d_in[8];
  const float* w_hh = (const float*)d_in[9];
  const float* b_hh = (const float*)d_in[10];
  const float* gate_w = (const float*)d_in[11];
  const float* gate_b = (const float*)d_in[12];
  const float* tograph_w = (const float*)d_in[13];
  const float* tograph_b = (const float*)d_in[14];
  const float* addnode_w = (const float*)d_in[15];
  const float* addnode_b = (const float*)d_in[16];
  const float* ntype_embed = (const float*)d_in[17];
  const float* inithv_w = (const float*)d_in[18];
  const float* inithv_b = (const float*)d_in[19];
  const float* addedge_w = (const float*)d_in[20];
  const float* addedge_b = (const float*)d_in[21];
  const float* dest_w = (const float*)d_in[22];
  const float* dest_b = (const float*)d_in[23];

  float* out = (float*)d_out;
  float* HV = out;
  float* gembed_out = out + (size_t)N_NODES * H;
  float* nodelogp_out = gembed_out + GH;
  float* hvinit_out = nodelogp_out + 4;
  float* edgelogit_out = hvinit_out + H;
  float* destlogp_out = edgelogit_out + 1;

  float* ws = (float*)d_ws;
  float* deg = ws;                                    // N
  float* hesum = deg + N_NODES;                       // N
  float* gi = hesum + N_NODES;                        // N*G3
  float* gh = gi + (size_t)N_NODES * G3;              // N*G3
  float* U = gh + (size_t)N_NODES * G3;               // NT*H
  float* G = U + NT * H;                              // NT
  float* misc = G + NT;                               // 16
  float* scores = misc + 16;                          // N
  int* cnt = (int*)(scores + N_NODES);                // N
  int* rowptr = cnt + N_NODES;                        // N+1
  int* cursor = rowptr + N_NODES + 1;                 // N
  int* nbr = cursor + N_NODES;                        // E
  unsigned short* A_msg =
      (unsigned short*)(((uintptr_t)(nbr + N_EDGES) + 15) & ~(uintptr_t)15);
  unsigned short* HVb = A_msg + (size_t)(N_NODES + 128) * GH;
  unsigned short* a_b = HVb + (size_t)(N_NODES + 128) * H;
  unsigned short* wihb = a_b + (size_t)(N_NODES + 128) * GH;
  unsigned short* whhb = wihb + (size_t)2 * G3 * GH;
  unsigned short* Wmt = whhb + (size_t)2 * G3 * H;

  hipMemcpyAsync(HV, hv0, sizeof(float) * (size_t)N_NODES * H,
                 hipMemcpyDeviceToDevice, stream);

  // ---- weight prep (bf16; msg_w transposed to N x K)
  cast_bf16<<<(2 * G3 * GH + 255) / 256, 256, 0, stream>>>(w_ih, wihb, 2 * G3 * GH);
  cast_bf16<<<(2 * G3 * H + 255) / 256, 256, 0, stream>>>(w_hh, whhb, 2 * G3 * H);
  transpose_cast<<<(512 * 512) / 256, 256, 0, stream>>>(msg_w, Wmt);
  transpose_cast<<<(512 * 512) / 256, 256, 0, stream>>>(msg_w + 513 * 512,
                                                        Wmt + 512 * 512);

  // ---- CSR build
  hipMemsetAsync(hesum, 0, sizeof(float) * N_NODES, stream);
  hipMemsetAsync(cnt, 0, sizeof(int) * N_NODES, stream);
  hist_kernel<<<(N_EDGES + 255) / 256, 256, 0, stream>>>(dst, he, cnt, hesum);
  scan_kernel<<<1, 1024, 0, stream>>>(cnt, rowptr, cursor);
  fill_kernel<<<(N_EDGES + 255) / 256, 256, 0, stream>>>(dst, src, cursor, nbr);

  const int MB = (N_NODES + 127) / 128;  // 157
  for (int t = 0; t < R_ROUNDS; t++) {
    gather_kernel<<<N_NODES / 4, 256, 0, stream>>>(HV, rowptr, nbr, A_msg, HVb, deg);
    mfma_gemm<<<dim3(GH / 128, MB), 256, 0, stream>>>(
        N_NODES, GH, A_msg, Wmt + (size_t)t * GH * GH, msg_b + (size_t)t * GH,
        msg_w + (size_t)t * (2 * H + 1) * GH + (size_t)GH * GH, deg, hesum,
        nullptr, a_b, GH, 1);
    mfma_gemm<<<dim3(G3 / 128, MB), 256, 0, stream>>>(
        N_NODES, GH, a_b, wihb + (size_t)t * G3 * GH, b_ih + (size_t)t * G3,
        nullptr, nullptr, nullptr, gi, nullptr, G3, 0);
    mfma_gemm<<<dim3(G3 / 128, MB), 256, 0, stream>>>(
        N_NODES, H, HVb, whhb + (size_t)t * G3 * H, b_hh + (size_t)t * G3,
        nullptr, nullptr, nullptr, gh, nullptr, G3, 0);
    gru_update<<<(N_NODES * H + 255) / 256, 256, 0, stream>>>(gi, gh, HV);
  }

  // dest head no longer depends on the embed tail (c2 cancels in log_softmax)
  dest_scores_kernel<<<((N_NODES - 1) * 64 + 255) / 256, 256, 0, stream>>>(
      HV, dest_w, scores);
  dest_softmax<<<1, 1024, 0, stream>>>(scores, destlogp_out);

  hipMemsetAsync(U, 0, sizeof(float) * (NT * H + NT), stream);
  embed_phase1<<<128, 256, 0, stream>>>(HV, ntype, gate_w, gate_b, U, G);
  // zero gembed(512) + nodelogp(4) + hvinit(256) + edgelogit(1) in one shot
  hipMemsetAsync(gembed_out, 0, sizeof(float) * (GH + 4 + H + 1), stream);
  gembed_partial<<<48, 256, 0, stream>>>(U, G, tograph_w, tograph_b, gembed_out);
  heads_kernel<<<26, 256, 0, stream>>>(gembed_out, addnode_w, addnode_b, ntype_embed,
                                       inithv_w, inithv_b, addedge_w, addedge_b, HV,
                                       nodelogp_out, hvinit_out, edgelogit_out);
}

// Round 7
// 674.217 us; speedup vs baseline: 1.1778x; 1.0528x over previous
//
#include <hip/hip_runtime.h>
#include <math.h>
#include <stdint.h>

#define N_NODES 20000
#define N_EDGES 320000
#define H 256
#define GH 512
#define G3 768
#define NT 3
#define R_ROUNDS 2

typedef __attribute__((ext_vector_type(8))) short short8;
typedef __attribute__((ext_vector_type(8))) unsigned short ushort8;
typedef __attribute__((ext_vector_type(4))) float floatx4;

static __device__ __forceinline__ unsigned short f2bf(float x) {
  unsigned u = __float_as_uint(x);
  u += 0x7fffu + ((u >> 16) & 1u);
  return (unsigned short)(u >> 16);
}

// ---------------------------------------------------------------- CSR build
__global__ __launch_bounds__(256) void hist_kernel(
    const int* __restrict__ dst, const float* __restrict__ he,
    int* __restrict__ cnt, float* __restrict__ hesum) {
  int e = blockIdx.x * 256 + threadIdx.x;
  if (e >= N_EDGES) return;
  int d = dst[e];
  atomicAdd(&cnt[d], 1);
  unsafeAtomicAdd(&hesum[d], he[e]);
}

__global__ __launch_bounds__(1024) void scan_kernel(
    const int* __restrict__ cnt, int* __restrict__ rowptr, int* __restrict__ cursor) {
  __shared__ int part[1024];
  const int CH = (N_NODES + 1023) / 1024;  // 20
  int t = threadIdx.x;
  int base = t * CH;
  int s = 0;
  for (int j = 0; j < CH; j++) {
    int idx = base + j;
    if (idx < N_NODES) s += cnt[idx];
  }
  part[t] = s;
  __syncthreads();
  int v = part[t];
  for (int off = 1; off < 1024; off <<= 1) {
    int o = (t >= off) ? part[t - off] : 0;
    __syncthreads();
    part[t] += o;
    __syncthreads();
  }
  int excl = part[t] - v;
  int run = excl;
  for (int j = 0; j < CH; j++) {
    int idx = base + j;
    if (idx < N_NODES) {
      rowptr[idx] = run;
      cursor[idx] = run;
      run += cnt[idx];
    }
  }
  if (t == 1023) rowptr[N_NODES] = run;
}

__global__ __launch_bounds__(256) void fill_kernel(
    const int* __restrict__ dst, const int* __restrict__ src,
    int* __restrict__ cursor, int* __restrict__ nbr) {
  int e = blockIdx.x * 256 + threadIdx.x;
  if (e >= N_EDGES) return;
  int p = atomicAdd(&cursor[dst[e]], 1);
  nbr[p] = src[e];
}

// ---------------------------------------------------------------- weight prep
__global__ __launch_bounds__(256) void cast_bf16(const float* __restrict__ in,
                                                 unsigned short* __restrict__ out, int n) {
  int i = blockIdx.x * 256 + threadIdx.x;
  if (i < n) out[i] = f2bf(in[i]);
}

// in: 512x512 (k rows, n cols) -> out[n*512+k] = in[k*512+n]
__global__ __launch_bounds__(256) void transpose_cast(const float* __restrict__ in,
                                                      unsigned short* __restrict__ out) {
  int idx = blockIdx.x * 256 + threadIdx.x;
  int n = idx >> 9, k = idx & 511;
  out[idx] = f2bf(in[k * 512 + n]);
}

// ---------------------------------------------------------------- gather
// A_msg[i] = bf16([deg[i]*hv[i] | sum_nbr hv]); HVb[i] = bf16(hv[i]); deg out.
__global__ __launch_bounds__(256) void gather_kernel(
    const float* __restrict__ hv, const int* __restrict__ rowptr,
    const int* __restrict__ nbr, unsigned short* __restrict__ A_msg,
    unsigned short* __restrict__ HVb, float* __restrict__ deg) {
  int w = (blockIdx.x * blockDim.x + threadIdx.x) >> 6;
  int lane = threadIdx.x & 63;
  if (w >= N_NODES) return;
  int start = rowptr[w], end = rowptr[w + 1];
  float4 acc = make_float4(0.f, 0.f, 0.f, 0.f);
  for (int b = start; b < end; b += 64) {
    int nb = min(64, end - b);
    int sidx = (lane < nb) ? nbr[b + lane] : 0;
    for (int j = 0; j < nb; j++) {
      int s = __shfl(sidx, j);
      const float4 v = *reinterpret_cast<const float4*>(hv + (size_t)s * H + lane * 4);
      acc.x += v.x; acc.y += v.y; acc.z += v.z; acc.w += v.w;
    }
  }
  float dg = (float)(end - start);
  const float4 own = *reinterpret_cast<const float4*>(hv + (size_t)w * H + lane * 4);
  ushort4 o;
  o.x = f2bf(own.x * dg); o.y = f2bf(own.y * dg);
  o.z = f2bf(own.z * dg); o.w = f2bf(own.w * dg);
  *reinterpret_cast<ushort4*>(A_msg + (size_t)w * GH + lane * 4) = o;
  o.x = f2bf(acc.x); o.y = f2bf(acc.y); o.z = f2bf(acc.z); o.w = f2bf(acc.w);
  *reinterpret_cast<ushort4*>(A_msg + (size_t)w * GH + H + lane * 4) = o;
  o.x = f2bf(own.x); o.y = f2bf(own.y); o.z = f2bf(own.z); o.w = f2bf(own.w);
  *reinterpret_cast<ushort4*>(HVb + (size_t)w * H + lane * 4) = o;
  if (lane == 0) deg[w] = dg;
}

// ---------------------------------------------------------------- MFMA GEMM
// C[M x Nc] = A[M x K](bf16) @ W[Nc x K](bf16)^T, 128x128 tile, BK=64.
// mode 0: Cf = acc + bias[col] (fp32); mode 1: Cb = bf16(acc + hesum*we + deg*bias)
__global__ __launch_bounds__(256) void mfma_gemm(
    int M, int K,
    const unsigned short* __restrict__ A, const unsigned short* __restrict__ W,
    const float* __restrict__ bias, const float* __restrict__ we,
    const float* __restrict__ deg, const float* __restrict__ hesum,
    float* __restrict__ Cf, unsigned short* __restrict__ Cb, int ldc, int mode) {
  __shared__ unsigned short As[128 * 88];
  __shared__ unsigned short Bs[128 * 88];
  int t = threadIdx.x;
  size_t i0 = (size_t)blockIdx.y * 128;
  size_t j0 = (size_t)blockIdx.x * 128;
  int wv = t >> 6, lane = t & 63;
  int m0 = (wv >> 1) * 64, n0 = (wv & 1) * 64;
  int lr = lane & 15, lq = lane >> 4;
  int r0 = t >> 3, kc = t & 7;
  floatx4 acc[4][4];
#pragma unroll
  for (int a = 0; a < 4; a++)
#pragma unroll
    for (int b = 0; b < 4; b++) acc[a][b] = (floatx4){0.f, 0.f, 0.f, 0.f};

  for (int k0 = 0; k0 < K; k0 += 64) {
    ushort8 va[4], vb[4];
#pragma unroll
    for (int p = 0; p < 4; p++) {
      va[p] = *(const ushort8*)(A + (i0 + r0 + p * 32) * K + k0 + kc * 8);
      vb[p] = *(const ushort8*)(W + (j0 + r0 + p * 32) * K + k0 + kc * 8);
    }
    __syncthreads();
#pragma unroll
    for (int p = 0; p < 4; p++) {
      *(ushort8*)(As + (r0 + p * 32) * 88 + kc * 8) = va[p];
      *(ushort8*)(Bs + (r0 + p * 32) * 88 + kc * 8) = vb[p];
    }
    __syncthreads();
#pragma unroll
    for (int kk = 0; kk < 2; kk++) {
      short8 af[4], bf[4];
#pragma unroll
      for (int mi = 0; mi < 4; mi++)
        af[mi] = *(const short8*)(As + (m0 + mi * 16 + lr) * 88 + kk * 32 + lq * 8);
#pragma unroll
      for (int ni = 0; ni < 4; ni++)
        bf[ni] = *(const short8*)(Bs + (n0 + ni * 16 + lr) * 88 + kk * 32 + lq * 8);
#pragma unroll
      for (int mi = 0; mi < 4; mi++)
#pragma unroll
        for (int ni = 0; ni < 4; ni++)
          acc[mi][ni] = __builtin_amdgcn_mfma_f32_16x16x32_bf16(af[mi], bf[ni],
                                                                acc[mi][ni], 0, 0, 0);
    }
  }

  if (mode == 0) {
#pragma unroll
    for (int mi = 0; mi < 4; mi++) {
#pragma unroll
      for (int ni = 0; ni < 4; ni++) {
        int col = (int)j0 + n0 + ni * 16 + lr;
        float bv = bias[col];
#pragma unroll
        for (int i = 0; i < 4; i++) {
          size_t row = i0 + m0 + mi * 16 + lq * 4 + i;
          if (row < (size_t)M) Cf[row * ldc + col] = acc[mi][ni][i] + bv;
        }
      }
    }
  } else {
#pragma unroll
    for (int mi = 0; mi < 4; mi++) {
#pragma unroll
      for (int ni = 0; ni < 4; ni++) {
        int col = (int)j0 + n0 + ni * 16 + lr;
        float wv_ = we[col], bv = bias[col];
#pragma unroll
        for (int i = 0; i < 4; i++) {
          size_t row = i0 + m0 + mi * 16 + lq * 4 + i;
          if (row < (size_t)M)
            Cb[row * ldc + col] = f2bf(acc[mi][ni][i] + hesum[row] * wv_ + deg[row] * bv);
        }
      }
    }
  }
}

// ---------------------------------------------------------------- GRU elementwise
__global__ void gru_update(const float* __restrict__ gi, const float* __restrict__ gh,
                           float* __restrict__ hv) {
  int idx = blockIdx.x * blockDim.x + threadIdx.x;
  if (idx >= N_NODES * H) return;
  int row = idx >> 8, col = idx & 255;
  const float* gir = gi + (size_t)row * G3;
  const float* ghr = gh + (size_t)row * G3;
  float ir = gir[col], iz = gir[H + col], inn = gir[2 * H + col];
  float hr = ghr[col], hz = ghr[H + col], hn = ghr[2 * H + col];
  float r = 1.f / (1.f + expf(-(ir + hr)));
  float z = 1.f / (1.f + expf(-(iz + hz)));
  float n = tanhf(inn + r * hn);
  hv[idx] = (1.f - z) * n + z * hv[idx];
}

// ---------------------------------------------------------------- gate pass
// gw[i] = sigmoid(hv[i] . gate_w[ntype[i]] + gate_b[ntype[i]]). One wave per node.
__global__ __launch_bounds__(256) void gate_kernel(
    const float* __restrict__ hv, const int* __restrict__ ntype,
    const float* __restrict__ gate_w, const float* __restrict__ gate_b,
    float* __restrict__ gw) {
  int w = (blockIdx.x * blockDim.x + threadIdx.x) >> 6;
  int lane = threadIdx.x & 63;
  if (w >= N_NODES) return;
  int t = ntype[w];
  float4 h = *reinterpret_cast<const float4*>(hv + (size_t)w * H + lane * 4);
  float4 g = *reinterpret_cast<const float4*>(gate_w + t * H + lane * 4);
  float s = h.x * g.x + h.y * g.y + h.z * g.z + h.w * g.w;
  for (int off = 32; off; off >>= 1) s += __shfl_xor(s, off);
  if (lane == 0) gw[w] = 1.f / (1.f + expf(-(s + gate_b[t])));
}

// ---------------------------------------------------------------- U column-sum
// U[t][col] = sum_{i: ntype=t} gw[i]*hv[i][col]; G[t] = sum gw[i].
// 256 blocks x 256 threads; thread = col, block = row chunk; register accumulators.
__global__ __launch_bounds__(256) void usum_kernel(
    const float* __restrict__ hv, const int* __restrict__ ntype,
    const float* __restrict__ gw, float* __restrict__ U, float* __restrict__ G) {
  const int CH = (N_NODES + 255) / 256;  // 79
  int col = threadIdx.x;
  int r0 = blockIdx.x * CH;
  int r1 = min(r0 + CH, N_NODES);
  float a0 = 0.f, a1 = 0.f, a2 = 0.f;
  float g0 = 0.f, g1 = 0.f, g2 = 0.f;
  int i = r0;
  for (; i + 4 <= r1; i += 4) {
    float v0 = hv[(size_t)(i + 0) * H + col];
    float v1 = hv[(size_t)(i + 1) * H + col];
    float v2 = hv[(size_t)(i + 2) * H + col];
    float v3 = hv[(size_t)(i + 3) * H + col];
    int t0 = ntype[i + 0], t1 = ntype[i + 1], t2 = ntype[i + 2], t3 = ntype[i + 3];
    float w0 = gw[i + 0], w1 = gw[i + 1], w2 = gw[i + 2], w3 = gw[i + 3];
    v0 *= w0; v1 *= w1; v2 *= w2; v3 *= w3;
    a0 += (t0 == 0) ? v0 : 0.f; a1 += (t0 == 1) ? v0 : 0.f; a2 += (t0 == 2) ? v0 : 0.f;
    a0 += (t1 == 0) ? v1 : 0.f; a1 += (t1 == 1) ? v1 : 0.f; a2 += (t1 == 2) ? v1 : 0.f;
    a0 += (t2 == 0) ? v2 : 0.f; a1 += (t2 == 1) ? v2 : 0.f; a2 += (t2 == 2) ? v2 : 0.f;
    a0 += (t3 == 0) ? v3 : 0.f; a1 += (t3 == 1) ? v3 : 0.f; a2 += (t3 == 2) ? v3 : 0.f;
    g0 += (t0 == 0) ? w0 : 0.f; g1 += (t0 == 1) ? w0 : 0.f; g2 += (t0 == 2) ? w0 : 0.f;
    g0 += (t1 == 0) ? w1 : 0.f; g1 += (t1 == 1) ? w1 : 0.f; g2 += (t1 == 2) ? w1 : 0.f;
    g0 += (t2 == 0) ? w2 : 0.f; g1 += (t2 == 1) ? w2 : 0.f; g2 += (t2 == 2) ? w2 : 0.f;
    g0 += (t3 == 0) ? w3 : 0.f; g1 += (t3 == 1) ? w3 : 0.f; g2 += (t3 == 2) ? w3 : 0.f;
  }
  for (; i < r1; i++) {
    float v = hv[(size_t)i * H + col];
    int t = ntype[i];
    float w = gw[i];
    v *= w;
    a0 += (t == 0) ? v : 0.f; a1 += (t == 1) ? v : 0.f; a2 += (t == 2) ? v : 0.f;
    g0 += (t == 0) ? w : 0.f; g1 += (t == 1) ? w : 0.f; g2 += (t == 2) ? w : 0.f;
  }
  unsafeAtomicAdd(&U[0 * H + col], a0);
  unsafeAtomicAdd(&U[1 * H + col], a1);
  unsafeAtomicAdd(&U[2 * H + col], a2);
  if (col == 0) {
    unsafeAtomicAdd(&G[0], g0);
    unsafeAtomicAdd(&G[1], g1);
    unsafeAtomicAdd(&G[2], g2);
  }
}

// ---------------------------------------------------------------- gembed (k-split, MLP)
// grid 48: t = b>>4, half = (b>>3)&1, kc = b&7 (32 k each). 32 independent loads.
__global__ __launch_bounds__(256) void gembed_partial(
    const float* __restrict__ U, const float* __restrict__ G,
    const float* __restrict__ tograph_w, const float* __restrict__ tograph_b,
    float* __restrict__ gembed_out) {
  int b = blockIdx.x;
  int t = b >> 4, half = (b >> 3) & 1, kc = b & 7;
  int col = half * 256 + threadIdx.x;
  int k0 = kc * 32;
  const float* Wt = tograph_w + (size_t)t * H * GH;
  float w[32], u[32];
#pragma unroll
  for (int j = 0; j < 32; j++) w[j] = Wt[(size_t)(k0 + j) * GH + col];
#pragma unroll
  for (int j = 0; j < 32; j++) u[j] = U[t * H + k0 + j];
  float acc = (kc == 0) ? G[t] * tograph_b[t * GH + col] : 0.f;
#pragma unroll
  for (int j = 0; j < 32; j++) acc += u[j] * w[j];
  unsafeAtomicAdd(&gembed_out[col], acc);
}

// ---------------------------------------------------------------- heads (k-split, MLP)
// grid 26: blocks 0..23 = hv_init k-chunks (32 k each); 24 = node logits; 25 = edge_logit.
// NOTE: dest c2 constant cancels in log_softmax -> not computed at all.
__global__ __launch_bounds__(256) void heads_kernel(
    const float* __restrict__ ge, const float* __restrict__ addnode_w,
    const float* __restrict__ addnode_b, const float* __restrict__ ntype_embed,
    const float* __restrict__ inithv_w, const float* __restrict__ inithv_b,
    const float* __restrict__ addedge_w, const float* __restrict__ addedge_b,
    const float* __restrict__ hv, float* __restrict__ nodelogp_out,
    float* __restrict__ hvinit_out, float* __restrict__ edgelogit_out) {
  int b = blockIdx.x;
  int tid = threadIdx.x;
  if (b < 24) {  // hv_init: k in [b*32, b*32+32), col = tid
    int k0 = b * 32;
    float w[32], x[32];
#pragma unroll
    for (int j = 0; j < 32; j++) w[j] = inithv_w[(size_t)(k0 + j) * H + tid];
#pragma unroll
    for (int j = 0; j < 32; j++) {
      int k = k0 + j;
      x[j] = (k < H) ? ntype_embed[k] : ge[k - H];
    }
    float acc = (b == 0) ? inithv_b[tid] : 0.f;
#pragma unroll
    for (int j = 0; j < 32; j++) acc += x[j] * w[j];
    unsafeAtomicAdd(&hvinit_out[tid], acc);
  } else if (b == 24) {  // node logits + log_softmax (4 waves, one per logit)
    __shared__ float lg[4];
    int w = tid >> 6, lane = tid & 63;
    float s = 0.f;
    for (int k = lane; k < GH; k += 64) s += ge[k] * addnode_w[k * 4 + w];
    for (int off = 32; off; off >>= 1) s += __shfl_xor(s, off);
    if (lane == 0) lg[w] = s + addnode_b[w];
    __syncthreads();
    if (tid == 0) {
      float m = fmaxf(fmaxf(lg[0], lg[1]), fmaxf(lg[2], lg[3]));
      float sum = 0.f;
      for (int c = 0; c < 4; c++) sum += expf(lg[c] - m);
      float lse = m + logf(sum);
      for (int c = 0; c < 4; c++) nodelogp_out[c] = lg[c] - lse;
    }
  } else {  // edge_logit (wave 0)
    int w = tid >> 6, lane = tid & 63;
    if (w == 0) {
      const float* se = hv + (size_t)(N_NODES - 1) * H;
      float s = 0.f;
      for (int k = lane; k < G3; k += 64) {
        float x = (k < GH) ? ge[k] : se[k - GH];
        s += x * addedge_w[k];
      }
      for (int off = 32; off; off >>= 1) s += __shfl_xor(s, off);
      if (lane == 0) edgelogit_out[0] = s + addedge_b[0];
    }
  }
}

// ---------------------------------------------------------------- dest scores
// c2 (+dest_b + se.dest_w[256:]) is constant over i and cancels in log_softmax.
__global__ __launch_bounds__(256) void dest_scores_kernel(
    const float* __restrict__ hv, const float* __restrict__ dest_w,
    float* __restrict__ scores) {
  int w = (blockIdx.x * blockDim.x + threadIdx.x) >> 6;
  int lane = threadIdx.x & 63;
  if (w >= N_NODES - 1) return;
  float4 h = *reinterpret_cast<const float4*>(hv + (size_t)w * H + lane * 4);
  float4 d = *reinterpret_cast<const float4*>(dest_w + lane * 4);
  float s = h.x * d.x + h.y * d.y + h.z * d.z + h.w * d.w;
  for (int off = 32; off; off >>= 1) s += __shfl_xor(s, off);
  if (lane == 0) scores[w] = s;
}

__global__ __launch_bounds__(1024) void dest_softmax(const float* __restrict__ scores,
                                                     float* __restrict__ out) {
  const int n = N_NODES - 1;
  __shared__ float red[16];
  __shared__ float bc[2];
  int tid = threadIdx.x;
  float m = -1e30f;
  for (int i = tid; i < n; i += 1024) m = fmaxf(m, scores[i]);
  for (int off = 32; off; off >>= 1) m = fmaxf(m, __shfl_xor(m, off));
  if ((tid & 63) == 0) red[tid >> 6] = m;
  __syncthreads();
  if (tid == 0) {
    float v = red[0];
    for (int i = 1; i < 16; i++) v = fmaxf(v, red[i]);
    bc[0] = v;
  }
  __syncthreads();
  float mx = bc[0];
  float s = 0.f;
  for (int i = tid; i < n; i += 1024) s += expf(scores[i] - mx);
  for (int off = 32; off; off >>= 1) s += __shfl_xor(s, off);
  if ((tid & 63) == 0) red[tid >> 6] = s;
  __syncthreads();
  if (tid == 0) {
    float v = 0.f;
    for (int i = 0; i < 16; i++) v += red[i];
    bc[1] = v;
  }
  __syncthreads();
  float lse = mx + logf(bc[1]);
  for (int i = tid; i < n; i += 1024) out[i] = scores[i] - lse;
}

// ---------------------------------------------------------------- launch
extern "C" void kernel_launch(void* const* d_in, const int* in_sizes, int n_in,
                              void* d_out, int out_size, void* d_ws, size_t ws_size,
                              hipStream_t stream) {
  const float* hv0 = (const float*)d_in[0];
  const float* he = (const float*)d_in[1];
  const int* ntype = (const int*)d_in[2];
  const int* src = (const int*)d_in[3];
  const int* dst = (const int*)d_in[4];
  const float* msg_w = (const float*)d_in[5];
  const float* msg_b = (const float*)d_in[6];
  const float* w_ih = (const float*)d_in[7];
  const float* b_ih = (const float*)d_in[8];
  const float* w_hh = (const float*)d_in[9];
  const float* b_hh = (const float*)d_in[10];
  const float* gate_w = (const float*)d_in[11];
  const float* gate_b = (const float*)d_in[12];
  const float* tograph_w = (const float*)d_in[13];
  const float* tograph_b = (const float*)d_in[14];
  const float* addnode_w = (const float*)d_in[15];
  const float* addnode_b = (const float*)d_in[16];
  const float* ntype_embed = (const float*)d_in[17];
  const float* inithv_w = (const float*)d_in[18];
  const float* inithv_b = (const float*)d_in[19];
  const float* addedge_w = (const float*)d_in[20];
  const float* addedge_b = (const float*)d_in[21];
  const float* dest_w = (const float*)d_in[22];
  const float* dest_b = (const float*)d_in[23];

  float* out = (float*)d_out;
  float* HV = out;
  float* gembed_out = out + (size_t)N_NODES * H;
  float* nodelogp_out = gembed_out + GH;
  float* hvinit_out = nodelogp_out + 4;
  float* edgelogit_out = hvinit_out + H;
  float* destlogp_out = edgelogit_out + 1;

  float* ws = (float*)d_ws;
  float* deg = ws;                                    // N
  float* hesum = deg + N_NODES;                       // N
  float* gi = hesum + N_NODES;                        // N*G3
  float* gh = gi + (size_t)N_NODES * G3;              // N*G3
  float* U = gh + (size_t)N_NODES * G3;               // NT*H
  float* G = U + NT * H;                              // NT
  float* misc = G + NT;                               // 16
  float* scores = misc + 16;                          // N
  float* gw = scores + N_NODES;                       // N
  int* cnt = (int*)(gw + N_NODES);                    // N
  int* rowptr = cnt + N_NODES;                        // N+1
  int* cursor = rowptr + N_NODES + 1;                 // N
  int* nbr = cursor + N_NODES;                        // E
  unsigned short* A_msg =
      (unsigned short*)(((uintptr_t)(nbr + N_EDGES) + 15) & ~(uintptr_t)15);
  unsigned short* HVb = A_msg + (size_t)(N_NODES + 128) * GH;
  unsigned short* a_b = HVb + (size_t)(N_NODES + 128) * H;
  unsigned short* wihb = a_b + (size_t)(N_NODES + 128) * GH;
  unsigned short* whhb = wihb + (size_t)2 * G3 * GH;
  unsigned short* Wmt = whhb + (size_t)2 * G3 * H;

  hipMemcpyAsync(HV, hv0, sizeof(float) * (size_t)N_NODES * H,
                 hipMemcpyDeviceToDevice, stream);

  // ---- weight prep (bf16; msg_w transposed to N x K)
  cast_bf16<<<(2 * G3 * GH + 255) / 256, 256, 0, stream>>>(w_ih, wihb, 2 * G3 * GH);
  cast_bf16<<<(2 * G3 * H + 255) / 256, 256, 0, stream>>>(w_hh, whhb, 2 * G3 * H);
  transpose_cast<<<(512 * 512) / 256, 256, 0, stream>>>(msg_w, Wmt);
  transpose_cast<<<(512 * 512) / 256, 256, 0, stream>>>(msg_w + 513 * 512,
                                                        Wmt + 512 * 512);

  // ---- CSR build
  hipMemsetAsync(hesum, 0, sizeof(float) * N_NODES, stream);
  hipMemsetAsync(cnt, 0, sizeof(int) * N_NODES, stream);
  hist_kernel<<<(N_EDGES + 255) / 256, 256, 0, stream>>>(dst, he, cnt, hesum);
  scan_kernel<<<1, 1024, 0, stream>>>(cnt, rowptr, cursor);
  fill_kernel<<<(N_EDGES + 255) / 256, 256, 0, stream>>>(dst, src, cursor, nbr);

  const int MB = (N_NODES + 127) / 128;  // 157
  for (int t = 0; t < R_ROUNDS; t++) {
    gather_kernel<<<N_NODES / 4, 256, 0, stream>>>(HV, rowptr, nbr, A_msg, HVb, deg);
    mfma_gemm<<<dim3(GH / 128, MB), 256, 0, stream>>>(
        N_NODES, GH, A_msg, Wmt + (size_t)t * GH * GH, msg_b + (size_t)t * GH,
        msg_w + (size_t)t * (2 * H + 1) * GH + (size_t)GH * GH, deg, hesum,
        nullptr, a_b, GH, 1);
    mfma_gemm<<<dim3(G3 / 128, MB), 256, 0, stream>>>(
        N_NODES, GH, a_b, wihb + (size_t)t * G3 * GH, b_ih + (size_t)t * G3,
        nullptr, nullptr, nullptr, gi, nullptr, G3, 0);
    mfma_gemm<<<dim3(G3 / 128, MB), 256, 0, stream>>>(
        N_NODES, H, HVb, whhb + (size_t)t * G3 * H, b_hh + (size_t)t * G3,
        nullptr, nullptr, nullptr, gh, nullptr, G3, 0);
    gru_update<<<(N_NODES * H + 255) / 256, 256, 0, stream>>>(gi, gh, HV);
  }

  // dest head no longer depends on the embed tail (c2 cancels in log_softmax)
  dest_scores_kernel<<<((N_NODES - 1) * 64 + 255) / 256, 256, 0, stream>>>(
      HV, dest_w, scores);
  dest_softmax<<<1, 1024, 0, stream>>>(scores, destlogp_out);

  // ---- graph embed: gate pass + column-sum (no LDS atomics, no contention)
  hipMemsetAsync(U, 0, sizeof(float) * (NT * H + NT), stream);
  gate_kernel<<<(N_NODES * 64 + 255) / 256, 256, 0, stream>>>(HV, ntype, gate_w,
                                                              gate_b, gw);
  usum_kernel<<<256, 256, 0, stream>>>(HV, ntype, gw, U, G);
  // zero gembed(512) + nodelogp(4) + hvinit(256) + edgelogit(1) in one shot
  hipMemsetAsync(gembed_out, 0, sizeof(float) * (GH + 4 + H + 1), stream);
  gembed_partial<<<48, 256, 0, stream>>>(U, G, tograph_w, tograph_b, gembed_out);
  heads_kernel<<<26, 256, 0, stream>>>(gembed_out, addnode_w, addnode_b, ntype_embed,
                                       inithv_w, inithv_b, addedge_w, addedge_b, HV,
                                       nodelogp_out, hvinit_out, edgelogit_out);
}

// Round 9
// 638.315 us; speedup vs baseline: 1.2441x; 1.0562x over previous
//
#include <hip/hip_runtime.h>
#include <math.h>
#include <stdint.h>

#define N_NODES 20000
#define N_EDGES 320000
#define H 256
#define GH 512
#define G3 768
#define NT 3
#define R_ROUNDS 2
#define LDSW 72  // LDS row stride in shorts (64 data + 8 pad; 144B, 2-way-free)

typedef __attribute__((ext_vector_type(8))) short short8;
typedef __attribute__((ext_vector_type(8))) unsigned short ushort8;
typedef __attribute__((ext_vector_type(4))) float floatx4;

static __device__ __forceinline__ unsigned short f2bf(float x) {
  unsigned u = __float_as_uint(x);
  u += 0x7fffu + ((u >> 16) & 1u);
  return (unsigned short)(u >> 16);
}
static __device__ __forceinline__ float b2f(unsigned short x) {
  return __uint_as_float((unsigned)x << 16);
}

// ---------------------------------------------------------------- CSR build
__global__ __launch_bounds__(256) void hist_kernel(
    const int* __restrict__ dst, const float* __restrict__ he,
    int* __restrict__ cnt, float* __restrict__ hesum) {
  int e = blockIdx.x * 256 + threadIdx.x;
  if (e >= N_EDGES) return;
  int d = dst[e];
  atomicAdd(&cnt[d], 1);
  unsafeAtomicAdd(&hesum[d], he[e]);
}

__global__ __launch_bounds__(1024) void scan_kernel(
    const int* __restrict__ cnt, int* __restrict__ rowptr, int* __restrict__ cursor) {
  __shared__ int part[1024];
  const int CH = (N_NODES + 1023) / 1024;  // 20
  int t = threadIdx.x;
  int base = t * CH;
  int s = 0;
  for (int j = 0; j < CH; j++) {
    int idx = base + j;
    if (idx < N_NODES) s += cnt[idx];
  }
  part[t] = s;
  __syncthreads();
  int v = part[t];
  for (int off = 1; off < 1024; off <<= 1) {
    int o = (t >= off) ? part[t - off] : 0;
    __syncthreads();
    part[t] += o;
    __syncthreads();
  }
  int excl = part[t] - v;
  int run = excl;
  for (int j = 0; j < CH; j++) {
    int idx = base + j;
    if (idx < N_NODES) {
      rowptr[idx] = run;
      cursor[idx] = run;
      run += cnt[idx];
    }
  }
  if (t == 1023) rowptr[N_NODES] = run;
}

__global__ __launch_bounds__(256) void fill_kernel(
    const int* __restrict__ dst, const int* __restrict__ src,
    int* __restrict__ cursor, int* __restrict__ nbr) {
  int e = blockIdx.x * 256 + threadIdx.x;
  if (e >= N_EDGES) return;
  int p = atomicAdd(&cursor[dst[e]], 1);
  nbr[p] = src[e];
}

// ---------------------------------------------------------------- weight prep
__global__ __launch_bounds__(256) void cast_bf16(const float* __restrict__ in,
                                                 unsigned short* __restrict__ out, int n) {
  int i = blockIdx.x * 256 + threadIdx.x;
  if (i < n) out[i] = f2bf(in[i]);
}

// in: 512x512 (k rows, n cols) -> out[n*512+k] = in[k*512+n]
__global__ __launch_bounds__(256) void transpose_cast(const float* __restrict__ in,
                                                      unsigned short* __restrict__ out) {
  int idx = blockIdx.x * 256 + threadIdx.x;
  int n = idx >> 9, k = idx & 511;
  out[idx] = f2bf(in[k * 512 + n]);
}

// ---------------------------------------------------------------- gather
__global__ __launch_bounds__(256) void gather_kernel(
    const float* __restrict__ hv, const int* __restrict__ rowptr,
    const int* __restrict__ nbr, unsigned short* __restrict__ A_msg,
    unsigned short* __restrict__ HVb, float* __restrict__ deg) {
  int w = (blockIdx.x * blockDim.x + threadIdx.x) >> 6;
  int lane = threadIdx.x & 63;
  if (w >= N_NODES) return;
  int start = rowptr[w], end = rowptr[w + 1];
  float4 acc = make_float4(0.f, 0.f, 0.f, 0.f);
  for (int b = start; b < end; b += 64) {
    int nb = min(64, end - b);
    int sidx = (lane < nb) ? nbr[b + lane] : 0;
    for (int j = 0; j < nb; j++) {
      int s = __shfl(sidx, j);
      const float4 v = *reinterpret_cast<const float4*>(hv + (size_t)s * H + lane * 4);
      acc.x += v.x; acc.y += v.y; acc.z += v.z; acc.w += v.w;
    }
  }
  float dg = (float)(end - start);
  const float4 own = *reinterpret_cast<const float4*>(hv + (size_t)w * H + lane * 4);
  ushort4 o;
  o.x = f2bf(own.x * dg); o.y = f2bf(own.y * dg);
  o.z = f2bf(own.z * dg); o.w = f2bf(own.w * dg);
  *reinterpret_cast<ushort4*>(A_msg + (size_t)w * GH + lane * 4) = o;
  o.x = f2bf(acc.x); o.y = f2bf(acc.y); o.z = f2bf(acc.z); o.w = f2bf(acc.w);
  *reinterpret_cast<ushort4*>(A_msg + (size_t)w * GH + H + lane * 4) = o;
  o.x = f2bf(own.x); o.y = f2bf(own.y); o.z = f2bf(own.z); o.w = f2bf(own.w);
  *reinterpret_cast<ushort4*>(HVb + (size_t)w * H + lane * 4) = o;
  if (lane == 0) deg[w] = dg;
}

// ---------------------------------------------------------------- GEMM core macro
// 128x128 tile, BK=64, prefetched staging (loads for k+1 issued before MFMA of k).
#define GEMM_CORE(A, W, K)                                                        \
  {                                                                               \
    ushort8 va[4], vb[4];                                                         \
    _Pragma("unroll") for (int p = 0; p < 4; p++) {                               \
      va[p] = *(const ushort8*)((A) + (i0 + r0 + p * 32) * (K) + kc * 8);         \
      vb[p] = *(const ushort8*)((W) + (j0 + r0 + p * 32) * (K) + kc * 8);         \
    }                                                                             \
    for (int k0 = 0; k0 < (K); k0 += 64) {                                        \
      __syncthreads();                                                            \
      _Pragma("unroll") for (int p = 0; p < 4; p++) {                             \
        *(ushort8*)(As + (r0 + p * 32) * LDSW + kc * 8) = va[p];                  \
        *(ushort8*)(Bs + (r0 + p * 32) * LDSW + kc * 8) = vb[p];                  \
      }                                                                           \
      __syncthreads();                                                            \
      if (k0 + 64 < (K)) {                                                        \
        int kn = k0 + 64;                                                         \
        _Pragma("unroll") for (int p = 0; p < 4; p++) {                           \
          va[p] = *(const ushort8*)((A) + (i0 + r0 + p * 32) * (K) + kn + kc * 8);\
          vb[p] = *(const ushort8*)((W) + (j0 + r0 + p * 32) * (K) + kn + kc * 8);\
        }                                                                         \
      }                                                                           \
      _Pragma("unroll") for (int kk = 0; kk < 2; kk++) {                          \
        short8 af[4], bf[4];                                                      \
        _Pragma("unroll") for (int mi = 0; mi < 4; mi++)                          \
          af[mi] = *(const short8*)(As + (m0 + mi * 16 + lr) * LDSW + kk * 32 + lq * 8); \
        _Pragma("unroll") for (int ni = 0; ni < 4; ni++)                          \
          bf[ni] = *(const short8*)(Bs + (n0 + ni * 16 + lr) * LDSW + kk * 32 + lq * 8); \
        _Pragma("unroll") for (int mi = 0; mi < 4; mi++)                          \
          _Pragma("unroll") for (int ni = 0; ni < 4; ni++)                        \
            acc[mi][ni] = __builtin_amdgcn_mfma_f32_16x16x32_bf16(af[mi], bf[ni], \
                                                                  acc[mi][ni], 0, 0, 0); \
      }                                                                           \
    }                                                                             \
  }

// ---------------------------------------------------------------- merged msg + gh GEMM
// blockIdx.x 0..3: a = [deg*hv|S]@Wm + hesum*we + deg*bm -> a_b (bf16, ldc GH)
// blockIdx.x 4..9: gh = HVb@Whh^T + bhh -> ghb (bf16, ldc G3)
__global__ __launch_bounds__(256) void msg_gh_gemm(
    const unsigned short* __restrict__ A_msg, const unsigned short* __restrict__ Wm,
    const float* __restrict__ msg_bias, const float* __restrict__ we,
    const float* __restrict__ deg, const float* __restrict__ hesum,
    unsigned short* __restrict__ a_b, const unsigned short* __restrict__ HVb,
    const unsigned short* __restrict__ Whh, const float* __restrict__ bhh,
    unsigned short* __restrict__ ghb) {
  __shared__ unsigned short As[128 * LDSW];
  __shared__ unsigned short Bs[128 * LDSW];
  bool is_msg = blockIdx.x < 4;
  int t = threadIdx.x;
  size_t i0 = (size_t)blockIdx.y * 128;
  size_t j0 = is_msg ? (size_t)blockIdx.x * 128 : (size_t)(blockIdx.x - 4) * 128;
  int wv = t >> 6, lane = t & 63;
  int m0 = (wv >> 1) * 64, n0 = (wv & 1) * 64;
  int lr = lane & 15, lq = lane >> 4;
  int r0 = t >> 3, kc = t & 7;
  floatx4 acc[4][4];
#pragma unroll
  for (int a = 0; a < 4; a++)
#pragma unroll
    for (int b = 0; b < 4; b++) acc[a][b] = (floatx4){0.f, 0.f, 0.f, 0.f};

  if (is_msg) {
    GEMM_CORE(A_msg, Wm, GH)
#pragma unroll
    for (int mi = 0; mi < 4; mi++) {
#pragma unroll
      for (int ni = 0; ni < 4; ni++) {
        int col = (int)j0 + n0 + ni * 16 + lr;
        float wv_ = we[col], bv = msg_bias[col];
#pragma unroll
        for (int i = 0; i < 4; i++) {
          size_t row = i0 + m0 + mi * 16 + lq * 4 + i;
          if (row < (size_t)N_NODES)
            a_b[row * GH + col] = f2bf(acc[mi][ni][i] + hesum[row] * wv_ + deg[row] * bv);
        }
      }
    }
  } else {
    GEMM_CORE(HVb, Whh, H)
#pragma unroll
    for (int mi = 0; mi < 4; mi++) {
#pragma unroll
      for (int ni = 0; ni < 4; ni++) {
        int col = (int)j0 + n0 + ni * 16 + lr;
        float bv = bhh[col];
#pragma unroll
        for (int i = 0; i < 4; i++) {
          size_t row = i0 + m0 + mi * 16 + lq * 4 + i;
          if (row < (size_t)N_NODES) ghb[row * G3 + col] = f2bf(acc[mi][ni][i] + bv);
        }
      }
    }
  }
}

// ---------------------------------------------------------------- gi GEMM (bf16 out)
__global__ __launch_bounds__(256) void mfma_gemm(
    const unsigned short* __restrict__ A, const unsigned short* __restrict__ W,
    const float* __restrict__ bias, unsigned short* __restrict__ Cb) {
  __shared__ unsigned short As[128 * LDSW];
  __shared__ unsigned short Bs[128 * LDSW];
  int t = threadIdx.x;
  size_t i0 = (size_t)blockIdx.y * 128;
  size_t j0 = (size_t)blockIdx.x * 128;
  int wv = t >> 6, lane = t & 63;
  int m0 = (wv >> 1) * 64, n0 = (wv & 1) * 64;
  int lr = lane & 15, lq = lane >> 4;
  int r0 = t >> 3, kc = t & 7;
  floatx4 acc[4][4];
#pragma unroll
  for (int a = 0; a < 4; a++)
#pragma unroll
    for (int b = 0; b < 4; b++) acc[a][b] = (floatx4){0.f, 0.f, 0.f, 0.f};

  GEMM_CORE(A, W, GH)
#pragma unroll
  for (int mi = 0; mi < 4; mi++) {
#pragma unroll
    for (int ni = 0; ni < 4; ni++) {
      int col = (int)j0 + n0 + ni * 16 + lr;
      float bv = bias[col];
#pragma unroll
      for (int i = 0; i < 4; i++) {
        size_t row = i0 + m0 + mi * 16 + lq * 4 + i;
        if (row < (size_t)N_NODES) Cb[row * G3 + col] = f2bf(acc[mi][ni][i] + bv);
      }
    }
  }
}

// ---------------------------------------------------------------- GRU elementwise (bf16 in)
__global__ __launch_bounds__(256) void gru_update(const unsigned short* __restrict__ gi,
                                                  const unsigned short* __restrict__ gh,
                                                  float* __restrict__ hv) {
  int idx = blockIdx.x * 256 + threadIdx.x;
  if (idx >= N_NODES * 32) return;
  int row = idx >> 5;
  int c8 = (idx & 31) << 3;
  const unsigned short* gir = gi + (size_t)row * G3;
  const unsigned short* ghr = gh + (size_t)row * G3;
  ushort8 vir = *(const ushort8*)(gir + c8);
  ushort8 viz = *(const ushort8*)(gir + H + c8);
  ushort8 vin = *(const ushort8*)(gir + 2 * H + c8);
  ushort8 vhr = *(const ushort8*)(ghr + c8);
  ushort8 vhz = *(const ushort8*)(ghr + H + c8);
  ushort8 vhn = *(const ushort8*)(ghr + 2 * H + c8);
  float* hp = hv + (size_t)row * H + c8;
  float4 h0 = *(float4*)hp;
  float4 h1 = *(float4*)(hp + 4);
  float hvv[8] = {h0.x, h0.y, h0.z, h0.w, h1.x, h1.y, h1.z, h1.w};
#pragma unroll
  for (int j = 0; j < 8; j++) {
    float r = 1.f / (1.f + expf(-(b2f(vir[j]) + b2f(vhr[j]))));
    float z = 1.f / (1.f + expf(-(b2f(viz[j]) + b2f(vhz[j]))));
    float n = tanhf(b2f(vin[j]) + r * b2f(vhn[j]));
    hvv[j] = (1.f - z) * n + z * hvv[j];
  }
  *(float4*)hp = make_float4(hvv[0], hvv[1], hvv[2], hvv[3]);
  *(float4*)(hp + 4) = make_float4(hvv[4], hvv[5], hvv[6], hvv[7]);
}

// ---------------------------------------------------------------- gate pass
__global__ __launch_bounds__(256) void gate_kernel(
    const float* __restrict__ hv, const int* __restrict__ ntype,
    const float* __restrict__ gate_w, const float* __restrict__ gate_b,
    float* __restrict__ gw) {
  int w = (blockIdx.x * blockDim.x + threadIdx.x) >> 6;
  int lane = threadIdx.x & 63;
  if (w >= N_NODES) return;
  int t = ntype[w];
  float4 h = *reinterpret_cast<const float4*>(hv + (size_t)w * H + lane * 4);
  float4 g = *reinterpret_cast<const float4*>(gate_w + t * H + lane * 4);
  float s = h.x * g.x + h.y * g.y + h.z * g.z + h.w * g.w;
  for (int off = 32; off; off >>= 1) s += __shfl_xor(s, off);
  if (lane == 0) gw[w] = 1.f / (1.f + expf(-(s + gate_b[t])));
}

// ---------------------------------------------------------------- U column-sum
__global__ __launch_bounds__(256) void usum_kernel(
    const float* __restrict__ hv, const int* __restrict__ ntype,
    const float* __restrict__ gw, float* __restrict__ U, float* __restrict__ G) {
  const int CH = (N_NODES + 255) / 256;  // 79
  int col = threadIdx.x;
  int r0 = blockIdx.x * CH;
  int r1 = min(r0 + CH, N_NODES);
  float a0 = 0.f, a1 = 0.f, a2 = 0.f;
  float g0 = 0.f, g1 = 0.f, g2 = 0.f;
  int i = r0;
  for (; i + 4 <= r1; i += 4) {
    float v0 = hv[(size_t)(i + 0) * H + col];
    float v1 = hv[(size_t)(i + 1) * H + col];
    float v2 = hv[(size_t)(i + 2) * H + col];
    float v3 = hv[(size_t)(i + 3) * H + col];
    int t0 = ntype[i + 0], t1 = ntype[i + 1], t2 = ntype[i + 2], t3 = ntype[i + 3];
    float w0 = gw[i + 0], w1 = gw[i + 1], w2 = gw[i + 2], w3 = gw[i + 3];
    v0 *= w0; v1 *= w1; v2 *= w2; v3 *= w3;
    a0 += (t0 == 0) ? v0 : 0.f; a1 += (t0 == 1) ? v0 : 0.f; a2 += (t0 == 2) ? v0 : 0.f;
    a0 += (t1 == 0) ? v1 : 0.f; a1 += (t1 == 1) ? v1 : 0.f; a2 += (t1 == 2) ? v1 : 0.f;
    a0 += (t2 == 0) ? v2 : 0.f; a1 += (t2 == 1) ? v2 : 0.f; a2 += (t2 == 2) ? v2 : 0.f;
    a0 += (t3 == 0) ? v3 : 0.f; a1 += (t3 == 1) ? v3 : 0.f; a2 += (t3 == 2) ? v3 : 0.f;
    g0 += (t0 == 0) ? w0 : 0.f; g1 += (t0 == 1) ? w0 : 0.f; g2 += (t0 == 2) ? w0 : 0.f;
    g0 += (t1 == 0) ? w1 : 0.f; g1 += (t1 == 1) ? w1 : 0.f; g2 += (t1 == 2) ? w1 : 0.f;
    g0 += (t2 == 0) ? w2 : 0.f; g1 += (t2 == 1) ? w2 : 0.f; g2 += (t2 == 2) ? w2 : 0.f;
    g0 += (t3 == 0) ? w3 : 0.f; g1 += (t3 == 1) ? w3 : 0.f; g2 += (t3 == 2) ? w3 : 0.f;
  }
  for (; i < r1; i++) {
    float v = hv[(size_t)i * H + col];
    int t = ntype[i];
    float w = gw[i];
    v *= w;
    a0 += (t == 0) ? v : 0.f; a1 += (t == 1) ? v : 0.f; a2 += (t == 2) ? v : 0.f;
    g0 += (t == 0) ? w : 0.f; g1 += (t == 1) ? w : 0.f; g2 += (t == 2) ? w : 0.f;
  }
  unsafeAtomicAdd(&U[0 * H + col], a0);
  unsafeAtomicAdd(&U[1 * H + col], a1);
  unsafeAtomicAdd(&U[2 * H + col], a2);
  if (col == 0) {
    unsafeAtomicAdd(&G[0], g0);
    unsafeAtomicAdd(&G[1], g1);
    unsafeAtomicAdd(&G[2], g2);
  }
}

// ---------------------------------------------------------------- gembed (k-split, MLP)
__global__ __launch_bounds__(256) void gembed_partial(
    const float* __restrict__ U, const float* __restrict__ G,
    const float* __restrict__ tograph_w, const float* __restrict__ tograph_b,
    float* __restrict__ gembed_out) {
  int b = blockIdx.x;
  int t = b >> 4, half = (b >> 3) & 1, kc = b & 7;
  int col = half * 256 + threadIdx.x;
  int k0 = kc * 32;
  const float* Wt = tograph_w + (size_t)t * H * GH;
  float w[32], u[32];
#pragma unroll
  for (int j = 0; j < 32; j++) w[j] = Wt[(size_t)(k0 + j) * GH + col];
#pragma unroll
  for (int j = 0; j < 32; j++) u[j] = U[t * H + k0 + j];
  float acc = (kc == 0) ? G[t] * tograph_b[t * GH + col] : 0.f;
#pragma unroll
  for (int j = 0; j < 32; j++) acc += u[j] * w[j];
  unsafeAtomicAdd(&gembed_out[col], acc);
}

// ---------------------------------------------------------------- heads (k-split, MLP)
__global__ __launch_bounds__(256) void heads_kernel(
    const float* __restrict__ ge, const float* __restrict__ addnode_w,
    const float* __restrict__ addnode_b, const float* __restrict__ ntype_embed,
    const float* __restrict__ inithv_w, const float* __restrict__ inithv_b,
    const float* __restrict__ addedge_w, const float* __restrict__ addedge_b,
    const float* __restrict__ hv, float* __restrict__ nodelogp_out,
    float* __restrict__ hvinit_out, float* __restrict__ edgelogit_out) {
  int b = blockIdx.x;
  int tid = threadIdx.x;
  if (b < 24) {
    int k0 = b * 32;
    float w[32], x[32];
#pragma unroll
    for (int j = 0; j < 32; j++) w[j] = inithv_w[(size_t)(k0 + j) * H + tid];
#pragma unroll
    for (int j = 0; j < 32; j++) {
      int k = k0 + j;
      x[j] = (k < H) ? ntype_embed[k] : ge[k - H];
    }
    float acc = (b == 0) ? inithv_b[tid] : 0.f;
#pragma unroll
    for (int j = 0; j < 32; j++) acc += x[j] * w[j];
    unsafeAtomicAdd(&hvinit_out[tid], acc);
  } else if (b == 24) {
    __shared__ float lg[4];
    int w = tid >> 6, lane = tid & 63;
    float s = 0.f;
    for (int k = lane; k < GH; k += 64) s += ge[k] * addnode_w[k * 4 + w];
    for (int off = 32; off; off >>= 1) s += __shfl_xor(s, off);
    if (lane == 0) lg[w] = s + addnode_b[w];
    __syncthreads();
    if (tid == 0) {
      float m = fmaxf(fmaxf(lg[0], lg[1]), fmaxf(lg[2], lg[3]));
      float sum = 0.f;
      for (int c = 0; c < 4; c++) sum += expf(lg[c] - m);
      float lse = m + logf(sum);
      for (int c = 0; c < 4; c++) nodelogp_out[c] = lg[c] - lse;
    }
  } else {
    int w = tid >> 6, lane = tid & 63;
    if (w == 0) {
      const float* se = hv + (size_t)(N_NODES - 1) * H;
      float s = 0.f;
      for (int k = lane; k < G3; k += 64) {
        float x = (k < GH) ? ge[k] : se[k - GH];
        s += x * addedge_w[k];
      }
      for (int off = 32; off; off >>= 1) s += __shfl_xor(s, off);
      if (lane == 0) edgelogit_out[0] = s + addedge_b[0];
    }
  }
}

// ---------------------------------------------------------------- dest scores
__global__ __launch_bounds__(256) void dest_scores_kernel(
    const float* __restrict__ hv, const float* __restrict__ dest_w,
    float* __restrict__ scores) {
  int w = (blockIdx.x * blockDim.x + threadIdx.x) >> 6;
  int lane = threadIdx.x & 63;
  if (w >= N_NODES - 1) return;
  float4 h = *reinterpret_cast<const float4*>(hv + (size_t)w * H + lane * 4);
  float4 d = *reinterpret_cast<const float4*>(dest_w + lane * 4);
  float s = h.x * d.x + h.y * d.y + h.z * d.z + h.w * d.w;
  for (int off = 32; off; off >>= 1) s += __shfl_xor(s, off);
  if (lane == 0) scores[w] = s;
}

__global__ __launch_bounds__(1024) void dest_softmax(const float* __restrict__ scores,
                                                     float* __restrict__ out) {
  const int n = N_NODES - 1;
  __shared__ float red[16];
  __shared__ float bc[2];
  int tid = threadIdx.x;
  float m = -1e30f;
  for (int i = tid; i < n; i += 1024) m = fmaxf(m, scores[i]);
  for (int off = 32; off; off >>= 1) m = fmaxf(m, __shfl_xor(m, off));
  if ((tid & 63) == 0) red[tid >> 6] = m;
  __syncthreads();
  if (tid == 0) {
    float v = red[0];
    for (int i = 1; i < 16; i++) v = fmaxf(v, red[i]);
    bc[0] = v;
  }
  __syncthreads();
  float mx = bc[0];
  float s = 0.f;
  for (int i = tid; i < n; i += 1024) s += expf(scores[i] - mx);
  for (int off = 32; off; off >>= 1) s += __shfl_xor(s, off);
  if ((tid & 63) == 0) red[tid >> 6] = s;
  __syncthreads();
  if (tid == 0) {
    float v = 0.f;
    for (int i = 0; i < 16; i++) v += red[i];
    bc[1] = v;
  }
  __syncthreads();
  float lse = mx + logf(bc[1]);
  for (int i = tid; i < n; i += 1024) out[i] = scores[i] - lse;
}

// ---------------------------------------------------------------- launch
extern "C" void kernel_launch(void* const* d_in, const int* in_sizes, int n_in,
                              void* d_out, int out_size, void* d_ws, size_t ws_size,
                              hipStream_t stream) {
  const float* hv0 = (const float*)d_in[0];
  const float* he = (const float*)d_in[1];
  const int* ntype = (const int*)d_in[2];
  const int* src = (const int*)d_in[3];
  const int* dst = (const int*)d_in[4];
  const float* msg_w = (const float*)d_in[5];
  const float* msg_b = (const float*)d_in[6];
  const float* w_ih = (const float*)d_in[7];
  const float* b_ih = (const float*)d_in[8];
  const float* w_hh = (const float*)d_in[9];
  const float* b_hh = (const float*)d_in[10];
  const float* gate_w = (const float*)d_in[11];
  const float* gate_b = (const float*)d_in[12];
  const float* tograph_w = (const float*)d_in[13];
  const float* tograph_b = (const float*)d_in[14];
  const float* addnode_w = (const float*)d_in[15];
  const float* addnode_b = (const float*)d_in[16];
  const float* ntype_embed = (const float*)d_in[17];
  const float* inithv_w = (const float*)d_in[18];
  const float* inithv_b = (const float*)d_in[19];
  const float* addedge_w = (const float*)d_in[20];
  const float* addedge_b = (const float*)d_in[21];
  const float* dest_w = (const float*)d_in[22];
  const float* dest_b = (const float*)d_in[23];

  float* out = (float*)d_out;
  float* HV = out;
  float* gembed_out = out + (size_t)N_NODES * H;
  float* nodelogp_out = gembed_out + GH;
  float* hvinit_out = nodelogp_out + 4;
  float* edgelogit_out = hvinit_out + H;
  float* destlogp_out = edgelogit_out + 1;

  float* ws = (float*)d_ws;
  float* deg = ws;                                    // N
  float* hesum = deg + N_NODES;                       // N
  float* U = hesum + N_NODES;                         // NT*H
  float* G = U + NT * H;                              // NT
  float* misc = G + NT;                               // 16
  float* scores = misc + 16;                          // N
  float* gw = scores + N_NODES;                       // N
  int* cnt = (int*)(gw + N_NODES);                    // N
  int* rowptr = cnt + N_NODES;                        // N+1
  int* cursor = rowptr + N_NODES + 1;                 // N
  int* nbr = cursor + N_NODES;                        // E
  unsigned short* A_msg =
      (unsigned short*)(((uintptr_t)(nbr + N_EDGES) + 15) & ~(uintptr_t)15);
  unsigned short* HVb = A_msg + (size_t)(N_NODES + 128) * GH;
  unsigned short* a_b = HVb + (size_t)(N_NODES + 128) * H;
  unsigned short* gib = a_b + (size_t)(N_NODES + 128) * GH;
  unsigned short* ghb = gib + (size_t)(N_NODES + 128) * G3;
  unsigned short* wihb = ghb + (size_t)(N_NODES + 128) * G3;
  unsigned short* whhb = wihb + (size_t)2 * G3 * GH;
  unsigned short* Wmt = whhb + (size_t)2 * G3 * H;

  hipMemcpyAsync(HV, hv0, sizeof(float) * (size_t)N_NODES * H,
                 hipMemcpyDeviceToDevice, stream);

  // ---- weight prep (bf16; msg_w transposed to N x K)
  cast_bf16<<<(2 * G3 * GH + 255) / 256, 256, 0, stream>>>(w_ih, wihb, 2 * G3 * GH);
  cast_bf16<<<(2 * G3 * H + 255) / 256, 256, 0, stream>>>(w_hh, whhb, 2 * G3 * H);
  transpose_cast<<<(512 * 512) / 256, 256, 0, stream>>>(msg_w, Wmt);
  transpose_cast<<<(512 * 512) / 256, 256, 0, stream>>>(msg_w + 513 * 512,
                                                        Wmt + 512 * 512);

  // ---- CSR build
  hipMemsetAsync(hesum, 0, sizeof(float) * N_NODES, stream);
  hipMemsetAsync(cnt, 0, sizeof(int) * N_NODES, stream);
  hist_kernel<<<(N_EDGES + 255) / 256, 256, 0, stream>>>(dst, he, cnt, hesum);
  scan_kernel<<<1, 1024, 0, stream>>>(cnt, rowptr, cursor);
  fill_kernel<<<(N_EDGES + 255) / 256, 256, 0, stream>>>(dst, src, cursor, nbr);

  const int MB = (N_NODES + 127) / 128;  // 157
  for (int t = 0; t < R_ROUNDS; t++) {
    gather_kernel<<<N_NODES / 4, 256, 0, stream>>>(HV, rowptr, nbr, A_msg, HVb, deg);
    // msg + gh merged (both depend only on gather outputs)
    msg_gh_gemm<<<dim3(10, MB), 256, 0, stream>>>(
        A_msg, Wmt + (size_t)t * GH * GH, msg_b + (size_t)t * GH,
        msg_w + (size_t)t * (2 * H + 1) * GH + (size_t)GH * GH, deg, hesum, a_b,
        HVb, whhb + (size_t)t * G3 * H, b_hh + (size_t)t * G3, ghb);
    // gi = a @ w_ih^T + b_ih (bf16 out)
    mfma_gemm<<<dim3(G3 / 128, MB), 256, 0, stream>>>(
        a_b, wihb + (size_t)t * G3 * GH, b_ih + (size_t)t * G3, gib);
    gru_update<<<(N_NODES * 32 + 255) / 256, 256, 0, stream>>>(gib, ghb, HV);
  }

  // dest head (c2 cancels in log_softmax)
  dest_scores_kernel<<<((N_NODES - 1) * 64 + 255) / 256, 256, 0, stream>>>(
      HV, dest_w, scores);
  dest_softmax<<<1, 1024, 0, stream>>>(scores, destlogp_out);

  // ---- graph embed
  hipMemsetAsync(U, 0, sizeof(float) * (NT * H + NT), stream);
  gate_kernel<<<(N_NODES * 64 + 255) / 256, 256, 0, stream>>>(HV, ntype, gate_w,
                                                              gate_b, gw);
  usum_kernel<<<256, 256, 0, stream>>>(HV, ntype, gw, U, G);
  hipMemsetAsync(gembed_out, 0, sizeof(float) * (GH + 4 + H + 1), stream);
  gembed_partial<<<48, 256, 0, stream>>>(U, G, tograph_w, tograph_b, gembed_out);
  heads_kernel<<<26, 256, 0, stream>>>(gembed_out, addnode_w, addnode_b, ntype_embed,
                                       inithv_w, inithv_b, addedge_w, addedge_b, HV,
                                       nodelogp_out, hvinit_out, edgelogit_out);
}

// Round 10
// 609.512 us; speedup vs baseline: 1.3028x; 1.0473x over previous
//
#include <hip/hip_runtime.h>
#include <math.h>
#include <stdint.h>

#define N_NODES 20000
#define N_EDGES 320000
#define H 256
#define GH 512
#define G3 768
#define NT 3
#define R_ROUNDS 2
#define LDSW 72  // LDS row stride in shorts (64 data + 8 pad; 144B, 2-way-free)
#define MTILES 157  // ceil(20000/128)

typedef __attribute__((ext_vector_type(8))) short short8;
typedef __attribute__((ext_vector_type(8))) unsigned short ushort8;
typedef __attribute__((ext_vector_type(4))) float floatx4;

static __device__ __forceinline__ unsigned short f2bf(float x) {
  unsigned u = __float_as_uint(x);
  u += 0x7fffu + ((u >> 16) & 1u);
  return (unsigned short)(u >> 16);
}
static __device__ __forceinline__ float b2f(unsigned short x) {
  return __uint_as_float((unsigned)x << 16);
}

// ---------------------------------------------------------------- CSR build
__global__ __launch_bounds__(256) void hist_kernel(
    const int* __restrict__ dst, const float* __restrict__ he,
    int* __restrict__ cnt, float* __restrict__ hesum) {
  int e = blockIdx.x * 256 + threadIdx.x;
  if (e >= N_EDGES) return;
  int d = dst[e];
  atomicAdd(&cnt[d], 1);
  unsafeAtomicAdd(&hesum[d], he[e]);
}

__global__ __launch_bounds__(1024) void scan_kernel(
    const int* __restrict__ cnt, int* __restrict__ rowptr, int* __restrict__ cursor) {
  __shared__ int part[1024];
  const int CH = (N_NODES + 1023) / 1024;  // 20
  int t = threadIdx.x;
  int base = t * CH;
  int s = 0;
  for (int j = 0; j < CH; j++) {
    int idx = base + j;
    if (idx < N_NODES) s += cnt[idx];
  }
  part[t] = s;
  __syncthreads();
  int v = part[t];
  for (int off = 1; off < 1024; off <<= 1) {
    int o = (t >= off) ? part[t - off] : 0;
    __syncthreads();
    part[t] += o;
    __syncthreads();
  }
  int excl = part[t] - v;
  int run = excl;
  for (int j = 0; j < CH; j++) {
    int idx = base + j;
    if (idx < N_NODES) {
      rowptr[idx] = run;
      cursor[idx] = run;
      run += cnt[idx];
    }
  }
  if (t == 1023) rowptr[N_NODES] = run;
}

__global__ __launch_bounds__(256) void fill_kernel(
    const int* __restrict__ dst, const int* __restrict__ src,
    int* __restrict__ cursor, int* __restrict__ nbr) {
  int e = blockIdx.x * 256 + threadIdx.x;
  if (e >= N_EDGES) return;
  int p = atomicAdd(&cursor[dst[e]], 1);
  nbr[p] = src[e];
}

// ---------------------------------------------------------------- weight prep
__global__ __launch_bounds__(256) void cast_bf16(const float* __restrict__ in,
                                                 unsigned short* __restrict__ out, int n) {
  int i = blockIdx.x * 256 + threadIdx.x;
  if (i < n) out[i] = f2bf(in[i]);
}

// in: 512x512 (k rows, n cols) -> out[n*512+k] = in[k*512+n]
__global__ __launch_bounds__(256) void transpose_cast(const float* __restrict__ in,
                                                      unsigned short* __restrict__ out) {
  int idx = blockIdx.x * 256 + threadIdx.x;
  int n = idx >> 9, k = idx & 511;
  out[idx] = f2bf(in[k * 512 + n]);
}

// ---------------------------------------------------------------- gather
__global__ __launch_bounds__(256) void gather_kernel(
    const float* __restrict__ hv, const int* __restrict__ rowptr,
    const int* __restrict__ nbr, unsigned short* __restrict__ A_msg,
    unsigned short* __restrict__ HVb, float* __restrict__ deg) {
  int w = (blockIdx.x * blockDim.x + threadIdx.x) >> 6;
  int lane = threadIdx.x & 63;
  if (w >= N_NODES) return;
  int start = rowptr[w], end = rowptr[w + 1];
  float4 acc = make_float4(0.f, 0.f, 0.f, 0.f);
  for (int b = start; b < end; b += 64) {
    int nb = min(64, end - b);
    int sidx = (lane < nb) ? nbr[b + lane] : 0;
    for (int j = 0; j < nb; j++) {
      int s = __shfl(sidx, j);
      const float4 v = *reinterpret_cast<const float4*>(hv + (size_t)s * H + lane * 4);
      acc.x += v.x; acc.y += v.y; acc.z += v.z; acc.w += v.w;
    }
  }
  float dg = (float)(end - start);
  const float4 own = *reinterpret_cast<const float4*>(hv + (size_t)w * H + lane * 4);
  ushort4 o;
  o.x = f2bf(own.x * dg); o.y = f2bf(own.y * dg);
  o.z = f2bf(own.z * dg); o.w = f2bf(own.w * dg);
  *reinterpret_cast<ushort4*>(A_msg + (size_t)w * GH + lane * 4) = o;
  o.x = f2bf(acc.x); o.y = f2bf(acc.y); o.z = f2bf(acc.z); o.w = f2bf(acc.w);
  *reinterpret_cast<ushort4*>(A_msg + (size_t)w * GH + H + lane * 4) = o;
  o.x = f2bf(own.x); o.y = f2bf(own.y); o.z = f2bf(own.z); o.w = f2bf(own.w);
  *reinterpret_cast<ushort4*>(HVb + (size_t)w * H + lane * 4) = o;
  if (lane == 0) deg[w] = dg;
}

// ---------------------------------------------------------------- GEMM core macro
// 128x128 tile, BK=64, prefetched staging (loads for k+1 issued before MFMA of k).
#define GEMM_CORE(A, W, K)                                                        \
  {                                                                               \
    ushort8 va[4], vb[4];                                                         \
    _Pragma("unroll") for (int p = 0; p < 4; p++) {                               \
      va[p] = *(const ushort8*)((A) + (i0 + r0 + p * 32) * (K) + kc * 8);         \
      vb[p] = *(const ushort8*)((W) + (j0 + r0 + p * 32) * (K) + kc * 8);         \
    }                                                                             \
    for (int k0 = 0; k0 < (K); k0 += 64) {                                        \
      __syncthreads();                                                            \
      _Pragma("unroll") for (int p = 0; p < 4; p++) {                             \
        *(ushort8*)(As + (r0 + p * 32) * LDSW + kc * 8) = va[p];                  \
        *(ushort8*)(Bs + (r0 + p * 32) * LDSW + kc * 8) = vb[p];                  \
      }                                                                           \
      __syncthreads();                                                            \
      if (k0 + 64 < (K)) {                                                        \
        int kn = k0 + 64;                                                         \
        _Pragma("unroll") for (int p = 0; p < 4; p++) {                           \
          va[p] = *(const ushort8*)((A) + (i0 + r0 + p * 32) * (K) + kn + kc * 8);\
          vb[p] = *(const ushort8*)((W) + (j0 + r0 + p * 32) * (K) + kn + kc * 8);\
        }                                                                         \
      }                                                                           \
      _Pragma("unroll") for (int kk = 0; kk < 2; kk++) {                          \
        short8 af[4], bf[4];                                                      \
        _Pragma("unroll") for (int mi = 0; mi < 4; mi++)                          \
          af[mi] = *(const short8*)(As + (m0 + mi * 16 + lr) * LDSW + kk * 32 + lq * 8); \
        _Pragma("unroll") for (int ni = 0; ni < 4; ni++)                          \
          bf[ni] = *(const short8*)(Bs + (n0 + ni * 16 + lr) * LDSW + kk * 32 + lq * 8); \
        _Pragma("unroll") for (int mi = 0; mi < 4; mi++)                          \
          _Pragma("unroll") for (int ni = 0; ni < 4; ni++)                        \
            acc[mi][ni] = __builtin_amdgcn_mfma_f32_16x16x32_bf16(af[mi], bf[ni], \
                                                                  acc[mi][ni], 0, 0, 0); \
      }                                                                           \
    }                                                                             \
  }

// ---------------------------------------------------------------- merged msg + gh GEMM
// Flat grid 1600, XCD-swizzled: k = bid&7 (XCD), slot = bid>>3; each XCD owns a
// contiguous band of ~20 i-tiles, j fastest -> A panel stays in that XCD's L2.
// j 0..3: a = [deg*hv|S]@Wm + hesum*we + deg*bm -> a_b (bf16, ldc GH)
// j 4..9: gh = HVb@Whh^T + bhh -> ghb (bf16, ldc G3)
__global__ __launch_bounds__(256) void msg_gh_gemm(
    const unsigned short* __restrict__ A_msg, const unsigned short* __restrict__ Wm,
    const float* __restrict__ msg_bias, const float* __restrict__ we,
    const float* __restrict__ deg, const float* __restrict__ hesum,
    unsigned short* __restrict__ a_b, const unsigned short* __restrict__ HVb,
    const unsigned short* __restrict__ Whh, const float* __restrict__ bhh,
    unsigned short* __restrict__ ghb) {
  __shared__ unsigned short As[128 * LDSW];
  __shared__ unsigned short Bs[128 * LDSW];
  int bid = blockIdx.x;
  int xk = bid & 7, slot = bid >> 3;
  int it = xk * 20 + slot / 10;
  if (it >= MTILES) return;
  int jb = slot % 10;
  bool is_msg = jb < 4;
  int t = threadIdx.x;
  size_t i0 = (size_t)it * 128;
  size_t j0 = is_msg ? (size_t)jb * 128 : (size_t)(jb - 4) * 128;
  int wv = t >> 6, lane = t & 63;
  int m0 = (wv >> 1) * 64, n0 = (wv & 1) * 64;
  int lr = lane & 15, lq = lane >> 4;
  int r0 = t >> 3, kc = t & 7;
  floatx4 acc[4][4];
#pragma unroll
  for (int a = 0; a < 4; a++)
#pragma unroll
    for (int b = 0; b < 4; b++) acc[a][b] = (floatx4){0.f, 0.f, 0.f, 0.f};

  if (is_msg) {
    GEMM_CORE(A_msg, Wm, GH)
#pragma unroll
    for (int mi = 0; mi < 4; mi++) {
#pragma unroll
      for (int ni = 0; ni < 4; ni++) {
        int col = (int)j0 + n0 + ni * 16 + lr;
        float wv_ = we[col], bv = msg_bias[col];
#pragma unroll
        for (int i = 0; i < 4; i++) {
          size_t row = i0 + m0 + mi * 16 + lq * 4 + i;
          if (row < (size_t)N_NODES)
            a_b[row * GH + col] = f2bf(acc[mi][ni][i] + hesum[row] * wv_ + deg[row] * bv);
        }
      }
    }
  } else {
    GEMM_CORE(HVb, Whh, H)
#pragma unroll
    for (int mi = 0; mi < 4; mi++) {
#pragma unroll
      for (int ni = 0; ni < 4; ni++) {
        int col = (int)j0 + n0 + ni * 16 + lr;
        float bv = bhh[col];
#pragma unroll
        for (int i = 0; i < 4; i++) {
          size_t row = i0 + m0 + mi * 16 + lq * 4 + i;
          if (row < (size_t)N_NODES) ghb[row * G3 + col] = f2bf(acc[mi][ni][i] + bv);
        }
      }
    }
  }
}

// ---------------------------------------------------------------- gi GEMM (bf16 out)
// Flat grid 960, XCD-swizzled like msg_gh (6 j-tiles per i-tile).
__global__ __launch_bounds__(256) void mfma_gemm(
    const unsigned short* __restrict__ A, const unsigned short* __restrict__ W,
    const float* __restrict__ bias, unsigned short* __restrict__ Cb) {
  __shared__ unsigned short As[128 * LDSW];
  __shared__ unsigned short Bs[128 * LDSW];
  int bid = blockIdx.x;
  int xk = bid & 7, slot = bid >> 3;
  int it = xk * 20 + slot / 6;
  if (it >= MTILES) return;
  int jb = slot % 6;
  int t = threadIdx.x;
  size_t i0 = (size_t)it * 128;
  size_t j0 = (size_t)jb * 128;
  int wv = t >> 6, lane = t & 63;
  int m0 = (wv >> 1) * 64, n0 = (wv & 1) * 64;
  int lr = lane & 15, lq = lane >> 4;
  int r0 = t >> 3, kc = t & 7;
  floatx4 acc[4][4];
#pragma unroll
  for (int a = 0; a < 4; a++)
#pragma unroll
    for (int b = 0; b < 4; b++) acc[a][b] = (floatx4){0.f, 0.f, 0.f, 0.f};

  GEMM_CORE(A, W, GH)
#pragma unroll
  for (int mi = 0; mi < 4; mi++) {
#pragma unroll
    for (int ni = 0; ni < 4; ni++) {
      int col = (int)j0 + n0 + ni * 16 + lr;
      float bv = bias[col];
#pragma unroll
      for (int i = 0; i < 4; i++) {
        size_t row = i0 + m0 + mi * 16 + lq * 4 + i;
        if (row < (size_t)N_NODES) Cb[row * G3 + col] = f2bf(acc[mi][ni][i] + bv);
      }
    }
  }
}

// ---------------------------------------------------------------- GRU elementwise (bf16 in)
__global__ __launch_bounds__(256) void gru_update(const unsigned short* __restrict__ gi,
                                                  const unsigned short* __restrict__ gh,
                                                  float* __restrict__ hv) {
  int idx = blockIdx.x * 256 + threadIdx.x;
  if (idx >= N_NODES * 32) return;
  int row = idx >> 5;
  int c8 = (idx & 31) << 3;
  const unsigned short* gir = gi + (size_t)row * G3;
  const unsigned short* ghr = gh + (size_t)row * G3;
  ushort8 vir = *(const ushort8*)(gir + c8);
  ushort8 viz = *(const ushort8*)(gir + H + c8);
  ushort8 vin = *(const ushort8*)(gir + 2 * H + c8);
  ushort8 vhr = *(const ushort8*)(ghr + c8);
  ushort8 vhz = *(const ushort8*)(ghr + H + c8);
  ushort8 vhn = *(const ushort8*)(ghr + 2 * H + c8);
  float* hp = hv + (size_t)row * H + c8;
  float4 h0 = *(float4*)hp;
  float4 h1 = *(float4*)(hp + 4);
  float hvv[8] = {h0.x, h0.y, h0.z, h0.w, h1.x, h1.y, h1.z, h1.w};
#pragma unroll
  for (int j = 0; j < 8; j++) {
    float r = 1.f / (1.f + expf(-(b2f(vir[j]) + b2f(vhr[j]))));
    float z = 1.f / (1.f + expf(-(b2f(viz[j]) + b2f(vhz[j]))));
    float n = tanhf(b2f(vin[j]) + r * b2f(vhn[j]));
    hvv[j] = (1.f - z) * n + z * hvv[j];
  }
  *(float4*)hp = make_float4(hvv[0], hvv[1], hvv[2], hvv[3]);
  *(float4*)(hp + 4) = make_float4(hvv[4], hvv[5], hvv[6], hvv[7]);
}

// ---------------------------------------------------------------- gate pass
__global__ __launch_bounds__(256) void gate_kernel(
    const float* __restrict__ hv, const int* __restrict__ ntype,
    const float* __restrict__ gate_w, const float* __restrict__ gate_b,
    float* __restrict__ gw) {
  int w = (blockIdx.x * blockDim.x + threadIdx.x) >> 6;
  int lane = threadIdx.x & 63;
  if (w >= N_NODES) return;
  int t = ntype[w];
  float4 h = *reinterpret_cast<const float4*>(hv + (size_t)w * H + lane * 4);
  float4 g = *reinterpret_cast<const float4*>(gate_w + t * H + lane * 4);
  float s = h.x * g.x + h.y * g.y + h.z * g.z + h.w * g.w;
  for (int off = 32; off; off >>= 1) s += __shfl_xor(s, off);
  if (lane == 0) gw[w] = 1.f / (1.f + expf(-(s + gate_b[t])));
}

// ---------------------------------------------------------------- U column-sum
__global__ __launch_bounds__(256) void usum_kernel(
    const float* __restrict__ hv, const int* __restrict__ ntype,
    const float* __restrict__ gw, float* __restrict__ U, float* __restrict__ G) {
  const int CH = (N_NODES + 255) / 256;  // 79
  int col = threadIdx.x;
  int r0 = blockIdx.x * CH;
  int r1 = min(r0 + CH, N_NODES);
  float a0 = 0.f, a1 = 0.f, a2 = 0.f;
  float g0 = 0.f, g1 = 0.f, g2 = 0.f;
  int i = r0;
  for (; i + 4 <= r1; i += 4) {
    float v0 = hv[(size_t)(i + 0) * H + col];
    float v1 = hv[(size_t)(i + 1) * H + col];
    float v2 = hv[(size_t)(i + 2) * H + col];
    float v3 = hv[(size_t)(i + 3) * H + col];
    int t0 = ntype[i + 0], t1 = ntype[i + 1], t2 = ntype[i + 2], t3 = ntype[i + 3];
    float w0 = gw[i + 0], w1 = gw[i + 1], w2 = gw[i + 2], w3 = gw[i + 3];
    v0 *= w0; v1 *= w1; v2 *= w2; v3 *= w3;
    a0 += (t0 == 0) ? v0 : 0.f; a1 += (t0 == 1) ? v0 : 0.f; a2 += (t0 == 2) ? v0 : 0.f;
    a0 += (t1 == 0) ? v1 : 0.f; a1 += (t1 == 1) ? v1 : 0.f; a2 += (t1 == 2) ? v1 : 0.f;
    a0 += (t2 == 0) ? v2 : 0.f; a1 += (t2 == 1) ? v2 : 0.f; a2 += (t2 == 2) ? v2 : 0.f;
    a0 += (t3 == 0) ? v3 : 0.f; a1 += (t3 == 1) ? v3 : 0.f; a2 += (t3 == 2) ? v3 : 0.f;
    g0 += (t0 == 0) ? w0 : 0.f; g1 += (t0 == 1) ? w0 : 0.f; g2 += (t0 == 2) ? w0 : 0.f;
    g0 += (t1 == 0) ? w1 : 0.f; g1 += (t1 == 1) ? w1 : 0.f; g2 += (t1 == 2) ? w1 : 0.f;
    g0 += (t2 == 0) ? w2 : 0.f; g1 += (t2 == 1) ? w2 : 0.f; g2 += (t2 == 2) ? w2 : 0.f;
    g0 += (t3 == 0) ? w3 : 0.f; g1 += (t3 == 1) ? w3 : 0.f; g2 += (t3 == 2) ? w3 : 0.f;
  }
  for (; i < r1; i++) {
    float v = hv[(size_t)i * H + col];
    int t = ntype[i];
    float w = gw[i];
    v *= w;
    a0 += (t == 0) ? v : 0.f; a1 += (t == 1) ? v : 0.f; a2 += (t == 2) ? v : 0.f;
    g0 += (t == 0) ? w : 0.f; g1 += (t == 1) ? w : 0.f; g2 += (t == 2) ? w : 0.f;
  }
  unsafeAtomicAdd(&U[0 * H + col], a0);
  unsafeAtomicAdd(&U[1 * H + col], a1);
  unsafeAtomicAdd(&U[2 * H + col], a2);
  if (col == 0) {
    unsafeAtomicAdd(&G[0], g0);
    unsafeAtomicAdd(&G[1], g1);
    unsafeAtomicAdd(&G[2], g2);
  }
}

// ---------------------------------------------------------------- gembed (k-split, MLP)
__global__ __launch_bounds__(256) void gembed_partial(
    const float* __restrict__ U, const float* __restrict__ G,
    const float* __restrict__ tograph_w, const float* __restrict__ tograph_b,
    float* __restrict__ gembed_out) {
  int b = blockIdx.x;
  int t = b >> 4, half = (b >> 3) & 1, kc = b & 7;
  int col = half * 256 + threadIdx.x;
  int k0 = kc * 32;
  const float* Wt = tograph_w + (size_t)t * H * GH;
  float w[32], u[32];
#pragma unroll
  for (int j = 0; j < 32; j++) w[j] = Wt[(size_t)(k0 + j) * GH + col];
#pragma unroll
  for (int j = 0; j < 32; j++) u[j] = U[t * H + k0 + j];
  float acc = (kc == 0) ? G[t] * tograph_b[t * GH + col] : 0.f;
#pragma unroll
  for (int j = 0; j < 32; j++) acc += u[j] * w[j];
  unsafeAtomicAdd(&gembed_out[col], acc);
}

// ---------------------------------------------------------------- heads (k-split, MLP)
__global__ __launch_bounds__(256) void heads_kernel(
    const float* __restrict__ ge, const float* __restrict__ addnode_w,
    const float* __restrict__ addnode_b, const float* __restrict__ ntype_embed,
    const float* __restrict__ inithv_w, const float* __restrict__ inithv_b,
    const float* __restrict__ addedge_w, const float* __restrict__ addedge_b,
    const float* __restrict__ hv, float* __restrict__ nodelogp_out,
    float* __restrict__ hvinit_out, float* __restrict__ edgelogit_out) {
  int b = blockIdx.x;
  int tid = threadIdx.x;
  if (b < 24) {
    int k0 = b * 32;
    float w[32], x[32];
#pragma unroll
    for (int j = 0; j < 32; j++) w[j] = inithv_w[(size_t)(k0 + j) * H + tid];
#pragma unroll
    for (int j = 0; j < 32; j++) {
      int k = k0 + j;
      x[j] = (k < H) ? ntype_embed[k] : ge[k - H];
    }
    float acc = (b == 0) ? inithv_b[tid] : 0.f;
#pragma unroll
    for (int j = 0; j < 32; j++) acc += x[j] * w[j];
    unsafeAtomicAdd(&hvinit_out[tid], acc);
  } else if (b == 24) {
    __shared__ float lg[4];
    int w = tid >> 6, lane = tid & 63;
    float s = 0.f;
    for (int k = lane; k < GH; k += 64) s += ge[k] * addnode_w[k * 4 + w];
    for (int off = 32; off; off >>= 1) s += __shfl_xor(s, off);
    if (lane == 0) lg[w] = s + addnode_b[w];
    __syncthreads();
    if (tid == 0) {
      float m = fmaxf(fmaxf(lg[0], lg[1]), fmaxf(lg[2], lg[3]));
      float sum = 0.f;
      for (int c = 0; c < 4; c++) sum += expf(lg[c] - m);
      float lse = m + logf(sum);
      for (int c = 0; c < 4; c++) nodelogp_out[c] = lg[c] - lse;
    }
  } else {
    int w = tid >> 6, lane = tid & 63;
    if (w == 0) {
      const float* se = hv + (size_t)(N_NODES - 1) * H;
      float s = 0.f;
      for (int k = lane; k < G3; k += 64) {
        float x = (k < GH) ? ge[k] : se[k - GH];
        s += x * addedge_w[k];
      }
      for (int off = 32; off; off >>= 1) s += __shfl_xor(s, off);
      if (lane == 0) edgelogit_out[0] = s + addedge_b[0];
    }
  }
}

// ---------------------------------------------------------------- dest scores
__global__ __launch_bounds__(256) void dest_scores_kernel(
    const float* __restrict__ hv, const float* __restrict__ dest_w,
    float* __restrict__ scores) {
  int w = (blockIdx.x * blockDim.x + threadIdx.x) >> 6;
  int lane = threadIdx.x & 63;
  if (w >= N_NODES - 1) return;
  float4 h = *reinterpret_cast<const float4*>(hv + (size_t)w * H + lane * 4);
  float4 d = *reinterpret_cast<const float4*>(dest_w + lane * 4);
  float s = h.x * d.x + h.y * d.y + h.z * d.z + h.w * d.w;
  for (int off = 32; off; off >>= 1) s += __shfl_xor(s, off);
  if (lane == 0) scores[w] = s;
}

__global__ __launch_bounds__(1024) void dest_softmax(const float* __restrict__ scores,
                                                     float* __restrict__ out) {
  const int n = N_NODES - 1;
  __shared__ float red[16];
  __shared__ float bc[2];
  int tid = threadIdx.x;
  float m = -1e30f;
  for (int i = tid; i < n; i += 1024) m = fmaxf(m, scores[i]);
  for (int off = 32; off; off >>= 1) m = fmaxf(m, __shfl_xor(m, off));
  if ((tid & 63) == 0) red[tid >> 6] = m;
  __syncthreads();
  if (tid == 0) {
    float v = red[0];
    for (int i = 1; i < 16; i++) v = fmaxf(v, red[i]);
    bc[0] = v;
  }
  __syncthreads();
  float mx = bc[0];
  float s = 0.f;
  for (int i = tid; i < n; i += 1024) s += expf(scores[i] - mx);
  for (int off = 32; off; off >>= 1) s += __shfl_xor(s, off);
  if ((tid & 63) == 0) red[tid >> 6] = s;
  __syncthreads();
  if (tid == 0) {
    float v = 0.f;
    for (int i = 0; i < 16; i++) v += red[i];
    bc[1] = v;
  }
  __syncthreads();
  float lse = mx + logf(bc[1]);
  for (int i = tid; i < n; i += 1024) out[i] = scores[i] - lse;
}

// ---------------------------------------------------------------- launch
extern "C" void kernel_launch(void* const* d_in, const int* in_sizes, int n_in,
                              void* d_out, int out_size, void* d_ws, size_t ws_size,
                              hipStream_t stream) {
  const float* hv0 = (const float*)d_in[0];
  const float* he = (const float*)d_in[1];
  const int* ntype = (const int*)d_in[2];
  const int* src = (const int*)d_in[3];
  const int* dst = (const int*)d_in[4];
  const float* msg_w = (const float*)d_in[5];
  const float* msg_b = (const float*)d_in[6];
  const float* w_ih = (const float*)d_in[7];
  const float* b_ih = (const float*)d_in[8];
  const float* w_hh = (const float*)d_in[9];
  const float* b_hh = (const float*)d_in[10];
  const float* gate_w = (const float*)d_in[11];
  const float* gate_b = (const float*)d_in[12];
  const float* tograph_w = (const float*)d_in[13];
  const float* tograph_b = (const float*)d_in[14];
  const float* addnode_w = (const float*)d_in[15];
  const float* addnode_b = (const float*)d_in[16];
  const float* ntype_embed = (const float*)d_in[17];
  const float* inithv_w = (const float*)d_in[18];
  const float* inithv_b = (const float*)d_in[19];
  const float* addedge_w = (const float*)d_in[20];
  const float* addedge_b = (const float*)d_in[21];
  const float* dest_w = (const float*)d_in[22];
  const float* dest_b = (const float*)d_in[23];

  float* out = (float*)d_out;
  float* HV = out;
  float* gembed_out = out + (size_t)N_NODES * H;
  float* nodelogp_out = gembed_out + GH;
  float* hvinit_out = nodelogp_out + 4;
  float* edgelogit_out = hvinit_out + H;
  float* destlogp_out = edgelogit_out + 1;

  float* ws = (float*)d_ws;
  float* deg = ws;                                    // N
  float* hesum = deg + N_NODES;                       // N
  float* U = hesum + N_NODES;                         // NT*H
  float* G = U + NT * H;                              // NT
  float* misc = G + NT;                               // 16
  float* scores = misc + 16;                          // N
  float* gw = scores + N_NODES;                       // N
  int* cnt = (int*)(gw + N_NODES);                    // N
  int* rowptr = cnt + N_NODES;                        // N+1
  int* cursor = rowptr + N_NODES + 1;                 // N
  int* nbr = cursor + N_NODES;                        // E
  unsigned short* A_msg =
      (unsigned short*)(((uintptr_t)(nbr + N_EDGES) + 15) & ~(uintptr_t)15);
  unsigned short* HVb = A_msg + (size_t)(N_NODES + 128) * GH;
  unsigned short* a_b = HVb + (size_t)(N_NODES + 128) * H;
  unsigned short* gib = a_b + (size_t)(N_NODES + 128) * GH;
  unsigned short* ghb = gib + (size_t)(N_NODES + 128) * G3;
  unsigned short* wihb = ghb + (size_t)(N_NODES + 128) * G3;
  unsigned short* whhb = wihb + (size_t)2 * G3 * GH;
  unsigned short* Wmt = whhb + (size_t)2 * G3 * H;

  hipMemcpyAsync(HV, hv0, sizeof(float) * (size_t)N_NODES * H,
                 hipMemcpyDeviceToDevice, stream);

  // ---- weight prep (bf16; msg_w transposed to N x K)
  cast_bf16<<<(2 * G3 * GH + 255) / 256, 256, 0, stream>>>(w_ih, wihb, 2 * G3 * GH);
  cast_bf16<<<(2 * G3 * H + 255) / 256, 256, 0, stream>>>(w_hh, whhb, 2 * G3 * H);
  transpose_cast<<<(512 * 512) / 256, 256, 0, stream>>>(msg_w, Wmt);
  transpose_cast<<<(512 * 512) / 256, 256, 0, stream>>>(msg_w + 513 * 512,
                                                        Wmt + 512 * 512);

  // ---- CSR build
  hipMemsetAsync(hesum, 0, sizeof(float) * N_NODES, stream);
  hipMemsetAsync(cnt, 0, sizeof(int) * N_NODES, stream);
  hist_kernel<<<(N_EDGES + 255) / 256, 256, 0, stream>>>(dst, he, cnt, hesum);
  scan_kernel<<<1, 1024, 0, stream>>>(cnt, rowptr, cursor);
  fill_kernel<<<(N_EDGES + 255) / 256, 256, 0, stream>>>(dst, src, cursor, nbr);

  for (int t = 0; t < R_ROUNDS; t++) {
    gather_kernel<<<N_NODES / 4, 256, 0, stream>>>(HV, rowptr, nbr, A_msg, HVb, deg);
    // msg + gh merged, XCD-swizzled (8 XCDs x 200 slots)
    msg_gh_gemm<<<1600, 256, 0, stream>>>(
        A_msg, Wmt + (size_t)t * GH * GH, msg_b + (size_t)t * GH,
        msg_w + (size_t)t * (2 * H + 1) * GH + (size_t)GH * GH, deg, hesum, a_b,
        HVb, whhb + (size_t)t * G3 * H, b_hh + (size_t)t * G3, ghb);
    // gi = a @ w_ih^T + b_ih (bf16 out), XCD-swizzled (8 x 120)
    mfma_gemm<<<960, 256, 0, stream>>>(
        a_b, wihb + (size_t)t * G3 * GH, b_ih + (size_t)t * G3, gib);
    gru_update<<<(N_NODES * 32 + 255) / 256, 256, 0, stream>>>(gib, ghb, HV);
  }

  // dest head (c2 cancels in log_softmax)
  dest_scores_kernel<<<((N_NODES - 1) * 64 + 255) / 256, 256, 0, stream>>>(
      HV, dest_w, scores);
  dest_softmax<<<1, 1024, 0, stream>>>(scores, destlogp_out);

  // ---- graph embed
  hipMemsetAsync(U, 0, sizeof(float) * (NT * H + NT), stream);
  gate_kernel<<<(N_NODES * 64 + 255) / 256, 256, 0, stream>>>(HV, ntype, gate_w,
                                                              gate_b, gw);
  usum_kernel<<<256, 256, 0, stream>>>(HV, ntype, gw, U, G);
  hipMemsetAsync(gembed_out, 0, sizeof(float) * (GH + 4 + H + 1), stream);
  gembed_partial<<<48, 256, 0, stream>>>(U, G, tograph_w, tograph_b, gembed_out);
  heads_kernel<<<26, 256, 0, stream>>>(gembed_out, addnode_w, addnode_b, ntype_embed,
                                       inithv_w, inithv_b, addedge_w, addedge_b, HV,
                                       nodelogp_out, hvinit_out, edgelogit_out);
}

// Round 12
// 597.274 us; speedup vs baseline: 1.3295x; 1.0205x over previous
//
#include <hip/hip_runtime.h>
#include <math.h>
#include <stdint.h>

#define N_NODES 20000
#define N_EDGES 320000
#define H 256
#define GH 512
#define G3 768
#define NT 3
#define R_ROUNDS 2
#define LDSW 72  // LDS row stride in shorts (64 data + 8 pad; 144B, 2-way-free)
#define MTILES 157  // ceil(20000/128)

typedef __attribute__((ext_vector_type(8))) short short8;
typedef __attribute__((ext_vector_type(8))) unsigned short ushort8;
typedef __attribute__((ext_vector_type(4))) float floatx4;

static __device__ __forceinline__ unsigned short f2bf(float x) {
  unsigned u = __float_as_uint(x);
  u += 0x7fffu + ((u >> 16) & 1u);
  return (unsigned short)(u >> 16);
}
static __device__ __forceinline__ float b2f(unsigned short x) {
  return __uint_as_float((unsigned)x << 16);
}

// ---------------------------------------------------------------- CSR build
__global__ __launch_bounds__(256) void hist_kernel(
    const int* __restrict__ dst, const float* __restrict__ he,
    int* __restrict__ cnt, float* __restrict__ hesum) {
  int e = blockIdx.x * 256 + threadIdx.x;
  if (e >= N_EDGES) return;
  int d = dst[e];
  atomicAdd(&cnt[d], 1);
  unsafeAtomicAdd(&hesum[d], he[e]);
}

__global__ __launch_bounds__(1024) void scan_kernel(
    const int* __restrict__ cnt, int* __restrict__ rowptr, int* __restrict__ cursor) {
  __shared__ int part[1024];
  const int CH = (N_NODES + 1023) / 1024;  // 20
  int t = threadIdx.x;
  int base = t * CH;
  int s = 0;
  for (int j = 0; j < CH; j++) {
    int idx = base + j;
    if (idx < N_NODES) s += cnt[idx];
  }
  part[t] = s;
  __syncthreads();
  int v = part[t];
  for (int off = 1; off < 1024; off <<= 1) {
    int o = (t >= off) ? part[t - off] : 0;
    __syncthreads();
    part[t] += o;
    __syncthreads();
  }
  int excl = part[t] - v;
  int run = excl;
  for (int j = 0; j < CH; j++) {
    int idx = base + j;
    if (idx < N_NODES) {
      rowptr[idx] = run;
      cursor[idx] = run;
      run += cnt[idx];
    }
  }
  if (t == 1023) rowptr[N_NODES] = run;
}

__global__ __launch_bounds__(256) void fill_kernel(
    const int* __restrict__ dst, const int* __restrict__ src,
    int* __restrict__ cursor, int* __restrict__ nbr) {
  int e = blockIdx.x * 256 + threadIdx.x;
  if (e >= N_EDGES) return;
  int p = atomicAdd(&cursor[dst[e]], 1);
  nbr[p] = src[e];
}

// ---------------------------------------------------------------- weight prep
__global__ __launch_bounds__(256) void cast_bf16(const float* __restrict__ in,
                                                 unsigned short* __restrict__ out, int n) {
  int i = blockIdx.x * 256 + threadIdx.x;
  if (i < n) out[i] = f2bf(in[i]);
}

// wep[n] = dot(msg_w row 512, w_ih[n]); bmp[n] = dot(msg_b, w_ih[n])  (NO b_ih!)
__global__ __launch_bounds__(256) void vec_comb(
    const float* __restrict__ msg_w_t,  // 513x512 slice
    const float* __restrict__ msg_b_t,  // 512
    const float* __restrict__ w_ih_t,   // 768x512 slice
    float* __restrict__ wep, float* __restrict__ bmp) {
  int n = blockIdx.x * 4 + (threadIdx.x >> 6);
  int lane = threadIdx.x & 63;
  const float* we = msg_w_t + (size_t)GH * GH;
  const float* wr = w_ih_t + (size_t)n * GH;
  float s1 = 0.f, s2 = 0.f;
  for (int k = lane; k < GH; k += 64) {
    float w = wr[k];
    s1 += we[k] * w;
    s2 += msg_b_t[k] * w;
  }
  for (int off = 32; off; off >>= 1) {
    s1 += __shfl_xor(s1, off);
    s2 += __shfl_xor(s2, off);
  }
  if (lane == 0) {
    wep[n] = s1;
    bmp[n] = s2;
  }
}

// ---------------------------------------------------------------- gather
__global__ __launch_bounds__(256) void gather_kernel(
    const float* __restrict__ hv, const int* __restrict__ rowptr,
    const int* __restrict__ nbr, unsigned short* __restrict__ A_msg,
    unsigned short* __restrict__ HVb, float* __restrict__ deg) {
  int w = (blockIdx.x * blockDim.x + threadIdx.x) >> 6;
  int lane = threadIdx.x & 63;
  if (w >= N_NODES) return;
  int start = rowptr[w], end = rowptr[w + 1];
  float4 acc = make_float4(0.f, 0.f, 0.f, 0.f);
  for (int b = start; b < end; b += 64) {
    int nb = min(64, end - b);
    int sidx = (lane < nb) ? nbr[b + lane] : 0;
    for (int j = 0; j < nb; j++) {
      int s = __shfl(sidx, j);
      const float4 v = *reinterpret_cast<const float4*>(hv + (size_t)s * H + lane * 4);
      acc.x += v.x; acc.y += v.y; acc.z += v.z; acc.w += v.w;
    }
  }
  float dg = (float)(end - start);
  const float4 own = *reinterpret_cast<const float4*>(hv + (size_t)w * H + lane * 4);
  ushort4 o;
  o.x = f2bf(own.x * dg); o.y = f2bf(own.y * dg);
  o.z = f2bf(own.z * dg); o.w = f2bf(own.w * dg);
  *reinterpret_cast<ushort4*>(A_msg + (size_t)w * GH + lane * 4) = o;
  o.x = f2bf(acc.x); o.y = f2bf(acc.y); o.z = f2bf(acc.z); o.w = f2bf(acc.w);
  *reinterpret_cast<ushort4*>(A_msg + (size_t)w * GH + H + lane * 4) = o;
  o.x = f2bf(own.x); o.y = f2bf(own.y); o.z = f2bf(own.z); o.w = f2bf(own.w);
  *reinterpret_cast<ushort4*>(HVb + (size_t)w * H + lane * 4) = o;
  if (lane == 0) deg[w] = dg;
}

// ---------------------------------------------------------------- GEMM core macro
// 128x128 tile, BK=64, prefetched staging (loads for k+1 issued before MFMA of k).
#define GEMM_CORE(A, W, K)                                                        \
  {                                                                               \
    ushort8 va[4], vb[4];                                                         \
    _Pragma("unroll") for (int p = 0; p < 4; p++) {                               \
      va[p] = *(const ushort8*)((A) + (i0 + r0 + p * 32) * (K) + kc * 8);         \
      vb[p] = *(const ushort8*)((W) + (j0 + r0 + p * 32) * (K) + kc * 8);         \
    }                                                                             \
    for (int k0 = 0; k0 < (K); k0 += 64) {                                        \
      __syncthreads();                                                            \
      _Pragma("unroll") for (int p = 0; p < 4; p++) {                             \
        *(ushort8*)(As + (r0 + p * 32) * LDSW + kc * 8) = va[p];                  \
        *(ushort8*)(Bs + (r0 + p * 32) * LDSW + kc * 8) = vb[p];                  \
      }                                                                           \
      __syncthreads();                                                            \
      if (k0 + 64 < (K)) {                                                        \
        int kn = k0 + 64;                                                         \
        _Pragma("unroll") for (int p = 0; p < 4; p++) {                           \
          va[p] = *(const ushort8*)((A) + (i0 + r0 + p * 32) * (K) + kn + kc * 8);\
          vb[p] = *(const ushort8*)((W) + (j0 + r0 + p * 32) * (K) + kn + kc * 8);\
        }                                                                         \
      }                                                                           \
      _Pragma("unroll") for (int kk = 0; kk < 2; kk++) {                          \
        short8 af[4], bf[4];                                                      \
        _Pragma("unroll") for (int mi = 0; mi < 4; mi++)                          \
          af[mi] = *(const short8*)(As + (m0 + mi * 16 + lr) * LDSW + kk * 32 + lq * 8); \
        _Pragma("unroll") for (int ni = 0; ni < 4; ni++)                          \
          bf[ni] = *(const short8*)(Bs + (n0 + ni * 16 + lr) * LDSW + kk * 32 + lq * 8); \
        _Pragma("unroll") for (int mi = 0; mi < 4; mi++)                          \
          _Pragma("unroll") for (int ni = 0; ni < 4; ni++)                        \
            acc[mi][ni] = __builtin_amdgcn_mfma_f32_16x16x32_bf16(af[mi], bf[ni], \
                                                                  acc[mi][ni], 0, 0, 0); \
      }                                                                           \
    }                                                                             \
  }

// ---------------------------------------------------------------- weight-combine GEMM
// Wc[n][k] = sum_j w_ih[n][j] * msg_w[k][j].  A = wihb (768x512), W = msg_wb
// (512x512 rows of msg_w cast), out bf16 768x512. grid (4, 6).
__global__ __launch_bounds__(256) void wcomb_gemm(
    const unsigned short* __restrict__ A, const unsigned short* __restrict__ W,
    unsigned short* __restrict__ Cb) {
  __shared__ unsigned short As[128 * LDSW];
  __shared__ unsigned short Bs[128 * LDSW];
  int t = threadIdx.x;
  size_t i0 = (size_t)blockIdx.y * 128;
  size_t j0 = (size_t)blockIdx.x * 128;
  int wv = t >> 6, lane = t & 63;
  int m0 = (wv >> 1) * 64, n0 = (wv & 1) * 64;
  int lr = lane & 15, lq = lane >> 4;
  int r0 = t >> 3, kc = t & 7;
  floatx4 acc[4][4];
#pragma unroll
  for (int a = 0; a < 4; a++)
#pragma unroll
    for (int b = 0; b < 4; b++) acc[a][b] = (floatx4){0.f, 0.f, 0.f, 0.f};
  GEMM_CORE(A, W, GH)
#pragma unroll
  for (int mi = 0; mi < 4; mi++) {
#pragma unroll
    for (int ni = 0; ni < 4; ni++) {
      int col = (int)j0 + n0 + ni * 16 + lr;
#pragma unroll
      for (int i = 0; i < 4; i++) {
        size_t row = i0 + m0 + mi * 16 + lq * 4 + i;
        Cb[row * GH + col] = f2bf(acc[mi][ni][i]);
      }
    }
  }
}

// ---------------------------------------------------------------- fused gi + gh GEMM
// Flat grid 1920, XCD-swizzled. jb 0..5: gi = A_msg@Wc^T + hesum*wep + deg*bmp + b_ih.
// jb 6..11: gh = HVb@Whh^T + bhh.  Both bf16 out, ldc G3.
__global__ __launch_bounds__(256) void gi_gh_gemm(
    const unsigned short* __restrict__ A_msg, const unsigned short* __restrict__ Wc,
    const float* __restrict__ wep, const float* __restrict__ bmp,
    const float* __restrict__ bih,
    const float* __restrict__ deg, const float* __restrict__ hesum,
    unsigned short* __restrict__ gib, const unsigned short* __restrict__ HVb,
    const unsigned short* __restrict__ Whh, const float* __restrict__ bhh,
    unsigned short* __restrict__ ghb) {
  __shared__ unsigned short As[128 * LDSW];
  __shared__ unsigned short Bs[128 * LDSW];
  int bid = blockIdx.x;
  int xk = bid & 7, slot = bid >> 3;
  int it = xk * 20 + slot / 12;
  if (it >= MTILES) return;
  int jb = slot % 12;
  bool is_gi = jb < 6;
  int t = threadIdx.x;
  size_t i0 = (size_t)it * 128;
  size_t j0 = is_gi ? (size_t)jb * 128 : (size_t)(jb - 6) * 128;
  int wv = t >> 6, lane = t & 63;
  int m0 = (wv >> 1) * 64, n0 = (wv & 1) * 64;
  int lr = lane & 15, lq = lane >> 4;
  int r0 = t >> 3, kc = t & 7;
  floatx4 acc[4][4];
#pragma unroll
  for (int a = 0; a < 4; a++)
#pragma unroll
    for (int b = 0; b < 4; b++) acc[a][b] = (floatx4){0.f, 0.f, 0.f, 0.f};

  if (is_gi) {
    GEMM_CORE(A_msg, Wc, GH)
#pragma unroll
    for (int mi = 0; mi < 4; mi++) {
#pragma unroll
      for (int ni = 0; ni < 4; ni++) {
        int col = (int)j0 + n0 + ni * 16 + lr;
        float wv_ = wep[col], bv = bmp[col], b2 = bih[col];
#pragma unroll
        for (int i = 0; i < 4; i++) {
          size_t row = i0 + m0 + mi * 16 + lq * 4 + i;
          if (row < (size_t)N_NODES)
            gib[row * G3 + col] =
                f2bf(acc[mi][ni][i] + hesum[row] * wv_ + deg[row] * bv + b2);
        }
      }
    }
  } else {
    GEMM_CORE(HVb, Whh, H)
#pragma unroll
    for (int mi = 0; mi < 4; mi++) {
#pragma unroll
      for (int ni = 0; ni < 4; ni++) {
        int col = (int)j0 + n0 + ni * 16 + lr;
        float bv = bhh[col];
#pragma unroll
        for (int i = 0; i < 4; i++) {
          size_t row = i0 + m0 + mi * 16 + lq * 4 + i;
          if (row < (size_t)N_NODES) ghb[row * G3 + col] = f2bf(acc[mi][ni][i] + bv);
        }
      }
    }
  }
}

// ---------------------------------------------------------------- GRU elementwise (bf16 in)
__global__ __launch_bounds__(256) void gru_update(const unsigned short* __restrict__ gi,
                                                  const unsigned short* __restrict__ gh,
                                                  float* __restrict__ hv) {
  int idx = blockIdx.x * 256 + threadIdx.x;
  if (idx >= N_NODES * 32) return;
  int row = idx >> 5;
  int c8 = (idx & 31) << 3;
  const unsigned short* gir = gi + (size_t)row * G3;
  const unsigned short* ghr = gh + (size_t)row * G3;
  ushort8 vir = *(const ushort8*)(gir + c8);
  ushort8 viz = *(const ushort8*)(gir + H + c8);
  ushort8 vin = *(const ushort8*)(gir + 2 * H + c8);
  ushort8 vhr = *(const ushort8*)(ghr + c8);
  ushort8 vhz = *(const ushort8*)(ghr + H + c8);
  ushort8 vhn = *(const ushort8*)(ghr + 2 * H + c8);
  float* hp = hv + (size_t)row * H + c8;
  float4 h0 = *(float4*)hp;
  float4 h1 = *(float4*)(hp + 4);
  float hvv[8] = {h0.x, h0.y, h0.z, h0.w, h1.x, h1.y, h1.z, h1.w};
#pragma unroll
  for (int j = 0; j < 8; j++) {
    float r = 1.f / (1.f + expf(-(b2f(vir[j]) + b2f(vhr[j]))));
    float z = 1.f / (1.f + expf(-(b2f(viz[j]) + b2f(vhz[j]))));
    float n = tanhf(b2f(vin[j]) + r * b2f(vhn[j]));
    hvv[j] = (1.f - z) * n + z * hvv[j];
  }
  *(float4*)hp = make_float4(hvv[0], hvv[1], hvv[2], hvv[3]);
  *(float4*)(hp + 4) = make_float4(hvv[4], hvv[5], hvv[6], hvv[7]);
}

// ---------------------------------------------------------------- gate pass
__global__ __launch_bounds__(256) void gate_kernel(
    const float* __restrict__ hv, const int* __restrict__ ntype,
    const float* __restrict__ gate_w, const float* __restrict__ gate_b,
    float* __restrict__ gw) {
  int w = (blockIdx.x * blockDim.x + threadIdx.x) >> 6;
  int lane = threadIdx.x & 63;
  if (w >= N_NODES) return;
  int t = ntype[w];
  float4 h = *reinterpret_cast<const float4*>(hv + (size_t)w * H + lane * 4);
  float4 g = *reinterpret_cast<const float4*>(gate_w + t * H + lane * 4);
  float s = h.x * g.x + h.y * g.y + h.z * g.z + h.w * g.w;
  for (int off = 32; off; off >>= 1) s += __shfl_xor(s, off);
  if (lane == 0) gw[w] = 1.f / (1.f + expf(-(s + gate_b[t])));
}

// ---------------------------------------------------------------- U column-sum
__global__ __launch_bounds__(256) void usum_kernel(
    const float* __restrict__ hv, const int* __restrict__ ntype,
    const float* __restrict__ gw, float* __restrict__ U, float* __restrict__ G) {
  const int CH = (N_NODES + 255) / 256;  // 79
  int col = threadIdx.x;
  int r0 = blockIdx.x * CH;
  int r1 = min(r0 + CH, N_NODES);
  float a0 = 0.f, a1 = 0.f, a2 = 0.f;
  float g0 = 0.f, g1 = 0.f, g2 = 0.f;
  int i = r0;
  for (; i + 4 <= r1; i += 4) {
    float v0 = hv[(size_t)(i + 0) * H + col];
    float v1 = hv[(size_t)(i + 1) * H + col];
    float v2 = hv[(size_t)(i + 2) * H + col];
    float v3 = hv[(size_t)(i + 3) * H + col];
    int t0 = ntype[i + 0], t1 = ntype[i + 1], t2 = ntype[i + 2], t3 = ntype[i + 3];
    float w0 = gw[i + 0], w1 = gw[i + 1], w2 = gw[i + 2], w3 = gw[i + 3];
    v0 *= w0; v1 *= w1; v2 *= w2; v3 *= w3;
    a0 += (t0 == 0) ? v0 : 0.f; a1 += (t0 == 1) ? v0 : 0.f; a2 += (t0 == 2) ? v0 : 0.f;
    a0 += (t1 == 0) ? v1 : 0.f; a1 += (t1 == 1) ? v1 : 0.f; a2 += (t1 == 2) ? v1 : 0.f;
    a0 += (t2 == 0) ? v2 : 0.f; a1 += (t2 == 1) ? v2 : 0.f; a2 += (t2 == 2) ? v2 : 0.f;
    a0 += (t3 == 0) ? v3 : 0.f; a1 += (t3 == 1) ? v3 : 0.f; a2 += (t3 == 2) ? v3 : 0.f;
    g0 += (t0 == 0) ? w0 : 0.f; g1 += (t0 == 1) ? w0 : 0.f; g2 += (t0 == 2) ? w0 : 0.f;
    g0 += (t1 == 0) ? w1 : 0.f; g1 += (t1 == 1) ? w1 : 0.f; g2 += (t1 == 2) ? w1 : 0.f;
    g0 += (t2 == 0) ? w2 : 0.f; g1 += (t2 == 1) ? w2 : 0.f; g2 += (t2 == 2) ? w2 : 0.f;
    g0 += (t3 == 0) ? w3 : 0.f; g1 += (t3 == 1) ? w3 : 0.f; g2 += (t3 == 2) ? w3 : 0.f;
  }
  for (; i < r1; i++) {
    float v = hv[(size_t)i * H + col];
    int t = ntype[i];
    float w = gw[i];
    v *= w;
    a0 += (t == 0) ? v : 0.f; a1 += (t == 1) ? v : 0.f; a2 += (t == 2) ? v : 0.f;
    g0 += (t == 0) ? w : 0.f; g1 += (t == 1) ? w : 0.f; g2 += (t == 2) ? w : 0.f;
  }
  unsafeAtomicAdd(&U[0 * H + col], a0);
  unsafeAtomicAdd(&U[1 * H + col], a1);
  unsafeAtomicAdd(&U[2 * H + col], a2);
  if (col == 0) {
    unsafeAtomicAdd(&G[0], g0);
    unsafeAtomicAdd(&G[1], g1);
    unsafeAtomicAdd(&G[2], g2);
  }
}

// ---------------------------------------------------------------- gembed (k-split, MLP)
__global__ __launch_bounds__(256) void gembed_partial(
    const float* __restrict__ U, const float* __restrict__ G,
    const float* __restrict__ tograph_w, const float* __restrict__ tograph_b,
    float* __restrict__ gembed_out) {
  int b = blockIdx.x;
  int t = b >> 4, half = (b >> 3) & 1, kc = b & 7;
  int col = half * 256 + threadIdx.x;
  int k0 = kc * 32;
  const float* Wt = tograph_w + (size_t)t * H * GH;
  float w[32], u[32];
#pragma unroll
  for (int j = 0; j < 32; j++) w[j] = Wt[(size_t)(k0 + j) * GH + col];
#pragma unroll
  for (int j = 0; j < 32; j++) u[j] = U[t * H + k0 + j];
  float acc = (kc == 0) ? G[t] * tograph_b[t * GH + col] : 0.f;
#pragma unroll
  for (int j = 0; j < 32; j++) acc += u[j] * w[j];
  unsafeAtomicAdd(&gembed_out[col], acc);
}

// ---------------------------------------------------------------- heads (k-split, MLP)
__global__ __launch_bounds__(256) void heads_kernel(
    const float* __restrict__ ge, const float* __restrict__ addnode_w,
    const float* __restrict__ addnode_b, const float* __restrict__ ntype_embed,
    const float* __restrict__ inithv_w, const float* __restrict__ inithv_b,
    const float* __restrict__ addedge_w, const float* __restrict__ addedge_b,
    const float* __restrict__ hv, float* __restrict__ nodelogp_out,
    float* __restrict__ hvinit_out, float* __restrict__ edgelogit_out) {
  int b = blockIdx.x;
  int tid = threadIdx.x;
  if (b < 24) {
    int k0 = b * 32;
    float w[32], x[32];
#pragma unroll
    for (int j = 0; j < 32; j++) w[j] = inithv_w[(size_t)(k0 + j) * H + tid];
#pragma unroll
    for (int j = 0; j < 32; j++) {
      int k = k0 + j;
      x[j] = (k < H) ? ntype_embed[k] : ge[k - H];
    }
    float acc = (b == 0) ? inithv_b[tid] : 0.f;
#pragma unroll
    for (int j = 0; j < 32; j++) acc += x[j] * w[j];
    unsafeAtomicAdd(&hvinit_out[tid], acc);
  } else if (b == 24) {
    __shared__ float lg[4];
    int w = tid >> 6, lane = tid & 63;
    float s = 0.f;
    for (int k = lane; k < GH; k += 64) s += ge[k] * addnode_w[k * 4 + w];
    for (int off = 32; off; off >>= 1) s += __shfl_xor(s, off);
    if (lane == 0) lg[w] = s + addnode_b[w];
    __syncthreads();
    if (tid == 0) {
      float m = fmaxf(fmaxf(lg[0], lg[1]), fmaxf(lg[2], lg[3]));
      float sum = 0.f;
      for (int c = 0; c < 4; c++) sum += expf(lg[c] - m);
      float lse = m + logf(sum);
      for (int c = 0; c < 4; c++) nodelogp_out[c] = lg[c] - lse;
    }
  } else {
    int w = tid >> 6, lane = tid & 63;
    if (w == 0) {
      const float* se = hv + (size_t)(N_NODES - 1) * H;
      float s = 0.f;
      for (int k = lane; k < G3; k += 64) {
        float x = (k < GH) ? ge[k] : se[k - GH];
        s += x * addedge_w[k];
      }
      for (int off = 32; off; off >>= 1) s += __shfl_xor(s, off);
      if (lane == 0) edgelogit_out[0] = s + addedge_b[0];
    }
  }
}

// ---------------------------------------------------------------- dest scores
__global__ __launch_bounds__(256) void dest_scores_kernel(
    const float* __restrict__ hv, const float* __restrict__ dest_w,
    float* __restrict__ scores) {
  int w = (blockIdx.x * blockDim.x + threadIdx.x) >> 6;
  int lane = threadIdx.x & 63;
  if (w >= N_NODES - 1) return;
  float4 h = *reinterpret_cast<const float4*>(hv + (size_t)w * H + lane * 4);
  float4 d = *reinterpret_cast<const float4*>(dest_w + lane * 4);
  float s = h.x * d.x + h.y * d.y + h.z * d.z + h.w * d.w;
  for (int off = 32; off; off >>= 1) s += __shfl_xor(s, off);
  if (lane == 0) scores[w] = s;
}

__global__ __launch_bounds__(1024) void dest_softmax(const float* __restrict__ scores,
                                                     float* __restrict__ out) {
  const int n = N_NODES - 1;
  __shared__ float red[16];
  __shared__ float bc[2];
  int tid = threadIdx.x;
  float m = -1e30f;
  for (int i = tid; i < n; i += 1024) m = fmaxf(m, scores[i]);
  for (int off = 32; off; off >>= 1) m = fmaxf(m, __shfl_xor(m, off));
  if ((tid & 63) == 0) red[tid >> 6] = m;
  __syncthreads();
  if (tid == 0) {
    float v = red[0];
    for (int i = 1; i < 16; i++) v = fmaxf(v, red[i]);
    bc[0] = v;
  }
  __syncthreads();
  float mx = bc[0];
  float s = 0.f;
  for (int i = tid; i < n; i += 1024) s += expf(scores[i] - mx);
  for (int off = 32; off; off >>= 1) s += __shfl_xor(s, off);
  if ((tid & 63) == 0) red[tid >> 6] = s;
  __syncthreads();
  if (tid == 0) {
    float v = 0.f;
    for (int i = 0; i < 16; i++) v += red[i];
    bc[1] = v;
  }
  __syncthreads();
  float lse = mx + logf(bc[1]);
  for (int i = tid; i < n; i += 1024) out[i] = scores[i] - lse;
}

// ---------------------------------------------------------------- launch
extern "C" void kernel_launch(void* const* d_in, const int* in_sizes, int n_in,
                              void* d_out, int out_size, void* d_ws, size_t ws_size,
                              hipStream_t stream) {
  const float* hv0 = (const float*)d_in[0];
  const float* he = (const float*)d_in[1];
  const int* ntype = (const int*)d_in[2];
  const int* src = (const int*)d_in[3];
  const int* dst = (const int*)d_in[4];
  const float* msg_w = (const float*)d_in[5];
  const float* msg_b = (const float*)d_in[6];
  const float* w_ih = (const float*)d_in[7];
  const float* b_ih = (const float*)d_in[8];
  const float* w_hh = (const float*)d_in[9];
  const float* b_hh = (const float*)d_in[10];
  const float* gate_w = (const float*)d_in[11];
  const float* gate_b = (const float*)d_in[12];
  const float* tograph_w = (const float*)d_in[13];
  const float* tograph_b = (const float*)d_in[14];
  const float* addnode_w = (const float*)d_in[15];
  const float* addnode_b = (const float*)d_in[16];
  const float* ntype_embed = (const float*)d_in[17];
  const float* inithv_w = (const float*)d_in[18];
  const float* inithv_b = (const float*)d_in[19];
  const float* addedge_w = (const float*)d_in[20];
  const float* addedge_b = (const float*)d_in[21];
  const float* dest_w = (const float*)d_in[22];
  const float* dest_b = (const float*)d_in[23];

  float* out = (float*)d_out;
  float* HV = out;
  float* gembed_out = out + (size_t)N_NODES * H;
  float* nodelogp_out = gembed_out + GH;
  float* hvinit_out = nodelogp_out + 4;
  float* edgelogit_out = hvinit_out + H;
  float* destlogp_out = edgelogit_out + 1;

  float* ws = (float*)d_ws;
  float* deg = ws;                                    // N
  float* hesum = deg + N_NODES;                       // N
  float* U = hesum + N_NODES;                         // NT*H
  float* G = U + NT * H;                              // NT
  float* misc = G + NT;                               // 16
  float* wep = misc + 16;                             // 2*G3
  float* bmp = wep + 2 * G3;                          // 2*G3
  float* scores = bmp + 2 * G3;                       // N
  float* gw = scores + N_NODES;                       // N
  int* cnt = (int*)(gw + N_NODES);                    // N
  int* rowptr = cnt + N_NODES;                        // N+1
  int* cursor = rowptr + N_NODES + 1;                 // N
  int* nbr = cursor + N_NODES;                        // E
  unsigned short* A_msg =
      (unsigned short*)(((uintptr_t)(nbr + N_EDGES) + 15) & ~(uintptr_t)15);
  unsigned short* HVb = A_msg + (size_t)(N_NODES + 128) * GH;
  unsigned short* gib = HVb + (size_t)(N_NODES + 128) * H;
  unsigned short* ghb = gib + (size_t)(N_NODES + 128) * G3;
  unsigned short* wihb = ghb + (size_t)(N_NODES + 128) * G3;
  unsigned short* whhb = wihb + (size_t)2 * G3 * GH;
  unsigned short* msg_wb = whhb + (size_t)2 * G3 * H;   // 2 * 513*512
  unsigned short* Wc = msg_wb + (size_t)2 * 513 * 512;  // 2 * G3*GH

  hipMemcpyAsync(HV, hv0, sizeof(float) * (size_t)N_NODES * H,
                 hipMemcpyDeviceToDevice, stream);

  // ---- weight prep: bf16 casts, then per-round combined weights
  cast_bf16<<<(2 * G3 * GH + 255) / 256, 256, 0, stream>>>(w_ih, wihb, 2 * G3 * GH);
  cast_bf16<<<(2 * G3 * H + 255) / 256, 256, 0, stream>>>(w_hh, whhb, 2 * G3 * H);
  cast_bf16<<<(2 * 513 * 512 + 255) / 256, 256, 0, stream>>>(msg_w, msg_wb,
                                                             2 * 513 * 512);
  for (int t = 0; t < R_ROUNDS; t++) {
    wcomb_gemm<<<dim3(GH / 128, G3 / 128), 256, 0, stream>>>(
        wihb + (size_t)t * G3 * GH, msg_wb + (size_t)t * 513 * 512,
        Wc + (size_t)t * G3 * GH);
    vec_comb<<<G3 / 4, 256, 0, stream>>>(
        msg_w + (size_t)t * 513 * 512, msg_b + (size_t)t * GH,
        w_ih + (size_t)t * G3 * GH, wep + (size_t)t * G3, bmp + (size_t)t * G3);
  }

  // ---- CSR build
  hipMemsetAsync(hesum, 0, sizeof(float) * N_NODES, stream);
  hipMemsetAsync(cnt, 0, sizeof(int) * N_NODES, stream);
  hist_kernel<<<(N_EDGES + 255) / 256, 256, 0, stream>>>(dst, he, cnt, hesum);
  scan_kernel<<<1, 1024, 0, stream>>>(cnt, rowptr, cursor);
  fill_kernel<<<(N_EDGES + 255) / 256, 256, 0, stream>>>(dst, src, cursor, nbr);

  for (int t = 0; t < R_ROUNDS; t++) {
    gather_kernel<<<N_NODES / 4, 256, 0, stream>>>(HV, rowptr, nbr, A_msg, HVb, deg);
    gi_gh_gemm<<<1920, 256, 0, stream>>>(
        A_msg, Wc + (size_t)t * G3 * GH, wep + (size_t)t * G3, bmp + (size_t)t * G3,
        b_ih + (size_t)t * G3, deg, hesum, gib, HVb,
        whhb + (size_t)t * G3 * H, b_hh + (size_t)t * G3, ghb);
    gru_update<<<(N_NODES * 32 + 255) / 256, 256, 0, stream>>>(gib, ghb, HV);
  }

  // dest head (c2 cancels in log_softmax)
  dest_scores_kernel<<<((N_NODES - 1) * 64 + 255) / 256, 256, 0, stream>>>(
      HV, dest_w, scores);
  dest_softmax<<<1, 1024, 0, stream>>>(scores, destlogp_out);

  // ---- graph embed
  hipMemsetAsync(U, 0, sizeof(float) * (NT * H + NT), stream);
  gate_kernel<<<(N_NODES * 64 + 255) / 256, 256, 0, stream>>>(HV, ntype, gate_w,
                                                              gate_b, gw);
  usum_kernel<<<256, 256, 0, stream>>>(HV, ntype, gw, U, G);
  hipMemsetAsync(gembed_out, 0, sizeof(float) * (GH + 4 + H + 1), stream);
  gembed_partial<<<48, 256, 0, stream>>>(U, G, tograph_w, tograph_b, gembed_out);
  heads_kernel<<<26, 256, 0, stream>>>(gembed_out, addnode_w, addnode_b, ntype_embed,
                                       inithv_w, inithv_b, addedge_w, addedge_b, HV,
                                       nodelogp_out, hvinit_out, edgelogit_out);
}

// Round 13
// 570.036 us; speedup vs baseline: 1.3931x; 1.0478x over previous
//
#include <hip/hip_runtime.h>
#include <math.h>
#include <stdint.h>

#define N_NODES 20000
#define N_EDGES 320000
#define H 256
#define GH 512
#define G3 768
#define NT 3
#define R_ROUNDS 2
#define MTILES 157  // ceil(20000/128)

typedef __attribute__((ext_vector_type(8))) short short8;
typedef __attribute__((ext_vector_type(8))) unsigned short ushort8;
typedef __attribute__((ext_vector_type(4))) float floatx4;

static __device__ __forceinline__ unsigned short f2bf(float x) {
  unsigned u = __float_as_uint(x);
  u += 0x7fffu + ((u >> 16) & 1u);
  return (unsigned short)(u >> 16);
}
static __device__ __forceinline__ float b2f(unsigned short x) {
  return __uint_as_float((unsigned)x << 16);
}

// async global->LDS, 16B per lane; LDS dest = wave-uniform base + lane*16
static __device__ __forceinline__ void load_lds_16(const unsigned short* g,
                                                   unsigned short* l) {
  __builtin_amdgcn_global_load_lds(
      (const __attribute__((address_space(1))) unsigned int*)g,
      (__attribute__((address_space(3))) unsigned int*)l, 16, 0, 0);
}

// ---------------------------------------------------------------- CSR build
__global__ __launch_bounds__(256) void hist_kernel(
    const int* __restrict__ dst, const float* __restrict__ he,
    int* __restrict__ cnt, float* __restrict__ hesum) {
  int e = blockIdx.x * 256 + threadIdx.x;
  if (e >= N_EDGES) return;
  int d = dst[e];
  atomicAdd(&cnt[d], 1);
  unsafeAtomicAdd(&hesum[d], he[e]);
}

__global__ __launch_bounds__(1024) void scan_kernel(
    const int* __restrict__ cnt, int* __restrict__ rowptr, int* __restrict__ cursor) {
  __shared__ int part[1024];
  const int CH = (N_NODES + 1023) / 1024;  // 20
  int t = threadIdx.x;
  int base = t * CH;
  int s = 0;
  for (int j = 0; j < CH; j++) {
    int idx = base + j;
    if (idx < N_NODES) s += cnt[idx];
  }
  part[t] = s;
  __syncthreads();
  int v = part[t];
  for (int off = 1; off < 1024; off <<= 1) {
    int o = (t >= off) ? part[t - off] : 0;
    __syncthreads();
    part[t] += o;
    __syncthreads();
  }
  int excl = part[t] - v;
  int run = excl;
  for (int j = 0; j < CH; j++) {
    int idx = base + j;
    if (idx < N_NODES) {
      rowptr[idx] = run;
      cursor[idx] = run;
      run += cnt[idx];
    }
  }
  if (t == 1023) rowptr[N_NODES] = run;
}

__global__ __launch_bounds__(256) void fill_kernel(
    const int* __restrict__ dst, const int* __restrict__ src,
    int* __restrict__ cursor, int* __restrict__ nbr) {
  int e = blockIdx.x * 256 + threadIdx.x;
  if (e >= N_EDGES) return;
  int p = atomicAdd(&cursor[dst[e]], 1);
  nbr[p] = src[e];
}

// ---------------------------------------------------------------- weight prep
__global__ __launch_bounds__(256) void cast_bf16(const float* __restrict__ in,
                                                 unsigned short* __restrict__ out, int n) {
  int i = blockIdx.x * 256 + threadIdx.x;
  if (i < n) out[i] = f2bf(in[i]);
}

// wep[n] = dot(msg_w row 512, w_ih[n]); bmp[n] = dot(msg_b, w_ih[n])  (NO b_ih)
__global__ __launch_bounds__(256) void vec_comb(
    const float* __restrict__ msg_w_t, const float* __restrict__ msg_b_t,
    const float* __restrict__ w_ih_t,
    float* __restrict__ wep, float* __restrict__ bmp) {
  int n = blockIdx.x * 4 + (threadIdx.x >> 6);
  int lane = threadIdx.x & 63;
  const float* we = msg_w_t + (size_t)GH * GH;
  const float* wr = w_ih_t + (size_t)n * GH;
  float s1 = 0.f, s2 = 0.f;
  for (int k = lane; k < GH; k += 64) {
    float w = wr[k];
    s1 += we[k] * w;
    s2 += msg_b_t[k] * w;
  }
  for (int off = 32; off; off >>= 1) {
    s1 += __shfl_xor(s1, off);
    s2 += __shfl_xor(s2, off);
  }
  if (lane == 0) {
    wep[n] = s1;
    bmp[n] = s2;
  }
}

// ---------------------------------------------------------------- gather
__global__ __launch_bounds__(256) void gather_kernel(
    const float* __restrict__ hv, const int* __restrict__ rowptr,
    const int* __restrict__ nbr, unsigned short* __restrict__ A_msg,
    unsigned short* __restrict__ HVb, float* __restrict__ deg) {
  int w = (blockIdx.x * blockDim.x + threadIdx.x) >> 6;
  int lane = threadIdx.x & 63;
  if (w >= N_NODES) return;
  int start = rowptr[w], end = rowptr[w + 1];
  float4 acc = make_float4(0.f, 0.f, 0.f, 0.f);
  for (int b = start; b < end; b += 64) {
    int nb = min(64, end - b);
    int sidx = (lane < nb) ? nbr[b + lane] : 0;
    for (int j = 0; j < nb; j++) {
      int s = __shfl(sidx, j);
      const float4 v = *reinterpret_cast<const float4*>(hv + (size_t)s * H + lane * 4);
      acc.x += v.x; acc.y += v.y; acc.z += v.z; acc.w += v.w;
    }
  }
  float dg = (float)(end - start);
  const float4 own = *reinterpret_cast<const float4*>(hv + (size_t)w * H + lane * 4);
  ushort4 o;
  o.x = f2bf(own.x * dg); o.y = f2bf(own.y * dg);
  o.z = f2bf(own.z * dg); o.w = f2bf(own.w * dg);
  *reinterpret_cast<ushort4*>(A_msg + (size_t)w * GH + lane * 4) = o;
  o.x = f2bf(acc.x); o.y = f2bf(acc.y); o.z = f2bf(acc.z); o.w = f2bf(acc.w);
  *reinterpret_cast<ushort4*>(A_msg + (size_t)w * GH + H + lane * 4) = o;
  o.x = f2bf(own.x); o.y = f2bf(own.y); o.z = f2bf(own.z); o.w = f2bf(own.w);
  *reinterpret_cast<ushort4*>(HVb + (size_t)w * H + lane * 4) = o;
  if (lane == 0) deg[w] = dg;
}

// ---------------------------------------------------------------- GEMM core
// 128x128 tile, BK=64, async global_load_lds staging with XOR chunk swizzle:
// LDS[row][p] holds global chunk (p ^ (row&7)) of row; rows packed, stride 64.
static __device__ __forceinline__ void stage_tile(
    const unsigned short* gA, const unsigned short* gB, int K,
    unsigned short* As, unsigned short* Bs,
    size_t i0, size_t j0, int k0, int wv, int lane) {
  int rsub = lane >> 3;
  int pos = lane & 7;
#pragma unroll
  for (int q = 0; q < 4; q++) {
    int row = wv * 32 + q * 8 + rsub;
    int gc = (pos ^ (row & 7)) * 8;
    load_lds_16(gA + (i0 + row) * (size_t)K + k0 + gc, As + (wv * 32 + q * 8) * 64);
    load_lds_16(gB + (j0 + row) * (size_t)K + k0 + gc, Bs + (wv * 32 + q * 8) * 64);
  }
}

#define MFMA_BLOCK                                                                \
  _Pragma("unroll") for (int kk = 0; kk < 2; kk++) {                              \
    short8 af[4], bf[4];                                                          \
    _Pragma("unroll") for (int mi = 0; mi < 4; mi++) {                            \
      int row = m0 + mi * 16 + lr;                                                \
      af[mi] = *(const short8*)(As + row * 64 + ((kk * 4 + lq) ^ (row & 7)) * 8); \
    }                                                                             \
    _Pragma("unroll") for (int ni = 0; ni < 4; ni++) {                            \
      int row = n0 + ni * 16 + lr;                                                \
      bf[ni] = *(const short8*)(Bs + row * 64 + ((kk * 4 + lq) ^ (row & 7)) * 8); \
    }                                                                             \
    _Pragma("unroll") for (int mi = 0; mi < 4; mi++)                              \
      _Pragma("unroll") for (int ni = 0; ni < 4; ni++)                            \
        acc[mi][ni] = __builtin_amdgcn_mfma_f32_16x16x32_bf16(af[mi], bf[ni],     \
                                                              acc[mi][ni], 0, 0, 0); \
  }

#define GEMM_CORE(A, W, K)                                                        \
  {                                                                               \
    stage_tile((A), (W), (K), As, Bs, i0, j0, 0, wv, lane);                       \
    for (int k0 = 0; k0 < (K); k0 += 64) {                                        \
      __syncthreads();                                                            \
      MFMA_BLOCK                                                                  \
      if (k0 + 64 < (K)) {                                                        \
        __syncthreads();                                                          \
        stage_tile((A), (W), (K), As, Bs, i0, j0, k0 + 64, wv, lane);             \
      }                                                                           \
    }                                                                             \
  }

// ---------------------------------------------------------------- weight-combine GEMM
// Wc[n][k] = sum_j w_ih[n][j] * msg_w[k][j]. grid (4, 6), out bf16 768x512.
__global__ __launch_bounds__(256) void wcomb_gemm(
    const unsigned short* __restrict__ A, const unsigned short* __restrict__ W,
    unsigned short* __restrict__ Cb) {
  __shared__ alignas(16) unsigned short As[128 * 64];
  __shared__ alignas(16) unsigned short Bs[128 * 64];
  int t = threadIdx.x;
  size_t i0 = (size_t)blockIdx.y * 128;
  size_t j0 = (size_t)blockIdx.x * 128;
  int wv = t >> 6, lane = t & 63;
  int m0 = (wv >> 1) * 64, n0 = (wv & 1) * 64;
  int lr = lane & 15, lq = lane >> 4;
  floatx4 acc[4][4];
#pragma unroll
  for (int a = 0; a < 4; a++)
#pragma unroll
    for (int b = 0; b < 4; b++) acc[a][b] = (floatx4){0.f, 0.f, 0.f, 0.f};
  GEMM_CORE(A, W, GH)
#pragma unroll
  for (int mi = 0; mi < 4; mi++) {
#pragma unroll
    for (int ni = 0; ni < 4; ni++) {
      int col = (int)j0 + n0 + ni * 16 + lr;
#pragma unroll
      for (int i = 0; i < 4; i++) {
        size_t row = i0 + m0 + mi * 16 + lq * 4 + i;
        Cb[row * GH + col] = f2bf(acc[mi][ni][i]);
      }
    }
  }
}

// ---------------------------------------------------------------- fused gi + gh GEMM
// Flat grid 1920, XCD-swizzled. jb 0..5: gi = A_msg@Wc^T + hesum*wep + deg*bmp + b_ih.
// jb 6..11: gh = HVb@Whh^T + bhh.  Both bf16 out, ldc G3.
__global__ __launch_bounds__(256) void gi_gh_gemm(
    const unsigned short* __restrict__ A_msg, const unsigned short* __restrict__ Wc,
    const float* __restrict__ wep, const float* __restrict__ bmp,
    const float* __restrict__ bih,
    const float* __restrict__ deg, const float* __restrict__ hesum,
    unsigned short* __restrict__ gib, const unsigned short* __restrict__ HVb,
    const unsigned short* __restrict__ Whh, const float* __restrict__ bhh,
    unsigned short* __restrict__ ghb) {
  __shared__ alignas(16) unsigned short As[128 * 64];
  __shared__ alignas(16) unsigned short Bs[128 * 64];
  int bid = blockIdx.x;
  int xk = bid & 7, slot = bid >> 3;
  int it = xk * 20 + slot / 12;
  if (it >= MTILES) return;
  int jb = slot % 12;
  bool is_gi = jb < 6;
  int t = threadIdx.x;
  size_t i0 = (size_t)it * 128;
  size_t j0 = is_gi ? (size_t)jb * 128 : (size_t)(jb - 6) * 128;
  int wv = t >> 6, lane = t & 63;
  int m0 = (wv >> 1) * 64, n0 = (wv & 1) * 64;
  int lr = lane & 15, lq = lane >> 4;
  floatx4 acc[4][4];
#pragma unroll
  for (int a = 0; a < 4; a++)
#pragma unroll
    for (int b = 0; b < 4; b++) acc[a][b] = (floatx4){0.f, 0.f, 0.f, 0.f};

  if (is_gi) {
    GEMM_CORE(A_msg, Wc, GH)
#pragma unroll
    for (int mi = 0; mi < 4; mi++) {
#pragma unroll
      for (int ni = 0; ni < 4; ni++) {
        int col = (int)j0 + n0 + ni * 16 + lr;
        float wv_ = wep[col], bv = bmp[col], b2 = bih[col];
#pragma unroll
        for (int i = 0; i < 4; i++) {
          size_t row = i0 + m0 + mi * 16 + lq * 4 + i;
          if (row < (size_t)N_NODES)
            gib[row * G3 + col] =
                f2bf(acc[mi][ni][i] + hesum[row] * wv_ + deg[row] * bv + b2);
        }
      }
    }
  } else {
    GEMM_CORE(HVb, Whh, H)
#pragma unroll
    for (int mi = 0; mi < 4; mi++) {
#pragma unroll
      for (int ni = 0; ni < 4; ni++) {
        int col = (int)j0 + n0 + ni * 16 + lr;
        float bv = bhh[col];
#pragma unroll
        for (int i = 0; i < 4; i++) {
          size_t row = i0 + m0 + mi * 16 + lq * 4 + i;
          if (row < (size_t)N_NODES) ghb[row * G3 + col] = f2bf(acc[mi][ni][i] + bv);
        }
      }
    }
  }
}

// ---------------------------------------------------------------- GRU elementwise (bf16 in)
__global__ __launch_bounds__(256) void gru_update(const unsigned short* __restrict__ gi,
                                                  const unsigned short* __restrict__ gh,
                                                  float* __restrict__ hv) {
  int idx = blockIdx.x * 256 + threadIdx.x;
  if (idx >= N_NODES * 32) return;
  int row = idx >> 5;
  int c8 = (idx & 31) << 3;
  const unsigned short* gir = gi + (size_t)row * G3;
  const unsigned short* ghr = gh + (size_t)row * G3;
  ushort8 vir = *(const ushort8*)(gir + c8);
  ushort8 viz = *(const ushort8*)(gir + H + c8);
  ushort8 vin = *(const ushort8*)(gir + 2 * H + c8);
  ushort8 vhr = *(const ushort8*)(ghr + c8);
  ushort8 vhz = *(const ushort8*)(ghr + H + c8);
  ushort8 vhn = *(const ushort8*)(ghr + 2 * H + c8);
  float* hp = hv + (size_t)row * H + c8;
  float4 h0 = *(float4*)hp;
  float4 h1 = *(float4*)(hp + 4);
  float hvv[8] = {h0.x, h0.y, h0.z, h0.w, h1.x, h1.y, h1.z, h1.w};
#pragma unroll
  for (int j = 0; j < 8; j++) {
    float r = 1.f / (1.f + expf(-(b2f(vir[j]) + b2f(vhr[j]))));
    float z = 1.f / (1.f + expf(-(b2f(viz[j]) + b2f(vhz[j]))));
    float n = tanhf(b2f(vin[j]) + r * b2f(vhn[j]));
    hvv[j] = (1.f - z) * n + z * hvv[j];
  }
  *(float4*)hp = make_float4(hvv[0], hvv[1], hvv[2], hvv[3]);
  *(float4*)(hp + 4) = make_float4(hvv[4], hvv[5], hvv[6], hvv[7]);
}

// ---------------------------------------------------------------- gate pass
__global__ __launch_bounds__(256) void gate_kernel(
    const float* __restrict__ hv, const int* __restrict__ ntype,
    const float* __restrict__ gate_w, const float* __restrict__ gate_b,
    float* __restrict__ gw) {
  int w = (blockIdx.x * blockDim.x + threadIdx.x) >> 6;
  int lane = threadIdx.x & 63;
  if (w >= N_NODES) return;
  int t = ntype[w];
  float4 h = *reinterpret_cast<const float4*>(hv + (size_t)w * H + lane * 4);
  float4 g = *reinterpret_cast<const float4*>(gate_w + t * H + lane * 4);
  float s = h.x * g.x + h.y * g.y + h.z * g.z + h.w * g.w;
  for (int off = 32; off; off >>= 1) s += __shfl_xor(s, off);
  if (lane == 0) gw[w] = 1.f / (1.f + expf(-(s + gate_b[t])));
}

// ---------------------------------------------------------------- U column-sum
__global__ __launch_bounds__(256) void usum_kernel(
    const float* __restrict__ hv, const int* __restrict__ ntype,
    const float* __restrict__ gw, float* __restrict__ U, float* __restrict__ G) {
  const int CH = (N_NODES + 255) / 256;  // 79
  int col = threadIdx.x;
  int r0 = blockIdx.x * CH;
  int r1 = min(r0 + CH, N_NODES);
  float a0 = 0.f, a1 = 0.f, a2 = 0.f;
  float g0 = 0.f, g1 = 0.f, g2 = 0.f;
  int i = r0;
  for (; i + 4 <= r1; i += 4) {
    float v0 = hv[(size_t)(i + 0) * H + col];
    float v1 = hv[(size_t)(i + 1) * H + col];
    float v2 = hv[(size_t)(i + 2) * H + col];
    float v3 = hv[(size_t)(i + 3) * H + col];
    int t0 = ntype[i + 0], t1 = ntype[i + 1], t2 = ntype[i + 2], t3 = ntype[i + 3];
    float w0 = gw[i + 0], w1 = gw[i + 1], w2 = gw[i + 2], w3 = gw[i + 3];
    v0 *= w0; v1 *= w1; v2 *= w2; v3 *= w3;
    a0 += (t0 == 0) ? v0 : 0.f; a1 += (t0 == 1) ? v0 : 0.f; a2 += (t0 == 2) ? v0 : 0.f;
    a0 += (t1 == 0) ? v1 : 0.f; a1 += (t1 == 1) ? v1 : 0.f; a2 += (t1 == 2) ? v1 : 0.f;
    a0 += (t2 == 0) ? v2 : 0.f; a1 += (t2 == 1) ? v2 : 0.f; a2 += (t2 == 2) ? v2 : 0.f;
    a0 += (t3 == 0) ? v3 : 0.f; a1 += (t3 == 1) ? v3 : 0.f; a2 += (t3 == 2) ? v3 : 0.f;
    g0 += (t0 == 0) ? w0 : 0.f; g1 += (t0 == 1) ? w0 : 0.f; g2 += (t0 == 2) ? w0 : 0.f;
    g0 += (t1 == 0) ? w1 : 0.f; g1 += (t1 == 1) ? w1 : 0.f; g2 += (t1 == 2) ? w1 : 0.f;
    g0 += (t2 == 0) ? w2 : 0.f; g1 += (t2 == 1) ? w2 : 0.f; g2 += (t2 == 2) ? w2 : 0.f;
    g0 += (t3 == 0) ? w3 : 0.f; g1 += (t3 == 1) ? w3 : 0.f; g2 += (t3 == 2) ? w3 : 0.f;
  }
  for (; i < r1; i++) {
    float v = hv[(size_t)i * H + col];
    int t = ntype[i];
    float w = gw[i];
    v *= w;
    a0 += (t == 0) ? v : 0.f; a1 += (t == 1) ? v : 0.f; a2 += (t == 2) ? v : 0.f;
    g0 += (t == 0) ? w : 0.f; g1 += (t == 1) ? w : 0.f; g2 += (t == 2) ? w : 0.f;
  }
  unsafeAtomicAdd(&U[0 * H + col], a0);
  unsafeAtomicAdd(&U[1 * H + col], a1);
  unsafeAtomicAdd(&U[2 * H + col], a2);
  if (col == 0) {
    unsafeAtomicAdd(&G[0], g0);
    unsafeAtomicAdd(&G[1], g1);
    unsafeAtomicAdd(&G[2], g2);
  }
}

// ---------------------------------------------------------------- gembed (k-split, MLP)
__global__ __launch_bounds__(256) void gembed_partial(
    const float* __restrict__ U, const float* __restrict__ G,
    const float* __restrict__ tograph_w, const float* __restrict__ tograph_b,
    float* __restrict__ gembed_out) {
  int b = blockIdx.x;
  int t = b >> 4, half = (b >> 3) & 1, kc = b & 7;
  int col = half * 256 + threadIdx.x;
  int k0 = kc * 32;
  const float* Wt = tograph_w + (size_t)t * H * GH;
  float w[32], u[32];
#pragma unroll
  for (int j = 0; j < 32; j++) w[j] = Wt[(size_t)(k0 + j) * GH + col];
#pragma unroll
  for (int j = 0; j < 32; j++) u[j] = U[t * H + k0 + j];
  float acc = (kc == 0) ? G[t] * tograph_b[t * GH + col] : 0.f;
#pragma unroll
  for (int j = 0; j < 32; j++) acc += u[j] * w[j];
  unsafeAtomicAdd(&gembed_out[col], acc);
}

// ---------------------------------------------------------------- heads (k-split, MLP)
__global__ __launch_bounds__(256) void heads_kernel(
    const float* __restrict__ ge, const float* __restrict__ addnode_w,
    const float* __restrict__ addnode_b, const float* __restrict__ ntype_embed,
    const float* __restrict__ inithv_w, const float* __restrict__ inithv_b,
    const float* __restrict__ addedge_w, const float* __restrict__ addedge_b,
    const float* __restrict__ hv, float* __restrict__ nodelogp_out,
    float* __restrict__ hvinit_out, float* __restrict__ edgelogit_out) {
  int b = blockIdx.x;
  int tid = threadIdx.x;
  if (b < 24) {
    int k0 = b * 32;
    float w[32], x[32];
#pragma unroll
    for (int j = 0; j < 32; j++) w[j] = inithv_w[(size_t)(k0 + j) * H + tid];
#pragma unroll
    for (int j = 0; j < 32; j++) {
      int k = k0 + j;
      x[j] = (k < H) ? ntype_embed[k] : ge[k - H];
    }
    float acc = (b == 0) ? inithv_b[tid] : 0.f;
#pragma unroll
    for (int j = 0; j < 32; j++) acc += x[j] * w[j];
    unsafeAtomicAdd(&hvinit_out[tid], acc);
  } else if (b == 24) {
    __shared__ float lg[4];
    int w = tid >> 6, lane = tid & 63;
    float s = 0.f;
    for (int k = lane; k < GH; k += 64) s += ge[k] * addnode_w[k * 4 + w];
    for (int off = 32; off; off >>= 1) s += __shfl_xor(s, off);
    if (lane == 0) lg[w] = s + addnode_b[w];
    __syncthreads();
    if (tid == 0) {
      float m = fmaxf(fmaxf(lg[0], lg[1]), fmaxf(lg[2], lg[3]));
      float sum = 0.f;
      for (int c = 0; c < 4; c++) sum += expf(lg[c] - m);
      float lse = m + logf(sum);
      for (int c = 0; c < 4; c++) nodelogp_out[c] = lg[c] - lse;
    }
  } else {
    int w = tid >> 6, lane = tid & 63;
    if (w == 0) {
      const float* se = hv + (size_t)(N_NODES - 1) * H;
      float s = 0.f;
      for (int k = lane; k < G3; k += 64) {
        float x = (k < GH) ? ge[k] : se[k - GH];
        s += x * addedge_w[k];
      }
      for (int off = 32; off; off >>= 1) s += __shfl_xor(s, off);
      if (lane == 0) edgelogit_out[0] = s + addedge_b[0];
    }
  }
}

// ---------------------------------------------------------------- dest scores
__global__ __launch_bounds__(256) void dest_scores_kernel(
    const float* __restrict__ hv, const float* __restrict__ dest_w,
    float* __restrict__ scores) {
  int w = (blockIdx.x * blockDim.x + threadIdx.x) >> 6;
  int lane = threadIdx.x & 63;
  if (w >= N_NODES - 1) return;
  float4 h = *reinterpret_cast<const float4*>(hv + (size_t)w * H + lane * 4);
  float4 d = *reinterpret_cast<const float4*>(dest_w + lane * 4);
  float s = h.x * d.x + h.y * d.y + h.z * d.z + h.w * d.w;
  for (int off = 32; off; off >>= 1) s += __shfl_xor(s, off);
  if (lane == 0) scores[w] = s;
}

__global__ __launch_bounds__(1024) void dest_softmax(const float* __restrict__ scores,
                                                     float* __restrict__ out) {
  const int n = N_NODES - 1;
  __shared__ float red[16];
  __shared__ float bc[2];
  int tid = threadIdx.x;
  float m = -1e30f;
  for (int i = tid; i < n; i += 1024) m = fmaxf(m, scores[i]);
  for (int off = 32; off; off >>= 1) m = fmaxf(m, __shfl_xor(m, off));
  if ((tid & 63) == 0) red[tid >> 6] = m;
  __syncthreads();
  if (tid == 0) {
    float v = red[0];
    for (int i = 1; i < 16; i++) v = fmaxf(v, red[i]);
    bc[0] = v;
  }
  __syncthreads();
  float mx = bc[0];
  float s = 0.f;
  for (int i = tid; i < n; i += 1024) s += expf(scores[i] - mx);
  for (int off = 32; off; off >>= 1) s += __shfl_xor(s, off);
  if ((tid & 63) == 0) red[tid >> 6] = s;
  __syncthreads();
  if (tid == 0) {
    float v = 0.f;
    for (int i = 0; i < 16; i++) v += red[i];
    bc[1] = v;
  }
  __syncthreads();
  float lse = mx + logf(bc[1]);
  for (int i = tid; i < n; i += 1024) out[i] = scores[i] - lse;
}

// ---------------------------------------------------------------- launch
extern "C" void kernel_launch(void* const* d_in, const int* in_sizes, int n_in,
                              void* d_out, int out_size, void* d_ws, size_t ws_size,
                              hipStream_t stream) {
  const float* hv0 = (const float*)d_in[0];
  const float* he = (const float*)d_in[1];
  const int* ntype = (const int*)d_in[2];
  const int* src = (const int*)d_in[3];
  const int* dst = (const int*)d_in[4];
  const float* msg_w = (const float*)d_in[5];
  const float* msg_b = (const float*)d_in[6];
  const float* w_ih = (const float*)d_in[7];
  const float* b_ih = (const float*)d_in[8];
  const float* w_hh = (const float*)d_in[9];
  const float* b_hh = (const float*)d_in[10];
  const float* gate_w = (const float*)d_in[11];
  const float* gate_b = (const float*)d_in[12];
  const float* tograph_w = (const float*)d_in[13];
  const float* tograph_b = (const float*)d_in[14];
  const float* addnode_w = (const float*)d_in[15];
  const float* addnode_b = (const float*)d_in[16];
  const float* ntype_embed = (const float*)d_in[17];
  const float* inithv_w = (const float*)d_in[18];
  const float* inithv_b = (const float*)d_in[19];
  const float* addedge_w = (const float*)d_in[20];
  const float* addedge_b = (const float*)d_in[21];
  const float* dest_w = (const float*)d_in[22];
  const float* dest_b = (const float*)d_in[23];

  float* out = (float*)d_out;
  float* HV = out;
  float* gembed_out = out + (size_t)N_NODES * H;
  float* nodelogp_out = gembed_out + GH;
  float* hvinit_out = nodelogp_out + 4;
  float* edgelogit_out = hvinit_out + H;
  float* destlogp_out = edgelogit_out + 1;

  float* ws = (float*)d_ws;
  float* deg = ws;                                    // N
  float* hesum = deg + N_NODES;                       // N
  float* U = hesum + N_NODES;                         // NT*H
  float* G = U + NT * H;                              // NT
  float* misc = G + NT;                               // 16
  float* wep = misc + 16;                             // 2*G3
  float* bmp = wep + 2 * G3;                          // 2*G3
  float* scores = bmp + 2 * G3;                       // N
  float* gw = scores + N_NODES;                       // N
  int* cnt = (int*)(gw + N_NODES);                    // N
  int* rowptr = cnt + N_NODES;                        // N+1
  int* cursor = rowptr + N_NODES + 1;                 // N
  int* nbr = cursor + N_NODES;                        // E
  unsigned short* A_msg =
      (unsigned short*)(((uintptr_t)(nbr + N_EDGES) + 15) & ~(uintptr_t)15);
  unsigned short* HVb = A_msg + (size_t)(N_NODES + 128) * GH;
  unsigned short* gib = HVb + (size_t)(N_NODES + 128) * H;
  unsigned short* ghb = gib + (size_t)(N_NODES + 128) * G3;
  unsigned short* wihb = ghb + (size_t)(N_NODES + 128) * G3;
  unsigned short* whhb = wihb + (size_t)2 * G3 * GH;
  unsigned short* msg_wb = whhb + (size_t)2 * G3 * H;   // 2 * 513*512
  unsigned short* Wc = msg_wb + (size_t)2 * 513 * 512;  // 2 * G3*GH

  hipMemcpyAsync(HV, hv0, sizeof(float) * (size_t)N_NODES * H,
                 hipMemcpyDeviceToDevice, stream);

  // ---- weight prep: bf16 casts, then per-round combined weights
  cast_bf16<<<(2 * G3 * GH + 255) / 256, 256, 0, stream>>>(w_ih, wihb, 2 * G3 * GH);
  cast_bf16<<<(2 * G3 * H + 255) / 256, 256, 0, stream>>>(w_hh, whhb, 2 * G3 * H);
  cast_bf16<<<(2 * 513 * 512 + 255) / 256, 256, 0, stream>>>(msg_w, msg_wb,
                                                             2 * 513 * 512);
  for (int t = 0; t < R_ROUNDS; t++) {
    wcomb_gemm<<<dim3(GH / 128, G3 / 128), 256, 0, stream>>>(
        wihb + (size_t)t * G3 * GH, msg_wb + (size_t)t * 513 * 512,
        Wc + (size_t)t * G3 * GH);
    vec_comb<<<G3 / 4, 256, 0, stream>>>(
        msg_w + (size_t)t * 513 * 512, msg_b + (size_t)t * GH,
        w_ih + (size_t)t * G3 * GH, wep + (size_t)t * G3, bmp + (size_t)t * G3);
  }

  // ---- CSR build
  hipMemsetAsync(hesum, 0, sizeof(float) * N_NODES, stream);
  hipMemsetAsync(cnt, 0, sizeof(int) * N_NODES, stream);
  hist_kernel<<<(N_EDGES + 255) / 256, 256, 0, stream>>>(dst, he, cnt, hesum);
  scan_kernel<<<1, 1024, 0, stream>>>(cnt, rowptr, cursor);
  fill_kernel<<<(N_EDGES + 255) / 256, 256, 0, stream>>>(dst, src, cursor, nbr);

  for (int t = 0; t < R_ROUNDS; t++) {
    gather_kernel<<<N_NODES / 4, 256, 0, stream>>>(HV, rowptr, nbr, A_msg, HVb, deg);
    gi_gh_gemm<<<1920, 256, 0, stream>>>(
        A_msg, Wc + (size_t)t * G3 * GH, wep + (size_t)t * G3, bmp + (size_t)t * G3,
        b_ih + (size_t)t * G3, deg, hesum, gib, HVb,
        whhb + (size_t)t * G3 * H, b_hh + (size_t)t * G3, ghb);
    gru_update<<<(N_NODES * 32 + 255) / 256, 256, 0, stream>>>(gib, ghb, HV);
  }

  // dest head (c2 cancels in log_softmax)
  dest_scores_kernel<<<((N_NODES - 1) * 64 + 255) / 256, 256, 0, stream>>>(
      HV, dest_w, scores);
  dest_softmax<<<1, 1024, 0, stream>>>(scores, destlogp_out);

  // ---- graph embed
  hipMemsetAsync(U, 0, sizeof(float) * (NT * H + NT), stream);
  gate_kernel<<<(N_NODES * 64 + 255) / 256, 256, 0, stream>>>(HV, ntype, gate_w,
                                                              gate_b, gw);
  usum_kernel<<<256, 256, 0, stream>>>(HV, ntype, gw, U, G);
  hipMemsetAsync(gembed_out, 0, sizeof(float) * (GH + 4 + H + 1), stream);
  gembed_partial<<<48, 256, 0, stream>>>(U, G, tograph_w, tograph_b, gembed_out);
  heads_kernel<<<26, 256, 0, stream>>>(gembed_out, addnode_w, addnode_b, ntype_embed,
                                       inithv_w, inithv_b, addedge_w, addedge_b, HV,
                                       nodelogp_out, hvinit_out, edgelogit_out);
}